// Round 3
// baseline (267.752 us; speedup 1.0000x reference)
//
#include <hip/hip_runtime.h>
#include <math.h>

#define NC 8192
#define NF 16384
#define NT 24576
#define RN 12288
#define RTILES 12
#define LASTD 1e-4f
#define PI_F 3.14159265358979323846f

// ws layout (float offsets)
#define WS_CONST 0
#define WS_TFINE 64
#define WS_SIGCO (WS_TFINE + NF)
#define WS_COLCO (WS_SIGCO + NC)
#define WS_SIGFI (WS_COLCO + 3*NC)
#define WS_COLFI (WS_SIGFI + NF)
#define WS_SRT   (WS_COLFI + 3*NF)
#define WS_RAD   (WS_SRT + 5*NT)
#define WS_WT    (WS_RAD + 4*NT)   // bf16 weights, 66 chunks * 8192 ushort

typedef __attribute__((ext_vector_type(8))) short bf16x8;
typedef __attribute__((ext_vector_type(4))) float f32x4;

static __device__ inline unsigned short f2b(float x){
  union { float f; unsigned int u; } c; c.f = x;
  unsigned int u = c.u;
  return (unsigned short)((u + 0x7fffu + ((u>>16)&1u)) >> 16);
}
static __device__ inline float b2f(unsigned short u){
  union { unsigned int u; float f; } c; c.u = ((unsigned int)u)<<16; return c.f;
}

// ---------------- prep: fold dir encoding into color bias, point affine ----------------
__global__ void k_prep(const float* hor_, const float* ver_, const float* tm,
                       const float* near_, const float* far_,
                       const float* Wcol, const float* bcol, float* cst) {
  if (threadIdx.x != 0) return;
  float hor = hor_[0], ver = ver_[0], nearv = near_[0], farv = far_[0];
  float dw[3];
  for (int j = 0; j < 3; ++j)
    dw[j] = tm[j*4+0]*hor + tm[j*4+1]*ver + tm[j*4+2] + tm[j*4+3];
  float enc[24];
  for (int i = 0; i < 3; ++i)
    for (int l = 0; l < 4; ++l) {
      float f = PI_F * exp2f(2.f*(float)l);
      float ang = dw[i]*f;
      enc[i*8 + l*2]     = sinf(ang);
      enc[i*8 + l*2 + 1] = cosf(ang);
    }
  for (int c = 0; c < 3; ++c) {
    float s = bcol[c];
    for (int d = 0; d < 24; ++d) s += enc[d]*Wcol[d*3+c];
    cst[6+c] = s;
  }
  for (int j = 0; j < 3; ++j) {
    cst[0+j] = tm[j*4+0]*hor + tm[j*4+1]*ver + tm[j*4+3];
    cst[3+j] = tm[j*4+2];
  }
  cst[9]  = nearv;
  cst[10] = (farv - nearv) / (float)(NC - 1);
  cst[11] = (farv - nearv) / (float)NC;
}

// ---------------- prep: weights -> bf16 in A-fragment-linear chunk order ----------------
// chunk c (0..65) -> [mt(16)][lane(64)][j(8)] ushort; chunk = 8192 ushort = 16KB
__global__ __launch_bounds__(256) void k_prep_w(
    const float* __restrict__ W0, const float* __restrict__ Wh,
    unsigned short* __restrict__ Wt)
{
  int base = (blockIdx.x*256 + threadIdx.x)*4;
  for (int e = base; e < base+4; ++e) {
    int c = e >> 13;
    int r = e & 8191;
    int mt = r >> 9;
    int q = r & 511;
    int ln = q >> 3, j = q & 7;
    int out = mt*16 + (ln & 15);
    int kk = (ln >> 4)*8 + j;
    float v;
    if (c < 2) {
      int k = c*32 + kk;
      v = (k < 60) ? W0[k*256 + out] : 0.f;
    } else {
      int m = (c-2) >> 3, kc = (c-2) & 7;
      v = Wh[m*65536 + (kc*32+kk)*256 + out];
    }
    Wt[e] = f2b(v);
  }
}

// ---------------- MFMA MLP: reg-streamed A (weights), h in LDS, 2 barriers/layer ----------------
template<int NCH, int NTL>
__device__ __forceinline__ void mlp_layer(
    const unsigned short* __restrict__ wl, const float* __restrict__ bias, bool relu,
    unsigned short* hbuf, int w, int lane, int lo, int hi)
{
  f32x4 acc[4][NTL];
  const f32x4 z4 = {0.f,0.f,0.f,0.f};
  #pragma unroll
  for (int mi=0;mi<4;++mi)
    #pragma unroll
    for (int ni=0;ni<NTL;++ni) acc[mi][ni] = z4;

  const unsigned short* wlane = wl + w*2048 + lane*8;
  #pragma unroll
  for (int kc = 0; kc < NCH; ++kc) {
    bf16x8 afr[4];
    #pragma unroll
    for (int mi=0;mi<4;++mi)
      afr[mi] = *(const bf16x8*)&wlane[kc*8192 + mi*512];
    bf16x8 bfr[NTL];
    #pragma unroll
    for (int ni=0;ni<NTL;++ni) {
      int p = ni*16 + lo;
      int slot = kc*4 + hi;
      bfr[ni] = *(const bf16x8*)&hbuf[p*256 + ((slot^(p&7))<<3)];
    }
    #pragma unroll
    for (int mi=0;mi<4;++mi)
      #pragma unroll
      for (int ni=0;ni<NTL;++ni)
        acc[mi][ni] = __builtin_amdgcn_mfma_f32_16x16x32_bf16(afr[mi], bfr[ni], acc[mi][ni], 0, 0, 0);
  }
  __syncthreads();   // all waves done READING hbuf (layer input)
  #pragma unroll
  for (int mi=0;mi<4;++mi) {
    int mt = w*4+mi;
    f32x4 bv = *(const f32x4*)&bias[mt*16 + hi*4];
    #pragma unroll
    for (int ni=0;ni<NTL;++ni) {
      f32x4 v = acc[mi][ni];
      float o0=v[0]+bv[0], o1=v[1]+bv[1], o2=v[2]+bv[2], o3=v[3]+bv[3];
      if (relu){o0=fmaxf(o0,0.f);o1=fmaxf(o1,0.f);o2=fmaxf(o2,0.f);o3=fmaxf(o3,0.f);}
      int p = ni*16 + lo;
      int colu = mt*16 + hi*4;
      int slot = colu >> 3, off = colu & 7;
      ushort4 uv = make_ushort4(f2b(o0), f2b(o1), f2b(o2), f2b(o3));
      *(ushort4*)&hbuf[p*256 + ((slot^(p&7))<<3) + off] = uv;
    }
  }
  __syncthreads();   // new h visible
}

template<int NTL>   // points per block = NTL*16
__global__ __launch_bounds__(256) void k_mlp_mfma(
    const float* __restrict__ cst, const unsigned short* __restrict__ Wt,
    const float* __restrict__ b0, const float* __restrict__ bh,
    const float* __restrict__ Wsig, const float* __restrict__ bsig,
    const float* __restrict__ Wcol,
    const float* __restrict__ tf, int npts,
    float* __restrict__ sig_out, float* __restrict__ col_out)
{
  __shared__ __align__(16) unsigned short hbuf[NTL*16*256];
  const int tid = threadIdx.x;
  const int w = tid >> 6, lane = tid & 63;
  const int lo = lane & 15, hi = lane >> 4;
  const int p0 = blockIdx.x * (NTL*16);

  // ---- positional encoding -> hbuf (bf16, swizzled); cols 60..63 zero ----
  {
    float a0=cst[0],a1=cst[1],a2=cst[2];
    float bb0=cst[3],bb1=cst[4],bb2=cst[5];
    float nearv=cst[9], step=cst[10];
    for (int idx = tid; idx < NTL*16*64; idx += 256) {
      int p = idx >> 6, d = idx & 63;
      unsigned short val = 0;
      if (d < 60) {
        int gp = p0 + p;
        float t = tf ? tf[gp] : fmaf(step, (float)gp, nearv);
        int i3 = d/20, rem = d%20, l = rem>>1;
        float x = (i3==0)? fmaf(bb0,t,a0) : (i3==1)? fmaf(bb1,t,a1) : fmaf(bb2,t,a2);
        float ang = x * (PI_F * exp2f(2.f*(float)l));
        val = f2b((rem&1)? cosf(ang) : sinf(ang));
      }
      hbuf[p*256 + (((d>>3)^(p&7))<<3) + (d&7)] = val;
    }
  }
  __syncthreads();

  mlp_layer<2,NTL>(Wt, b0, true, hbuf, w, lane, lo, hi);
  #pragma unroll 1
  for (int l = 1; l < 9; ++l)
    mlp_layer<8,NTL>(Wt + (size_t)(2 + (l-1)*8)*8192, bh + (l-1)*256, (l<8), hbuf, w, lane, lo, hi);

  // ---- heads: 4 threads per point, 64 k each; fp32 head weights ----
  if (tid < NTL*64) {
    int p = tid >> 2, s = tid & 3;
    float as_=0.f, a0=0.f, a1=0.f, a2=0.f;
    for (int q=0;q<8;++q) {
      int slot = s*8+q;
      bf16x8 hv = *(const bf16x8*)&hbuf[p*256 + ((slot^(p&7))<<3)];
      #pragma unroll
      for (int j=0;j<8;++j) {
        float hf = b2f((unsigned short)hv[j]);
        int k = s*64 + q*8 + j;
        as_ = fmaf(hf, Wsig[k], as_);
        const float* wc = Wcol + 72 + k*3;
        a0 = fmaf(hf, wc[0], a0);
        a1 = fmaf(hf, wc[1], a1);
        a2 = fmaf(hf, wc[2], a2);
      }
    }
    as_ += __shfl_xor(as_,1); as_ += __shfl_xor(as_,2);
    a0 += __shfl_xor(a0,1); a0 += __shfl_xor(a0,2);
    a1 += __shfl_xor(a1,1); a1 += __shfl_xor(a1,2);
    a2 += __shfl_xor(a2,1); a2 += __shfl_xor(a2,2);
    if (s == 0) {
      sig_out[p0+p] = 1.f/(1.f+expf(-(as_ + bsig[0])));
      col_out[0*npts + p0+p] = 1.f/(1.f+expf(-(a0 + cst[6])));
      col_out[1*npts + p0+p] = 1.f/(1.f+expf(-(a1 + cst[7])));
      col_out[2*npts + p0+p] = 1.f/(1.f+expf(-(a2 + cst[8])));
    }
  }
}

// ---------------- coarse post: cdf scan, C_coarse, inverse-CDF t_fine ----------------
__global__ __launch_bounds__(1024) void k_postco(
    const float* __restrict__ sigco, const float* __restrict__ colco,
    const float* __restrict__ cst, float* __restrict__ tfine, float* __restrict__ outv)
{
  __shared__ float cdf[NC];
  __shared__ float ts[1024];
  __shared__ float r0[16], r1[16], r2[16];
  const int tid = threadIdx.x;
  float v[8], inc[8];
  float run = 0.f;
  #pragma unroll
  for (int j = 0; j < 8; ++j) { v[j] = sigco[tid*8+j]; run += v[j]; inc[j] = run; }
  ts[tid] = run;
  __syncthreads();
  for (int off = 1; off < 1024; off <<= 1) {
    float x = (tid >= off) ? ts[tid-off] : 0.f;
    __syncthreads();
    ts[tid] += x;
    __syncthreads();
  }
  float excl = ts[tid] - run;
  #pragma unroll
  for (int j = 0; j < 8; ++j) cdf[tid*8+j] = excl + inc[j];
  __syncthreads();

  float dco = cst[11];
  float a0=0.f, a1=0.f, a2=0.f;
  #pragma unroll
  for (int j = 0; j < 8; ++j) {
    int i = tid*8+j;
    float T = expf(-dco*(excl+inc[j]));
    float w = T*(1.f-expf(-dco*v[j]));
    a0 += colco[i]*w; a1 += colco[NC+i]*w; a2 += colco[2*NC+i]*w;
  }
  for (int off = 32; off; off >>= 1) {
    a0 += __shfl_down(a0, off); a1 += __shfl_down(a1, off); a2 += __shfl_down(a2, off);
  }
  int wid = tid>>6, lane = tid&63;
  if (lane==0) { r0[wid]=a0; r1[wid]=a1; r2[wid]=a2; }
  __syncthreads();
  if (tid==0) {
    float s0=0,s1=0,s2=0;
    for (int i=0;i<16;++i){s0+=r0[i];s1+=r1[i];s2+=r2[i];}
    outv[0]=s0; outv[1]=s1; outv[2]=s2;
  }

  float cdf0 = cdf[0], cdfN = cdf[NC-1];
  float stepi = (cdfN - cdf0) / (float)(NF+1);
  float nearv = cst[9], dt = cst[10];
  for (int r = 0; r < NF/1024; ++r) {
    int j = tid + r*1024;
    float tv = cdf0 + (float)(j+1)*stepi;
    int lo = 0, hi = NC;
    while (lo < hi) { int mid = (lo+hi)>>1; if (cdf[mid] < tv) lo = mid+1; else hi = mid; }
    int idx = lo-1; idx = idx < 0 ? 0 : (idx > NC-2 ? NC-2 : idx);
    float sig1 = sigco[idx+1];
    tfine[j] = fmaf(dt, (float)idx, nearv) + (tv - cdf[idx]) * (dt / sig1);
  }
}

// ---------------- radix sort: 8 blocks, each sorts a 12288-elem half-array in LDS ----------------
// arrays: a=0..2 color channels, a=3 sigma (concat coarse,fine). positive floats -> uint order.
__global__ __launch_bounds__(1024) void k_radix(
    const float* __restrict__ sigco, const float* __restrict__ colco,
    const float* __restrict__ sigfi, const float* __restrict__ colfi,
    float* __restrict__ rad)
{
  __shared__ unsigned int buf[2][RN];          // 96KB
  __shared__ unsigned int tileh[RTILES][256];  // 12KB
  __shared__ unsigned int tot[256], gb[256];
  __shared__ unsigned int waveh[16][256];      // 16KB
  const int tid = threadIdx.x;
  const int a = blockIdx.x >> 1, hf = blockIdx.x & 1;

  for (int i = tid; i < RN; i += 1024) {
    int g = hf*RN + i;
    float v;
    if (a < 3) v = (g < NC) ? colco[a*NC+g] : colfi[a*NF + (g-NC)];
    else       v = (g < NC) ? sigco[g] : sigfi[g-NC];
    buf[0][i] = __float_as_uint(v);
  }
  __syncthreads();

  int s = 0;
  const int w = tid >> 6, lane = tid & 63;
  for (int p = 0; p < 4; ++p) {
    const int sh = p*8;
    // phase 1: per-tile histograms
    for (int i = tid; i < RTILES*256; i += 1024) ((unsigned int*)tileh)[i] = 0;
    __syncthreads();
    for (int t = 0; t < RTILES; ++t) {
      unsigned int d = (buf[s][t*1024+tid] >> sh) & 255u;
      atomicAdd(&tileh[t][d], 1u);
    }
    __syncthreads();
    // phase 2: scan tiles per digit, then exclusive scan digits
    if (tid < 256) {
      unsigned int run = 0;
      for (int t = 0; t < RTILES; ++t) { unsigned int c = tileh[t][tid]; tileh[t][tid] = run; run += c; }
      tot[tid] = run;
    }
    __syncthreads();
    if (tid < 64) {
      unsigned int t0=tot[tid*4], t1=tot[tid*4+1], t2=tot[tid*4+2], t3=tot[tid*4+3];
      unsigned int ssum = t0+t1+t2+t3;
      unsigned int sc = ssum;
      for (int off=1; off<64; off<<=1) { unsigned int vv = __shfl_up((int)sc, off); if (lane>=off) sc += vv; }
      unsigned int ex = sc - ssum;
      gb[tid*4] = ex; gb[tid*4+1] = ex+t0; gb[tid*4+2] = ex+t0+t1; gb[tid*4+3] = ex+t0+t1+t2;
    }
    __syncthreads();
    if (tid < 256) {
      unsigned int g0 = gb[tid];
      for (int t = 0; t < RTILES; ++t) tileh[t][tid] += g0;
    }
    __syncthreads();
    // phase 3: stable scatter, tile by tile
    for (int t = 0; t < RTILES; ++t) {
      for (int i = tid; i < 16*256; i += 1024) ((unsigned int*)waveh)[i] = 0;
      __syncthreads();
      unsigned int key = buf[s][t*1024+tid];
      unsigned int d = (key >> sh) & 255u;
      unsigned long long m = ~0ull;
      #pragma unroll
      for (int b = 0; b < 8; ++b) {
        unsigned long long bb = __ballot((d >> b) & 1u);
        m &= ((d >> b) & 1u) ? bb : ~bb;
      }
      unsigned int rk = (unsigned int)__popcll(m & ((1ull<<lane)-1ull));
      if (rk == 0) waveh[w][d] = (unsigned int)__popcll(m);
      __syncthreads();
      unsigned int off = tileh[t][d] + rk;
      for (int ww = 0; ww < 16; ++ww) { if (ww >= w) break; off += waveh[ww][d]; }
      buf[s^1][off] = key;
      __syncthreads();
    }
    s ^= 1;
  }
  for (int i = tid; i < RN; i += 1024)
    rad[a*NT + hf*RN + i] = __uint_as_float(buf[s][i]);
}

// ---------------- merge: 5 rows; row0 = t_coarse(analytic) ∪ t_fine; rows1-4 = sorted halves ----------------
__global__ __launch_bounds__(1024) void k_merge(
    const float* __restrict__ rad, const float* __restrict__ tfine,
    const float* __restrict__ cst, float* __restrict__ srt)
{
  const int row = blockIdx.x >> 2, q = blockIdx.x & 3;
  const float dt = cst[10], nv = cst[9];
  const bool isT = (row == 0);
  const float* A = isT ? (const float*)nullptr : rad + (row-1)*NT;
  const float* B = isT ? tfine : (A + RN);
  const int nA = isT ? NC : RN, nB = isT ? NF : RN;
  int k0 = q*6144 + (int)threadIdx.x*6;
  int lo = k0-nB; if (lo < 0) lo = 0;
  int hi = k0 < nA ? k0 : nA;
  while (lo < hi) {
    int mid = (lo+hi)>>1;
    float av = isT ? fmaf(dt,(float)mid,nv) : A[mid];
    if (av <= B[k0-mid-1]) lo = mid+1; else hi = mid;
  }
  int i = lo, j = k0 - lo;
  float* o = srt + row*NT;
  #pragma unroll
  for (int c = 0; c < 6; ++c) {
    float av = (i < nA) ? (isT ? fmaf(dt,(float)i,nv) : A[i]) : 0.f;
    bool ta = (j >= nB) || (i < nA && av <= B[j]);
    float v = ta ? av : B[j];
    if (ta) ++i; else ++j;
    o[k0+c] = v;
  }
}

// ---------------- final: weighted cumsum over sorted bundle ----------------
__global__ __launch_bounds__(1024) void k_final(
    const float* __restrict__ srt, float* __restrict__ outv)
{
  const float* trow = srt;
  const float* c0r = srt + NT;
  const float* c1r = srt + 2*NT;
  const float* c2r = srt + 3*NT;
  const float* sgr = srt + 4*NT;
  __shared__ float ts[1024];
  __shared__ float r0[16], r1[16], r2[16];
  const int tid = threadIdx.x;
  float sd[24], inc[24];
  float run = 0.f;
  int base = tid*24;
  float tprev = trow[base];
  #pragma unroll
  for (int j = 0; j < 24; ++j) {
    int i = base + j;
    float tnext = (i < NT-1) ? trow[i+1] : 0.f;
    float delta = (i == NT-1) ? LASTD : (tnext - tprev);
    sd[j] = delta * sgr[i];
    run += sd[j];
    inc[j] = run;
    tprev = tnext;
  }
  ts[tid] = run; __syncthreads();
  for (int off = 1; off < 1024; off <<= 1) {
    float x = (tid>=off) ? ts[tid-off] : 0.f;
    __syncthreads();
    ts[tid] += x;
    __syncthreads();
  }
  float excl = ts[tid] - run;
  float a0=0.f, a1=0.f, a2=0.f;
  #pragma unroll
  for (int j = 0; j < 24; ++j) {
    int i = base + j;
    float T = expf(-(excl+inc[j]));
    float w = T*(1.f-expf(-sd[j]));
    a0 += c0r[i]*w; a1 += c1r[i]*w; a2 += c2r[i]*w;
  }
  for (int off = 32; off; off >>= 1) {
    a0 += __shfl_down(a0, off); a1 += __shfl_down(a1, off); a2 += __shfl_down(a2, off);
  }
  int wid = tid>>6, lane = tid&63;
  if (lane==0) { r0[wid]=a0; r1[wid]=a1; r2[wid]=a2; }
  __syncthreads();
  if (tid==0) {
    float s0=0,s1=0,s2=0;
    for (int i=0;i<16;++i){s0+=r0[i];s1+=r1[i];s2+=r2[i];}
    outv[3]=s0; outv[4]=s1; outv[5]=s2;
  }
}

extern "C" void kernel_launch(void* const* d_in, const int* in_sizes, int n_in,
                              void* d_out, int out_size, void* d_ws, size_t ws_size,
                              hipStream_t stream) {
  (void)in_sizes; (void)n_in; (void)out_size; (void)ws_size;
  const float* hor  = (const float*)d_in[0];
  const float* ver  = (const float*)d_in[1];
  const float* tm   = (const float*)d_in[2];
  const float* nearp= (const float*)d_in[3];
  const float* farp = (const float*)d_in[4];
  const float* W0   = (const float*)d_in[5];
  const float* b0   = (const float*)d_in[6];
  const float* Wh   = (const float*)d_in[7];
  const float* bh   = (const float*)d_in[8];
  const float* Wsig = (const float*)d_in[9];
  const float* bsig = (const float*)d_in[10];
  const float* Wcol = (const float*)d_in[11];
  const float* bcol = (const float*)d_in[12];
  float* out = (float*)d_out;
  float* ws  = (float*)d_ws;

  float* cst   = ws + WS_CONST;
  float* tfine = ws + WS_TFINE;
  float* sigco = ws + WS_SIGCO;
  float* colco = ws + WS_COLCO;
  float* sigfi = ws + WS_SIGFI;
  float* colfi = ws + WS_COLFI;
  float* srt   = ws + WS_SRT;
  float* rad   = ws + WS_RAD;
  unsigned short* Wt = (unsigned short*)(ws + WS_WT);

  k_prep<<<dim3(1), dim3(64), 0, stream>>>(hor, ver, tm, nearp, farp, Wcol, bcol, cst);
  k_prep_w<<<dim3(528), dim3(256), 0, stream>>>(W0, Wh, Wt);
  k_mlp_mfma<2><<<dim3(NC/32), dim3(256), 0, stream>>>(cst, Wt, b0, bh, Wsig, bsig, Wcol,
                                                       (const float*)nullptr, NC, sigco, colco);
  k_postco<<<dim3(1), dim3(1024), 0, stream>>>(sigco, colco, cst, tfine, out);
  k_mlp_mfma<4><<<dim3(NF/64), dim3(256), 0, stream>>>(cst, Wt, b0, bh, Wsig, bsig, Wcol,
                                                       (const float*)tfine, NF, sigfi, colfi);
  k_radix<<<dim3(8), dim3(1024), 0, stream>>>(sigco, colco, sigfi, colfi, rad);
  k_merge<<<dim3(20), dim3(1024), 0, stream>>>(rad, tfine, cst, srt);
  k_final<<<dim3(1), dim3(1024), 0, stream>>>(srt, out);
}

// Round 4
// 200.065 us; speedup vs baseline: 1.3383x; 1.3383x over previous
//
#include <hip/hip_runtime.h>
#include <math.h>

#define NC 8192
#define NF 16384
#define NT 24576
#define RN 12288
#define LASTD 1e-4f
#define PI_F 3.14159265358979323846f

// ws layout (float offsets)
#define WS_CONST 0
#define WS_TFINE 64
#define WS_SIGCO (WS_TFINE + NF)
#define WS_COLCO (WS_SIGCO + NC)
#define WS_SIGFI (WS_COLCO + 3*NC)
#define WS_COLFI (WS_SIGFI + NF)
#define WS_SRT   (WS_COLFI + 3*NF)
#define WS_RAD   (WS_SRT + 5*NT)
#define WS_WT    (WS_RAD + 4*NT)   // bf16 weights, 66 chunks * 8192 ushort

typedef __attribute__((ext_vector_type(8))) short bf16x8;
typedef __attribute__((ext_vector_type(4))) float f32x4;

static __device__ inline unsigned short f2b(float x){
  union { float f; unsigned int u; } c; c.f = x;
  unsigned int u = c.u;
  return (unsigned short)((u + 0x7fffu + ((u>>16)&1u)) >> 16);
}
static __device__ inline float b2f(unsigned short u){
  union { unsigned int u; float f; } c; c.u = ((unsigned int)u)<<16; return c.f;
}

// ---------------- prep: fold dir encoding into color bias, point affine ----------------
__global__ void k_prep(const float* hor_, const float* ver_, const float* tm,
                       const float* near_, const float* far_,
                       const float* Wcol, const float* bcol, float* cst) {
  if (threadIdx.x != 0) return;
  float hor = hor_[0], ver = ver_[0], nearv = near_[0], farv = far_[0];
  float dw[3];
  for (int j = 0; j < 3; ++j)
    dw[j] = tm[j*4+0]*hor + tm[j*4+1]*ver + tm[j*4+2] + tm[j*4+3];
  float enc[24];
  for (int i = 0; i < 3; ++i)
    for (int l = 0; l < 4; ++l) {
      float f = PI_F * exp2f(2.f*(float)l);
      float ang = dw[i]*f;
      enc[i*8 + l*2]     = sinf(ang);
      enc[i*8 + l*2 + 1] = cosf(ang);
    }
  for (int c = 0; c < 3; ++c) {
    float s = bcol[c];
    for (int d = 0; d < 24; ++d) s += enc[d]*Wcol[d*3+c];
    cst[6+c] = s;
  }
  for (int j = 0; j < 3; ++j) {
    cst[0+j] = tm[j*4+0]*hor + tm[j*4+1]*ver + tm[j*4+3];
    cst[3+j] = tm[j*4+2];
  }
  cst[9]  = nearv;
  cst[10] = (farv - nearv) / (float)(NC - 1);
  cst[11] = (farv - nearv) / (float)NC;
}

// ---------------- prep: weights -> bf16 in A-fragment-linear chunk order ----------------
// chunk c (0..65) -> [mt(16)][lane(64)][j(8)] ushort; chunk = 8192 ushort = 16KB
__global__ __launch_bounds__(256) void k_prep_w(
    const float* __restrict__ W0, const float* __restrict__ Wh,
    unsigned short* __restrict__ Wt)
{
  int base = (blockIdx.x*256 + threadIdx.x)*4;
  for (int e = base; e < base+4; ++e) {
    int c = e >> 13;
    int r = e & 8191;
    int mt = r >> 9;
    int q = r & 511;
    int ln = q >> 3, j = q & 7;
    int out = mt*16 + (ln & 15);
    int kk = (ln >> 4)*8 + j;
    float v;
    if (c < 2) {
      int k = c*32 + kk;
      v = (k < 60) ? W0[k*256 + out] : 0.f;
    } else {
      int m = (c-2) >> 3, kc = (c-2) & 7;
      v = Wh[m*65536 + (kc*32+kk)*256 + out];
    }
    Wt[e] = f2b(v);
  }
}

// ---------------- MFMA MLP: reg-streamed A with depth-2 prefetch, h in LDS ----------------
template<int NCH, int NTL>
__device__ __forceinline__ void mlp_layer(
    const unsigned short* __restrict__ wl, const float* __restrict__ bias, bool relu,
    unsigned short* hbuf, int w, int lane, int lo, int hi)
{
  f32x4 acc[4][NTL];
  const f32x4 z4 = {0.f,0.f,0.f,0.f};
  #pragma unroll
  for (int mi=0;mi<4;++mi)
    #pragma unroll
    for (int ni=0;ni<NTL;++ni) acc[mi][ni] = z4;

  const unsigned short* wlane = wl + w*2048 + lane*8;
  bf16x8 aC[4], bC[NTL];
  #pragma unroll
  for (int mi=0;mi<4;++mi) aC[mi] = *(const bf16x8*)&wlane[mi*512];
  #pragma unroll
  for (int ni=0;ni<NTL;++ni) {
    int p = ni*16 + lo;
    bC[ni] = *(const bf16x8*)&hbuf[p*256 + ((hi^(p&7))<<3)];
  }
  #pragma unroll
  for (int kc = 0; kc < NCH; ++kc) {
    bf16x8 aN[4], bN[NTL];
    if (kc+1 < NCH) {
      #pragma unroll
      for (int mi=0;mi<4;++mi)
        aN[mi] = *(const bf16x8*)&wlane[(kc+1)*8192 + mi*512];
      #pragma unroll
      for (int ni=0;ni<NTL;++ni) {
        int p = ni*16 + lo;
        int slot = (kc+1)*4 + hi;
        bN[ni] = *(const bf16x8*)&hbuf[p*256 + ((slot^(p&7))<<3)];
      }
    }
    #pragma unroll
    for (int mi=0;mi<4;++mi)
      #pragma unroll
      for (int ni=0;ni<NTL;++ni)
        acc[mi][ni] = __builtin_amdgcn_mfma_f32_16x16x32_bf16(aC[mi], bC[ni], acc[mi][ni], 0, 0, 0);
    if (kc+1 < NCH) {
      #pragma unroll
      for (int mi=0;mi<4;++mi) aC[mi] = aN[mi];
      #pragma unroll
      for (int ni=0;ni<NTL;++ni) bC[ni] = bN[ni];
    }
  }
  __syncthreads();   // all waves done READING hbuf (layer input)
  #pragma unroll
  for (int mi=0;mi<4;++mi) {
    int mt = w*4+mi;
    f32x4 bv = *(const f32x4*)&bias[mt*16 + hi*4];
    #pragma unroll
    for (int ni=0;ni<NTL;++ni) {
      f32x4 v = acc[mi][ni];
      float o0=v[0]+bv[0], o1=v[1]+bv[1], o2=v[2]+bv[2], o3=v[3]+bv[3];
      if (relu){o0=fmaxf(o0,0.f);o1=fmaxf(o1,0.f);o2=fmaxf(o2,0.f);o3=fmaxf(o3,0.f);}
      int p = ni*16 + lo;
      int colu = mt*16 + hi*4;
      int slot = colu >> 3, off = colu & 7;
      ushort4 uv = make_ushort4(f2b(o0), f2b(o1), f2b(o2), f2b(o3));
      *(ushort4*)&hbuf[p*256 + ((slot^(p&7))<<3) + off] = uv;
    }
  }
  __syncthreads();   // new h visible
}

template<int NTL>   // points per block = NTL*16
__global__ __launch_bounds__(256) void k_mlp_mfma(
    const float* __restrict__ cst, const unsigned short* __restrict__ Wt,
    const float* __restrict__ b0, const float* __restrict__ bh,
    const float* __restrict__ Wsig, const float* __restrict__ bsig,
    const float* __restrict__ Wcol,
    const float* __restrict__ tf, int npts,
    float* __restrict__ sig_out, float* __restrict__ col_out)
{
  __shared__ __align__(16) unsigned short hbuf[NTL*16*256];
  const int tid = threadIdx.x;
  const int w = tid >> 6, lane = tid & 63;
  const int lo = lane & 15, hi = lane >> 4;
  const int p0 = blockIdx.x * (NTL*16);

  // ---- positional encoding -> hbuf (bf16, swizzled); cols 60..63 zero ----
  {
    float a0=cst[0],a1=cst[1],a2=cst[2];
    float bb0=cst[3],bb1=cst[4],bb2=cst[5];
    float nearv=cst[9], step=cst[10];
    for (int idx = tid; idx < NTL*16*64; idx += 256) {
      int p = idx >> 6, d = idx & 63;
      unsigned short val = 0;
      if (d < 60) {
        int gp = p0 + p;
        float t = tf ? tf[gp] : fmaf(step, (float)gp, nearv);
        int i3 = d/20, rem = d%20, l = rem>>1;
        float x = (i3==0)? fmaf(bb0,t,a0) : (i3==1)? fmaf(bb1,t,a1) : fmaf(bb2,t,a2);
        float ang = x * (PI_F * exp2f(2.f*(float)l));
        val = f2b((rem&1)? cosf(ang) : sinf(ang));
      }
      hbuf[p*256 + (((d>>3)^(p&7))<<3) + (d&7)] = val;
    }
  }
  __syncthreads();

  mlp_layer<2,NTL>(Wt, b0, true, hbuf, w, lane, lo, hi);
  #pragma unroll 1
  for (int l = 1; l < 9; ++l)
    mlp_layer<8,NTL>(Wt + (size_t)(2 + (l-1)*8)*8192, bh + (l-1)*256, (l<8), hbuf, w, lane, lo, hi);

  // ---- heads: 4 threads per point, 64 k each; fp32 head weights ----
  if (tid < NTL*64) {
    int p = tid >> 2, s = tid & 3;
    float as_=0.f, a0=0.f, a1=0.f, a2=0.f;
    for (int q=0;q<8;++q) {
      int slot = s*8+q;
      bf16x8 hv = *(const bf16x8*)&hbuf[p*256 + ((slot^(p&7))<<3)];
      #pragma unroll
      for (int j=0;j<8;++j) {
        float hf = b2f((unsigned short)hv[j]);
        int k = s*64 + q*8 + j;
        as_ = fmaf(hf, Wsig[k], as_);
        const float* wc = Wcol + 72 + k*3;
        a0 = fmaf(hf, wc[0], a0);
        a1 = fmaf(hf, wc[1], a1);
        a2 = fmaf(hf, wc[2], a2);
      }
    }
    as_ += __shfl_xor(as_,1); as_ += __shfl_xor(as_,2);
    a0 += __shfl_xor(a0,1); a0 += __shfl_xor(a0,2);
    a1 += __shfl_xor(a1,1); a1 += __shfl_xor(a1,2);
    a2 += __shfl_xor(a2,1); a2 += __shfl_xor(a2,2);
    if (s == 0) {
      sig_out[p0+p] = 1.f/(1.f+expf(-(as_ + bsig[0])));
      col_out[0*npts + p0+p] = 1.f/(1.f+expf(-(a0 + cst[6])));
      col_out[1*npts + p0+p] = 1.f/(1.f+expf(-(a1 + cst[7])));
      col_out[2*npts + p0+p] = 1.f/(1.f+expf(-(a2 + cst[8])));
    }
  }
}

// ---------------- coarse post: cdf scan, C_coarse, inverse-CDF t_fine ----------------
__global__ __launch_bounds__(1024) void k_postco(
    const float* __restrict__ sigco, const float* __restrict__ colco,
    const float* __restrict__ cst, float* __restrict__ tfine, float* __restrict__ outv)
{
  __shared__ float cdf[NC];
  __shared__ float ts[1024];
  __shared__ float r0[16], r1[16], r2[16];
  const int tid = threadIdx.x;
  float v[8], inc[8];
  float run = 0.f;
  #pragma unroll
  for (int j = 0; j < 8; ++j) { v[j] = sigco[tid*8+j]; run += v[j]; inc[j] = run; }
  ts[tid] = run;
  __syncthreads();
  for (int off = 1; off < 1024; off <<= 1) {
    float x = (tid >= off) ? ts[tid-off] : 0.f;
    __syncthreads();
    ts[tid] += x;
    __syncthreads();
  }
  float excl = ts[tid] - run;
  #pragma unroll
  for (int j = 0; j < 8; ++j) cdf[tid*8+j] = excl + inc[j];
  __syncthreads();

  float dco = cst[11];
  float a0=0.f, a1=0.f, a2=0.f;
  #pragma unroll
  for (int j = 0; j < 8; ++j) {
    int i = tid*8+j;
    float T = expf(-dco*(excl+inc[j]));
    float w = T*(1.f-expf(-dco*v[j]));
    a0 += colco[i]*w; a1 += colco[NC+i]*w; a2 += colco[2*NC+i]*w;
  }
  for (int off = 32; off; off >>= 1) {
    a0 += __shfl_down(a0, off); a1 += __shfl_down(a1, off); a2 += __shfl_down(a2, off);
  }
  int wid = tid>>6, lane = tid&63;
  if (lane==0) { r0[wid]=a0; r1[wid]=a1; r2[wid]=a2; }
  __syncthreads();
  if (tid==0) {
    float s0=0,s1=0,s2=0;
    for (int i=0;i<16;++i){s0+=r0[i];s1+=r1[i];s2+=r2[i];}
    outv[0]=s0; outv[1]=s1; outv[2]=s2;
  }

  // t_fine via inverse CDF: one binary search + monotone walk (contiguous j per thread)
  float cdf0 = cdf[0], cdfN = cdf[NC-1];
  float stepi = (cdfN - cdf0) / (float)(NF+1);
  float nearv = cst[9], dt = cst[10];
  int j0 = tid*16;
  float tv = cdf0 + (float)(j0+1)*stepi;
  int lo = 0, hi = NC;
  while (lo < hi) { int mid = (lo+hi)>>1; if (cdf[mid] < tv) lo = mid+1; else hi = mid; }
  for (int q = 0; q < 16; ++q) {
    int j = j0 + q;
    tv = cdf0 + (float)(j+1)*stepi;
    while (lo < NC && cdf[lo] < tv) ++lo;
    int idx = lo-1; idx = idx < 0 ? 0 : (idx > NC-2 ? NC-2 : idx);
    float sig1 = sigco[idx+1];
    tfine[j] = fmaf(dt, (float)idx, nearv) + (tv - cdf[idx]) * (dt / sig1);
  }
}

// ---------------- radix sort: 8 blocks (4 arrays x 2 halves), keys in regs, in-place scatter ----------------
__global__ __launch_bounds__(1024) void k_radix(
    const float* __restrict__ sigco, const float* __restrict__ colco,
    const float* __restrict__ sigfi, const float* __restrict__ colfi,
    float* __restrict__ rad)
{
  __shared__ unsigned int buf[RN];       // 48KB
  __shared__ unsigned int wh[16][256];   // 16KB
  __shared__ unsigned int tot[256];
  __shared__ unsigned int dbase[256];
  const int tid = threadIdx.x;
  const int w = tid >> 6, lane = tid & 63;
  const int a = blockIdx.x >> 1, hf = blockIdx.x & 1;
  const unsigned long long below = (1ull << lane) - 1ull;

  unsigned int key[12];
  #pragma unroll
  for (int j = 0; j < 12; ++j) {
    int i = w*768 + j*64 + lane;   // enumeration order = storage order
    int g = hf*RN + i;
    float v;
    if (a < 3) v = (g < NC) ? colco[a*NC+g] : colfi[a*NF + (g-NC)];
    else       v = (g < NC) ? sigco[g] : sigfi[g-NC];
    key[j] = __float_as_uint(v);
  }

  for (int p = 0; p < 4; ++p) {
    const int sh = p*8;
    for (int i = tid; i < 16*256; i += 1024) ((unsigned int*)wh)[i] = 0;
    __syncthreads();
    unsigned int lrk[12];
    #pragma unroll
    for (int j = 0; j < 12; ++j) {
      unsigned int d = (key[j] >> sh) & 255u;
      unsigned long long m = ~0ull;
      #pragma unroll
      for (int b = 0; b < 8; ++b) {
        unsigned long long bb = __ballot((d >> b) & 1u);
        m &= ((d >> b) & 1u) ? bb : ~bb;
      }
      unsigned int rkl = (unsigned int)__popcll(m & below);
      unsigned int base = wh[w][d];                       // broadcast within matched group
      if (rkl == 0) wh[w][d] = base + (unsigned int)__popcll(m);  // leader updates running count
      lrk[j] = base + rkl;
    }
    __syncthreads();
    // cross-wave exclusive prefix per digit + totals
    if (tid < 256) {
      unsigned int run2 = 0;
      #pragma unroll
      for (int ww = 0; ww < 16; ++ww) { unsigned int c = wh[ww][tid]; wh[ww][tid] = run2; run2 += c; }
      tot[tid] = run2;
    }
    __syncthreads();
    if (tid < 64) {
      unsigned int t0=tot[tid*4], t1=tot[tid*4+1], t2=tot[tid*4+2], t3=tot[tid*4+3];
      unsigned int ssum = t0+t1+t2+t3;
      unsigned int sc = ssum;
      for (int off=1; off<64; off<<=1) { unsigned int vv = __shfl_up((int)sc, off); if (lane>=off) sc += vv; }
      unsigned int ex = sc - ssum;
      dbase[tid*4] = ex; dbase[tid*4+1] = ex+t0; dbase[tid*4+2] = ex+t0+t1; dbase[tid*4+3] = ex+t0+t1+t2;
    }
    __syncthreads();
    // in-place scatter (all keys in registers; positions are a permutation)
    #pragma unroll
    for (int j = 0; j < 12; ++j) {
      unsigned int d = (key[j] >> sh) & 255u;
      buf[dbase[d] + wh[w][d] + lrk[j]] = key[j];
    }
    __syncthreads();
    if (p < 3) {
      #pragma unroll
      for (int j = 0; j < 12; ++j) key[j] = buf[w*768 + j*64 + lane];
      __syncthreads();
    }
  }
  for (int i = tid; i < RN; i += 1024)
    rad[a*NT + hf*RN + i] = __uint_as_float(buf[i]);
}

// ---------------- merge: 5 rows; row0 = t_coarse(analytic) ∪ t_fine; rows1-4 = sorted halves ----------------
__global__ __launch_bounds__(1024) void k_merge(
    const float* __restrict__ rad, const float* __restrict__ tfine,
    const float* __restrict__ cst, float* __restrict__ srt)
{
  const int row = blockIdx.x >> 2, q = blockIdx.x & 3;
  const float dt = cst[10], nv = cst[9];
  const bool isT = (row == 0);
  const float* A = isT ? (const float*)nullptr : rad + (row-1)*NT;
  const float* B = isT ? tfine : (A + RN);
  const int nA = isT ? NC : RN, nB = isT ? NF : RN;
  int k0 = q*6144 + (int)threadIdx.x*6;
  int lo = k0-nB; if (lo < 0) lo = 0;
  int hi = k0 < nA ? k0 : nA;
  while (lo < hi) {
    int mid = (lo+hi)>>1;
    float av = isT ? fmaf(dt,(float)mid,nv) : A[mid];
    if (av <= B[k0-mid-1]) lo = mid+1; else hi = mid;
  }
  int i = lo, j = k0 - lo;
  float* o = srt + row*NT;
  #pragma unroll
  for (int c = 0; c < 6; ++c) {
    float av = (i < nA) ? (isT ? fmaf(dt,(float)i,nv) : A[i]) : 0.f;
    bool ta = (j >= nB) || (i < nA && av <= B[j]);
    float v = ta ? av : B[j];
    if (ta) ++i; else ++j;
    o[k0+c] = v;
  }
}

// ---------------- final: weighted cumsum over sorted bundle ----------------
__global__ __launch_bounds__(1024) void k_final(
    const float* __restrict__ srt, float* __restrict__ outv)
{
  const float* trow = srt;
  const float* c0r = srt + NT;
  const float* c1r = srt + 2*NT;
  const float* c2r = srt + 3*NT;
  const float* sgr = srt + 4*NT;
  __shared__ float ts[1024];
  __shared__ float r0[16], r1[16], r2[16];
  const int tid = threadIdx.x;
  float sd[24], inc[24];
  float run = 0.f;
  int base = tid*24;
  float tprev = trow[base];
  #pragma unroll
  for (int j = 0; j < 24; ++j) {
    int i = base + j;
    float tnext = (i < NT-1) ? trow[i+1] : 0.f;
    float delta = (i == NT-1) ? LASTD : (tnext - tprev);
    sd[j] = delta * sgr[i];
    run += sd[j];
    inc[j] = run;
    tprev = tnext;
  }
  ts[tid] = run; __syncthreads();
  for (int off = 1; off < 1024; off <<= 1) {
    float x = (tid>=off) ? ts[tid-off] : 0.f;
    __syncthreads();
    ts[tid] += x;
    __syncthreads();
  }
  float excl = ts[tid] - run;
  float a0=0.f, a1=0.f, a2=0.f;
  #pragma unroll
  for (int j = 0; j < 24; ++j) {
    int i = base + j;
    float T = expf(-(excl+inc[j]));
    float w = T*(1.f-expf(-sd[j]));
    a0 += c0r[i]*w; a1 += c1r[i]*w; a2 += c2r[i]*w;
  }
  for (int off = 32; off; off >>= 1) {
    a0 += __shfl_down(a0, off); a1 += __shfl_down(a1, off); a2 += __shfl_down(a2, off);
  }
  int wid = tid>>6, lane = tid&63;
  if (lane==0) { r0[wid]=a0; r1[wid]=a1; r2[wid]=a2; }
  __syncthreads();
  if (tid==0) {
    float s0=0,s1=0,s2=0;
    for (int i=0;i<16;++i){s0+=r0[i];s1+=r1[i];s2+=r2[i];}
    outv[3]=s0; outv[4]=s1; outv[5]=s2;
  }
}

extern "C" void kernel_launch(void* const* d_in, const int* in_sizes, int n_in,
                              void* d_out, int out_size, void* d_ws, size_t ws_size,
                              hipStream_t stream) {
  (void)in_sizes; (void)n_in; (void)out_size; (void)ws_size;
  const float* hor  = (const float*)d_in[0];
  const float* ver  = (const float*)d_in[1];
  const float* tm   = (const float*)d_in[2];
  const float* nearp= (const float*)d_in[3];
  const float* farp = (const float*)d_in[4];
  const float* W0   = (const float*)d_in[5];
  const float* b0   = (const float*)d_in[6];
  const float* Wh   = (const float*)d_in[7];
  const float* bh   = (const float*)d_in[8];
  const float* Wsig = (const float*)d_in[9];
  const float* bsig = (const float*)d_in[10];
  const float* Wcol = (const float*)d_in[11];
  const float* bcol = (const float*)d_in[12];
  float* out = (float*)d_out;
  float* ws  = (float*)d_ws;

  float* cst   = ws + WS_CONST;
  float* tfine = ws + WS_TFINE;
  float* sigco = ws + WS_SIGCO;
  float* colco = ws + WS_COLCO;
  float* sigfi = ws + WS_SIGFI;
  float* colfi = ws + WS_COLFI;
  float* srt   = ws + WS_SRT;
  float* rad   = ws + WS_RAD;
  unsigned short* Wt = (unsigned short*)(ws + WS_WT);

  k_prep<<<dim3(1), dim3(64), 0, stream>>>(hor, ver, tm, nearp, farp, Wcol, bcol, cst);
  k_prep_w<<<dim3(528), dim3(256), 0, stream>>>(W0, Wh, Wt);
  k_mlp_mfma<2><<<dim3(NC/32), dim3(256), 0, stream>>>(cst, Wt, b0, bh, Wsig, bsig, Wcol,
                                                       (const float*)nullptr, NC, sigco, colco);
  k_postco<<<dim3(1), dim3(1024), 0, stream>>>(sigco, colco, cst, tfine, out);
  k_mlp_mfma<2><<<dim3(NF/32), dim3(256), 0, stream>>>(cst, Wt, b0, bh, Wsig, bsig, Wcol,
                                                       (const float*)tfine, NF, sigfi, colfi);
  k_radix<<<dim3(8), dim3(1024), 0, stream>>>(sigco, colco, sigfi, colfi, rad);
  k_merge<<<dim3(20), dim3(1024), 0, stream>>>(rad, tfine, cst, srt);
  k_final<<<dim3(1), dim3(1024), 0, stream>>>(srt, out);
}

// Round 5
// 199.166 us; speedup vs baseline: 1.3444x; 1.0045x over previous
//
#include <hip/hip_runtime.h>
#include <math.h>

#define NC 8192
#define NF 16384
#define NT 24576
#define RN 12288
#define LASTD 1e-4f
#define PI_F 3.14159265358979323846f

// ws layout (float offsets)
#define WS_CONST 0
#define WS_TFINE 64
#define WS_SIGCO (WS_TFINE + NF)
#define WS_COLCO (WS_SIGCO + NC)
#define WS_SIGFI (WS_COLCO + 3*NC)
#define WS_COLFI (WS_SIGFI + NF)
#define WS_SRT   (WS_COLFI + 3*NF)
#define WS_RAD   (WS_SRT + 5*NT)
#define WS_WT    (WS_RAD + 4*NT)   // bf16 weights, 66 chunks * 8192 ushort

typedef __attribute__((ext_vector_type(8))) short bf16x8;
typedef __attribute__((ext_vector_type(4))) float f32x4;

static __device__ inline unsigned short f2b(float x){
  union { float f; unsigned int u; } c; c.f = x;
  unsigned int u = c.u;
  return (unsigned short)((u + 0x7fffu + ((u>>16)&1u)) >> 16);
}
static __device__ inline float b2f(unsigned short u){
  union { unsigned int u; float f; } c; c.u = ((unsigned int)u)<<16; return c.f;
}
__device__ __forceinline__ int swz(int p, int d){
  return (((d>>3)^(p&7))<<3) + (d&7);
}

// ---------------- prep: fold dir encoding into color bias, point affine ----------------
__global__ void k_prep(const float* hor_, const float* ver_, const float* tm,
                       const float* near_, const float* far_,
                       const float* Wcol, const float* bcol, float* cst) {
  if (threadIdx.x != 0) return;
  float hor = hor_[0], ver = ver_[0], nearv = near_[0], farv = far_[0];
  float dw[3];
  for (int j = 0; j < 3; ++j)
    dw[j] = tm[j*4+0]*hor + tm[j*4+1]*ver + tm[j*4+2] + tm[j*4+3];
  float enc[24];
  for (int i = 0; i < 3; ++i)
    for (int l = 0; l < 4; ++l) {
      float f = PI_F * exp2f(2.f*(float)l);
      float ang = dw[i]*f;
      enc[i*8 + l*2]     = sinf(ang);
      enc[i*8 + l*2 + 1] = cosf(ang);
    }
  for (int c = 0; c < 3; ++c) {
    float s = bcol[c];
    for (int d = 0; d < 24; ++d) s += enc[d]*Wcol[d*3+c];
    cst[6+c] = s;
  }
  for (int j = 0; j < 3; ++j) {
    cst[0+j] = tm[j*4+0]*hor + tm[j*4+1]*ver + tm[j*4+3];
    cst[3+j] = tm[j*4+2];
  }
  cst[9]  = nearv;
  cst[10] = (farv - nearv) / (float)(NC - 1);
  cst[11] = (farv - nearv) / (float)NC;
}

// ---------------- prep: weights -> bf16 in A-fragment-linear chunk order ----------------
// chunk c (0..65) -> [mt(16)][lane(64)][j(8)] ushort; chunk = 8192 ushort = 16KB
__global__ __launch_bounds__(256) void k_prep_w(
    const float* __restrict__ W0, const float* __restrict__ Wh,
    unsigned short* __restrict__ Wt)
{
  int base = (blockIdx.x*256 + threadIdx.x)*4;
  for (int e = base; e < base+4; ++e) {
    int c = e >> 13;
    int r = e & 8191;
    int mt = r >> 9;
    int q = r & 511;
    int ln = q >> 3, j = q & 7;
    int out = mt*16 + (ln & 15);
    int kk = (ln >> 4)*8 + j;
    float v;
    if (c < 2) {
      int k = c*32 + kk;
      v = (k < 60) ? W0[k*256 + out] : 0.f;
    } else {
      int m = (c-2) >> 3, kc = (c-2) & 7;
      v = Wh[m*65536 + (kc*32+kk)*256 + out];
    }
    Wt[e] = f2b(v);
  }
}

// ---------------- MFMA MLP: full-layer A preload in VGPRs, h in LDS ----------------
template<int NCH, int NTL>
__device__ __forceinline__ void mlp_layer(
    const unsigned short* __restrict__ wl, const float* __restrict__ bias, bool relu,
    unsigned short* hbuf, int w, int lane, int lo, int hi)
{
  const unsigned short* wlane = wl + w*2048 + lane*8;
  // issue ALL layer A-loads upfront (independent global_load_dwordx4 -> deep MLP)
  bf16x8 aF[NCH][4];
  #pragma unroll
  for (int kc = 0; kc < NCH; ++kc)
    #pragma unroll
    for (int mi = 0; mi < 4; ++mi)
      aF[kc][mi] = *(const bf16x8*)&wlane[kc*8192 + mi*512];

  f32x4 acc[4][NTL];
  const f32x4 z4 = {0.f,0.f,0.f,0.f};
  #pragma unroll
  for (int mi=0;mi<4;++mi)
    #pragma unroll
    for (int ni=0;ni<NTL;++ni) acc[mi][ni] = z4;

  #pragma unroll
  for (int kc = 0; kc < NCH; ++kc) {
    bf16x8 b[NTL];
    #pragma unroll
    for (int ni = 0; ni < NTL; ++ni) {
      int p = ni*16 + lo;
      int slot = kc*4 + hi;
      b[ni] = *(const bf16x8*)&hbuf[p*256 + ((slot^(p&7))<<3)];
    }
    #pragma unroll
    for (int mi=0;mi<4;++mi)
      #pragma unroll
      for (int ni=0;ni<NTL;++ni)
        acc[mi][ni] = __builtin_amdgcn_mfma_f32_16x16x32_bf16(aF[kc][mi], b[ni], acc[mi][ni], 0, 0, 0);
  }
  __syncthreads();   // all waves done READING hbuf (layer input)
  #pragma unroll
  for (int mi=0;mi<4;++mi) {
    int mt = w*4+mi;
    f32x4 bv = *(const f32x4*)&bias[mt*16 + hi*4];
    #pragma unroll
    for (int ni=0;ni<NTL;++ni) {
      f32x4 v = acc[mi][ni];
      float o0=v[0]+bv[0], o1=v[1]+bv[1], o2=v[2]+bv[2], o3=v[3]+bv[3];
      if (relu){o0=fmaxf(o0,0.f);o1=fmaxf(o1,0.f);o2=fmaxf(o2,0.f);o3=fmaxf(o3,0.f);}
      int p = ni*16 + lo;
      int colu = mt*16 + hi*4;
      int slot = colu >> 3, off = colu & 7;
      ushort4 uv = make_ushort4(f2b(o0), f2b(o1), f2b(o2), f2b(o3));
      *(ushort4*)&hbuf[p*256 + ((slot^(p&7))<<3) + off] = uv;
    }
  }
  __syncthreads();   // new h visible
}

template<int NTL>   // points per block = NTL*16
__global__ __launch_bounds__(256, 2) void k_mlp_mfma(
    const float* __restrict__ cst, const unsigned short* __restrict__ Wt,
    const float* __restrict__ b0, const float* __restrict__ bh,
    const float* __restrict__ Wsig, const float* __restrict__ bsig,
    const float* __restrict__ Wcol,
    const float* __restrict__ tf, int npts,
    float* __restrict__ sig_out, float* __restrict__ col_out)
{
  __shared__ __align__(16) unsigned short hbuf[NTL*16*256];
  const int tid = threadIdx.x;
  const int w = tid >> 6, lane = tid & 63;
  const int lo = lane & 15, hi = lane >> 4;
  const int p0 = blockIdx.x * (NTL*16);

  // ---- positional encoding: 1 sincos + double-angle ladder per (point,dim) ----
  if (tid < NTL*16*3) {
    int p = tid / 3, i = tid - p*3;
    int gp = p0 + p;
    float step = cst[10], nearv = cst[9];
    float t = tf ? tf[gp] : fmaf(step, (float)gp, nearv);
    float x = fmaf(cst[3+i], t, cst[0+i]);
    float s, c;
    sincosf(PI_F * x, &s, &c);
    unsigned short* row = &hbuf[p*256];
    #pragma unroll
    for (int l = 0; l < 10; ++l) {
      int d0 = i*20 + l*2;
      row[swz(p, d0)]   = f2b(s);
      row[swz(p, d0+1)] = f2b(c);
      float s2 = 2.f*s*c, c2 = (c-s)*(c+s);
      s = 2.f*s2*c2; c = (c2-s2)*(c2+s2);
    }
    if (i == 0) {
      #pragma unroll
      for (int d = 60; d < 64; ++d) row[swz(p, d)] = 0;
    }
  }
  __syncthreads();

  mlp_layer<2,NTL>(Wt, b0, true, hbuf, w, lane, lo, hi);
  #pragma unroll 1
  for (int l = 1; l < 9; ++l)
    mlp_layer<8,NTL>(Wt + (size_t)(2 + (l-1)*8)*8192, bh + (l-1)*256, (l<8), hbuf, w, lane, lo, hi);

  // ---- heads: 4 threads per point, 64 k each; fp32 head weights ----
  if (tid < NTL*64) {
    int p = tid >> 2, s = tid & 3;
    float as_=0.f, a0=0.f, a1=0.f, a2=0.f;
    for (int q=0;q<8;++q) {
      int slot = s*8+q;
      bf16x8 hv = *(const bf16x8*)&hbuf[p*256 + ((slot^(p&7))<<3)];
      #pragma unroll
      for (int j=0;j<8;++j) {
        float hf = b2f((unsigned short)hv[j]);
        int k = s*64 + q*8 + j;
        as_ = fmaf(hf, Wsig[k], as_);
        const float* wc = Wcol + 72 + k*3;
        a0 = fmaf(hf, wc[0], a0);
        a1 = fmaf(hf, wc[1], a1);
        a2 = fmaf(hf, wc[2], a2);
      }
    }
    as_ += __shfl_xor(as_,1); as_ += __shfl_xor(as_,2);
    a0 += __shfl_xor(a0,1); a0 += __shfl_xor(a0,2);
    a1 += __shfl_xor(a1,1); a1 += __shfl_xor(a1,2);
    a2 += __shfl_xor(a2,1); a2 += __shfl_xor(a2,2);
    if (s == 0) {
      sig_out[p0+p] = 1.f/(1.f+expf(-(as_ + bsig[0])));
      col_out[0*npts + p0+p] = 1.f/(1.f+expf(-(a0 + cst[6])));
      col_out[1*npts + p0+p] = 1.f/(1.f+expf(-(a1 + cst[7])));
      col_out[2*npts + p0+p] = 1.f/(1.f+expf(-(a2 + cst[8])));
    }
  }
}

// ---------------- coarse post: cdf scan (shfl), C_coarse, inverse-CDF t_fine ----------------
__global__ __launch_bounds__(1024) void k_postco(
    const float* __restrict__ sigco, const float* __restrict__ colco,
    const float* __restrict__ cst, float* __restrict__ tfine, float* __restrict__ outv)
{
  __shared__ float cdf[NC];
  __shared__ float wsum[16];
  __shared__ float r0[16], r1[16], r2[16];
  const int tid = threadIdx.x;
  const int lane = tid & 63, wid = tid >> 6;
  float v[8], inc[8];
  float run = 0.f;
  #pragma unroll
  for (int j = 0; j < 8; ++j) { v[j] = sigco[tid*8+j]; run += v[j]; inc[j] = run; }
  float sc = run;
  #pragma unroll
  for (int off = 1; off < 64; off <<= 1) {
    float t = __shfl_up(sc, off);
    if (lane >= off) sc += t;
  }
  if (lane == 63) wsum[wid] = sc;
  __syncthreads();
  if (tid < 16) {
    float wv = wsum[tid];
    float s2 = wv;
    #pragma unroll
    for (int off = 1; off < 16; off <<= 1) {
      float t = __shfl_up(s2, off);
      if (tid >= off) s2 += t;
    }
    wsum[tid] = s2 - wv;
  }
  __syncthreads();
  float excl = wsum[wid] + (sc - run);
  #pragma unroll
  for (int j = 0; j < 8; ++j) cdf[tid*8+j] = excl + inc[j];
  __syncthreads();

  float dco = cst[11];
  float a0=0.f, a1=0.f, a2=0.f;
  #pragma unroll
  for (int j = 0; j < 8; ++j) {
    int i = tid*8+j;
    float T = expf(-dco*(excl+inc[j]));
    float w = T*(1.f-expf(-dco*v[j]));
    a0 += colco[i]*w; a1 += colco[NC+i]*w; a2 += colco[2*NC+i]*w;
  }
  for (int off = 32; off; off >>= 1) {
    a0 += __shfl_down(a0, off); a1 += __shfl_down(a1, off); a2 += __shfl_down(a2, off);
  }
  if (lane==0) { r0[wid]=a0; r1[wid]=a1; r2[wid]=a2; }
  __syncthreads();
  if (tid==0) {
    float s0=0,s1=0,s2=0;
    for (int i=0;i<16;++i){s0+=r0[i];s1+=r1[i];s2+=r2[i];}
    outv[0]=s0; outv[1]=s1; outv[2]=s2;
  }

  // t_fine via inverse CDF: one binary search + monotone walk
  float cdf0 = cdf[0], cdfN = cdf[NC-1];
  float stepi = (cdfN - cdf0) / (float)(NF+1);
  float nearv = cst[9], dt = cst[10];
  int j0 = tid*16;
  float tv = cdf0 + (float)(j0+1)*stepi;
  int lo = 0, hi = NC;
  while (lo < hi) { int mid = (lo+hi)>>1; if (cdf[mid] < tv) lo = mid+1; else hi = mid; }
  for (int q = 0; q < 16; ++q) {
    int j = j0 + q;
    tv = cdf0 + (float)(j+1)*stepi;
    while (lo < NC && cdf[lo] < tv) ++lo;
    int idx = lo-1; idx = idx < 0 ? 0 : (idx > NC-2 ? NC-2 : idx);
    float sig1 = sigco[idx+1];
    tfine[j] = fmaf(dt, (float)idx, nearv) + (tv - cdf[idx]) * (dt / sig1);
  }
}

// ---------------- radix sort: 8 blocks (4 arrays x 2 halves), keys in regs, in-place scatter ----------------
__global__ __launch_bounds__(1024) void k_radix(
    const float* __restrict__ sigco, const float* __restrict__ colco,
    const float* __restrict__ sigfi, const float* __restrict__ colfi,
    float* __restrict__ rad)
{
  __shared__ unsigned int buf[RN];       // 48KB
  __shared__ unsigned int wh[16][256];   // 16KB
  __shared__ unsigned int tot[256];
  __shared__ unsigned int dbase[256];
  const int tid = threadIdx.x;
  const int w = tid >> 6, lane = tid & 63;
  const int a = blockIdx.x >> 1, hf = blockIdx.x & 1;
  const unsigned long long below = (1ull << lane) - 1ull;

  unsigned int key[12];
  #pragma unroll
  for (int j = 0; j < 12; ++j) {
    int i = w*768 + j*64 + lane;   // enumeration order = storage order
    int g = hf*RN + i;
    float v;
    if (a < 3) v = (g < NC) ? colco[a*NC+g] : colfi[a*NF + (g-NC)];
    else       v = (g < NC) ? sigco[g] : sigfi[g-NC];
    key[j] = __float_as_uint(v);
  }

  for (int p = 0; p < 4; ++p) {
    const int sh = p*8;
    for (int i = tid; i < 16*256; i += 1024) ((unsigned int*)wh)[i] = 0;
    __syncthreads();
    unsigned int lrk[12];
    #pragma unroll
    for (int j = 0; j < 12; ++j) {
      unsigned int d = (key[j] >> sh) & 255u;
      unsigned long long m = ~0ull;
      #pragma unroll
      for (int b = 0; b < 8; ++b) {
        unsigned long long bb = __ballot((d >> b) & 1u);
        m &= ((d >> b) & 1u) ? bb : ~bb;
      }
      unsigned int rkl = (unsigned int)__popcll(m & below);
      unsigned int base = wh[w][d];
      if (rkl == 0) wh[w][d] = base + (unsigned int)__popcll(m);
      lrk[j] = base + rkl;
    }
    __syncthreads();
    if (tid < 256) {
      unsigned int run2 = 0;
      #pragma unroll
      for (int ww = 0; ww < 16; ++ww) { unsigned int c = wh[ww][tid]; wh[ww][tid] = run2; run2 += c; }
      tot[tid] = run2;
    }
    __syncthreads();
    if (tid < 64) {
      unsigned int t0=tot[tid*4], t1=tot[tid*4+1], t2=tot[tid*4+2], t3=tot[tid*4+3];
      unsigned int ssum = t0+t1+t2+t3;
      unsigned int sc = ssum;
      for (int off=1; off<64; off<<=1) { unsigned int vv = __shfl_up((int)sc, off); if (lane>=off) sc += vv; }
      unsigned int ex = sc - ssum;
      dbase[tid*4] = ex; dbase[tid*4+1] = ex+t0; dbase[tid*4+2] = ex+t0+t1; dbase[tid*4+3] = ex+t0+t1+t2;
    }
    __syncthreads();
    #pragma unroll
    for (int j = 0; j < 12; ++j) {
      unsigned int d = (key[j] >> sh) & 255u;
      buf[dbase[d] + wh[w][d] + lrk[j]] = key[j];
    }
    __syncthreads();
    if (p < 3) {
      #pragma unroll
      for (int j = 0; j < 12; ++j) key[j] = buf[w*768 + j*64 + lane];
      __syncthreads();
    }
  }
  for (int i = tid; i < RN; i += 1024)
    rad[a*NT + hf*RN + i] = __uint_as_float(buf[i]);
}

// ---------------- merge: 5 rows; row0 = t_coarse(analytic) ∪ t_fine; rows1-4 = sorted halves ----------------
__global__ __launch_bounds__(1024) void k_merge(
    const float* __restrict__ rad, const float* __restrict__ tfine,
    const float* __restrict__ cst, float* __restrict__ srt)
{
  const int row = blockIdx.x >> 2, q = blockIdx.x & 3;
  const float dt = cst[10], nv = cst[9];
  const bool isT = (row == 0);
  const float* A = isT ? (const float*)nullptr : rad + (row-1)*NT;
  const float* B = isT ? tfine : (A + RN);
  const int nA = isT ? NC : RN, nB = isT ? NF : RN;
  int k0 = q*6144 + (int)threadIdx.x*6;
  int lo = k0-nB; if (lo < 0) lo = 0;
  int hi = k0 < nA ? k0 : nA;
  while (lo < hi) {
    int mid = (lo+hi)>>1;
    float av = isT ? fmaf(dt,(float)mid,nv) : A[mid];
    if (av <= B[k0-mid-1]) lo = mid+1; else hi = mid;
  }
  int i = lo, j = k0 - lo;
  float* o = srt + row*NT;
  #pragma unroll
  for (int c = 0; c < 6; ++c) {
    float av = (i < nA) ? (isT ? fmaf(dt,(float)i,nv) : A[i]) : 0.f;
    bool ta = (j >= nB) || (i < nA && av <= B[j]);
    float v = ta ? av : B[j];
    if (ta) ++i; else ++j;
    o[k0+c] = v;
  }
}

// ---------------- final: weighted cumsum over sorted bundle (shfl scan) ----------------
__global__ __launch_bounds__(1024) void k_final(
    const float* __restrict__ srt, float* __restrict__ outv)
{
  const float* trow = srt;
  const float* c0r = srt + NT;
  const float* c1r = srt + 2*NT;
  const float* c2r = srt + 3*NT;
  const float* sgr = srt + 4*NT;
  __shared__ float wsum[16];
  __shared__ float r0[16], r1[16], r2[16];
  const int tid = threadIdx.x;
  const int lane = tid & 63, wid = tid >> 6;
  float sd[24], inc[24];
  float run = 0.f;
  int base = tid*24;
  float tprev = trow[base];
  #pragma unroll
  for (int j = 0; j < 24; ++j) {
    int i = base + j;
    float tnext = (i < NT-1) ? trow[i+1] : 0.f;
    float delta = (i == NT-1) ? LASTD : (tnext - tprev);
    sd[j] = delta * sgr[i];
    run += sd[j];
    inc[j] = run;
    tprev = tnext;
  }
  float sc = run;
  #pragma unroll
  for (int off = 1; off < 64; off <<= 1) {
    float t = __shfl_up(sc, off);
    if (lane >= off) sc += t;
  }
  if (lane == 63) wsum[wid] = sc;
  __syncthreads();
  if (tid < 16) {
    float wv = wsum[tid];
    float s2 = wv;
    #pragma unroll
    for (int off = 1; off < 16; off <<= 1) {
      float t = __shfl_up(s2, off);
      if (tid >= off) s2 += t;
    }
    wsum[tid] = s2 - wv;
  }
  __syncthreads();
  float excl = wsum[wid] + (sc - run);
  float a0=0.f, a1=0.f, a2=0.f;
  #pragma unroll
  for (int j = 0; j < 24; ++j) {
    int i = base + j;
    float T = expf(-(excl+inc[j]));
    float w = T*(1.f-expf(-sd[j]));
    a0 += c0r[i]*w; a1 += c1r[i]*w; a2 += c2r[i]*w;
  }
  for (int off = 32; off; off >>= 1) {
    a0 += __shfl_down(a0, off); a1 += __shfl_down(a1, off); a2 += __shfl_down(a2, off);
  }
  if (lane==0) { r0[wid]=a0; r1[wid]=a1; r2[wid]=a2; }
  __syncthreads();
  if (tid==0) {
    float s0=0,s1=0,s2=0;
    for (int i=0;i<16;++i){s0+=r0[i];s1+=r1[i];s2+=r2[i];}
    outv[3]=s0; outv[4]=s1; outv[5]=s2;
  }
}

extern "C" void kernel_launch(void* const* d_in, const int* in_sizes, int n_in,
                              void* d_out, int out_size, void* d_ws, size_t ws_size,
                              hipStream_t stream) {
  (void)in_sizes; (void)n_in; (void)out_size; (void)ws_size;
  const float* hor  = (const float*)d_in[0];
  const float* ver  = (const float*)d_in[1];
  const float* tm   = (const float*)d_in[2];
  const float* nearp= (const float*)d_in[3];
  const float* farp = (const float*)d_in[4];
  const float* W0   = (const float*)d_in[5];
  const float* b0   = (const float*)d_in[6];
  const float* Wh   = (const float*)d_in[7];
  const float* bh   = (const float*)d_in[8];
  const float* Wsig = (const float*)d_in[9];
  const float* bsig = (const float*)d_in[10];
  const float* Wcol = (const float*)d_in[11];
  const float* bcol = (const float*)d_in[12];
  float* out = (float*)d_out;
  float* ws  = (float*)d_ws;

  float* cst   = ws + WS_CONST;
  float* tfine = ws + WS_TFINE;
  float* sigco = ws + WS_SIGCO;
  float* colco = ws + WS_COLCO;
  float* sigfi = ws + WS_SIGFI;
  float* colfi = ws + WS_COLFI;
  float* srt   = ws + WS_SRT;
  float* rad   = ws + WS_RAD;
  unsigned short* Wt = (unsigned short*)(ws + WS_WT);

  k_prep<<<dim3(1), dim3(64), 0, stream>>>(hor, ver, tm, nearp, farp, Wcol, bcol, cst);
  k_prep_w<<<dim3(528), dim3(256), 0, stream>>>(W0, Wh, Wt);
  k_mlp_mfma<4><<<dim3(NC/64), dim3(256), 0, stream>>>(cst, Wt, b0, bh, Wsig, bsig, Wcol,
                                                       (const float*)nullptr, NC, sigco, colco);
  k_postco<<<dim3(1), dim3(1024), 0, stream>>>(sigco, colco, cst, tfine, out);
  k_mlp_mfma<4><<<dim3(NF/64), dim3(256), 0, stream>>>(cst, Wt, b0, bh, Wsig, bsig, Wcol,
                                                       (const float*)tfine, NF, sigfi, colfi);
  k_radix<<<dim3(8), dim3(1024), 0, stream>>>(sigco, colco, sigfi, colfi, rad);
  k_merge<<<dim3(20), dim3(1024), 0, stream>>>(rad, tfine, cst, srt);
  k_final<<<dim3(1), dim3(1024), 0, stream>>>(srt, out);
}

// Round 6
// 189.991 us; speedup vs baseline: 1.4093x; 1.0483x over previous
//
#include <hip/hip_runtime.h>
#include <math.h>

#define NC 8192
#define NF 16384
#define NT 24576
#define RN 12288
#define LASTD 1e-4f
#define PI_F 3.14159265358979323846f

// ws layout (float offsets)
#define WS_CONST 0
#define WS_TFINE 64
#define WS_SIGCO (WS_TFINE + NF)
#define WS_COLCO (WS_SIGCO + NC)
#define WS_SIGFI (WS_COLCO + 3*NC)
#define WS_COLFI (WS_SIGFI + NF)
#define WS_SRT   (WS_COLFI + 3*NF)
#define WS_RAD   (WS_SRT + 5*NT)
#define WS_WT    (WS_RAD + 4*NT)   // bf16 weights, 66 chunks * 8192 ushort

typedef __attribute__((ext_vector_type(8))) short bf16x8;
typedef __attribute__((ext_vector_type(4))) float f32x4;

static __device__ inline unsigned short f2b(float x){
  union { float f; unsigned int u; } c; c.f = x;
  unsigned int u = c.u;
  return (unsigned short)((u + 0x7fffu + ((u>>16)&1u)) >> 16);
}
static __device__ inline float b2f(unsigned short u){
  union { unsigned int u; float f; } c; c.u = ((unsigned int)u)<<16; return c.f;
}
__device__ __forceinline__ int swz(int p, int d){
  return (((d>>3)^(p&7))<<3) + (d&7);
}

// ---------------- prep: fold dir encoding into color bias, point affine ----------------
__global__ void k_prep(const float* hor_, const float* ver_, const float* tm,
                       const float* near_, const float* far_,
                       const float* Wcol, const float* bcol, float* cst) {
  if (threadIdx.x != 0) return;
  float hor = hor_[0], ver = ver_[0], nearv = near_[0], farv = far_[0];
  float dw[3];
  for (int j = 0; j < 3; ++j)
    dw[j] = tm[j*4+0]*hor + tm[j*4+1]*ver + tm[j*4+2] + tm[j*4+3];
  float enc[24];
  for (int i = 0; i < 3; ++i)
    for (int l = 0; l < 4; ++l) {
      float f = PI_F * exp2f(2.f*(float)l);
      float ang = dw[i]*f;
      enc[i*8 + l*2]     = sinf(ang);
      enc[i*8 + l*2 + 1] = cosf(ang);
    }
  for (int c = 0; c < 3; ++c) {
    float s = bcol[c];
    for (int d = 0; d < 24; ++d) s += enc[d]*Wcol[d*3+c];
    cst[6+c] = s;
  }
  for (int j = 0; j < 3; ++j) {
    cst[0+j] = tm[j*4+0]*hor + tm[j*4+1]*ver + tm[j*4+3];
    cst[3+j] = tm[j*4+2];
  }
  cst[9]  = nearv;
  cst[10] = (farv - nearv) / (float)(NC - 1);
  cst[11] = (farv - nearv) / (float)NC;
}

// ---------------- prep: weights -> bf16 in A-fragment-linear chunk order ----------------
// chunk c (0..65) -> [mt(16)][lane(64)][j(8)] ushort; chunk = 8192 ushort = 16KB
__global__ __launch_bounds__(256) void k_prep_w(
    const float* __restrict__ W0, const float* __restrict__ Wh,
    unsigned short* __restrict__ Wt)
{
  int base = (blockIdx.x*256 + threadIdx.x)*4;
  for (int e = base; e < base+4; ++e) {
    int c = e >> 13;
    int r = e & 8191;
    int mt = r >> 9;
    int q = r & 511;
    int ln = q >> 3, j = q & 7;
    int out = mt*16 + (ln & 15);
    int kk = (ln >> 4)*8 + j;
    float v;
    if (c < 2) {
      int k = c*32 + kk;
      v = (k < 60) ? W0[k*256 + out] : 0.f;
    } else {
      int m = (c-2) >> 3, kc = (c-2) & 7;
      v = Wh[m*65536 + (kc*32+kk)*256 + out];
    }
    Wt[e] = f2b(v);
  }
}

// ---------------- MFMA MLP: async LDS weight pipeline (wave-local, barrier-free granules) ----------------
// 66 chunks = 33 granules of 2 chunks (32KB). Wave w stages & reads only mt range [4w,4w+4).
// Per granule: 8 fire-and-forget global_load_lds -> s_waitcnt vmcnt(8) -> ds_read + MFMA.
template<int NTL>   // points per block = NTL*16
__global__ __launch_bounds__(256, 2) void k_mlp_mfma(
    const float* __restrict__ cst, const unsigned short* __restrict__ Wt,
    const float* __restrict__ b0, const float* __restrict__ bh,
    const float* __restrict__ Wsig, const float* __restrict__ bsig,
    const float* __restrict__ Wcol,
    const float* __restrict__ tf, int npts,
    float* __restrict__ sig_out, float* __restrict__ col_out)
{
  __shared__ __align__(16) unsigned short hbuf[NTL*16*256];
  __shared__ __align__(16) unsigned short wbuf[2][16384];   // 2 x 32KB (2 chunks each)
  const int tid = threadIdx.x;
  const int w = tid >> 6, lane = tid & 63;
  const int lo = lane & 15, hi = lane >> 4;
  const int p0 = blockIdx.x * (NTL*16);

  // ---- positional encoding: 1 sincos + double-angle ladder per (point,dim) ----
  if (tid < NTL*16*3) {
    int p = tid / 3, i = tid - p*3;
    int gp = p0 + p;
    float step = cst[10], nearv = cst[9];
    float t = tf ? tf[gp] : fmaf(step, (float)gp, nearv);
    float x = fmaf(cst[3+i], t, cst[0+i]);
    float s, c;
    sincosf(PI_F * x, &s, &c);
    unsigned short* row = &hbuf[p*256];
    #pragma unroll
    for (int l = 0; l < 10; ++l) {
      int d0 = i*20 + l*2;
      row[swz(p, d0)]   = f2b(s);
      row[swz(p, d0+1)] = f2b(c);
      float s2 = 2.f*s*c, c2 = (c-s)*(c+s);
      s = 2.f*s2*c2; c = (c2-s2)*(c2+s2);
    }
    if (i == 0) {
      #pragma unroll
      for (int d = 60; d < 64; ++d) row[swz(p, d)] = 0;
    }
  }
  __syncthreads();

  // stage granule g into wbuf[b] (wave-local region only)
  auto stage = [&](int g, int b) {
    if (g < 33) {
      const char* src = (const char*)Wt + (size_t)g*32768 + w*4096 + lane*16;
      char* dst = (char*)&wbuf[b][0] + w*4096 + lane*16;
      #pragma unroll
      for (int c2 = 0; c2 < 2; ++c2)
        #pragma unroll
        for (int i = 0; i < 4; ++i)
          __builtin_amdgcn_global_load_lds(
            (const __attribute__((address_space(1))) unsigned int*)(src + c2*16384 + i*1024),
            (__attribute__((address_space(3))) unsigned int*)(dst + c2*16384 + i*1024), 16, 0, 0);
    }
  };

  f32x4 acc[4][NTL];
  const f32x4 z4 = {0.f,0.f,0.f,0.f};
  stage(0, 0);
  int g = 0, buf = 0;
  #pragma unroll 1
  for (int l = 0; l < 9; ++l) {
    const int ngr = (l == 0) ? 1 : 4;
    #pragma unroll
    for (int mi=0;mi<4;++mi)
      #pragma unroll
      for (int ni=0;ni<NTL;++ni) acc[mi][ni] = z4;

    #pragma unroll 1
    for (int gg = 0; gg < ngr; ++gg) {
      stage(g+1, buf^1);
      if (g+1 < 33) { asm volatile("s_waitcnt vmcnt(8)" ::: "memory"); }
      else          { asm volatile("s_waitcnt vmcnt(0)" ::: "memory"); }
      __builtin_amdgcn_sched_barrier(0);
      const unsigned short* wb = &wbuf[buf][0];
      #pragma unroll
      for (int c2 = 0; c2 < 2; ++c2) {
        bf16x8 afr[4], bfr[NTL];
        #pragma unroll
        for (int mi=0;mi<4;++mi)
          afr[mi] = *(const bf16x8*)&wb[c2*8192 + (w*4+mi)*512 + lane*8];
        int slot = (gg*2 + c2)*4 + hi;
        #pragma unroll
        for (int ni=0;ni<NTL;++ni) {
          int p = ni*16 + lo;
          bfr[ni] = *(const bf16x8*)&hbuf[p*256 + ((slot^(p&7))<<3)];
        }
        #pragma unroll
        for (int mi=0;mi<4;++mi)
          #pragma unroll
          for (int ni=0;ni<NTL;++ni)
            acc[mi][ni] = __builtin_amdgcn_mfma_f32_16x16x32_bf16(afr[mi], bfr[ni], acc[mi][ni], 0, 0, 0);
      }
      __builtin_amdgcn_sched_barrier(0);
      buf ^= 1; ++g;
    }

    __builtin_amdgcn_s_barrier();   // all waves done reading hbuf (reads retired: consumed by MFMAs)
    const float* bias = (l==0)? b0 : bh + (l-1)*256;
    const bool relu = (l < 8);
    #pragma unroll
    for (int mi=0;mi<4;++mi) {
      int mt = w*4+mi;
      f32x4 bv = *(const f32x4*)&bias[mt*16 + hi*4];
      #pragma unroll
      for (int ni=0;ni<NTL;++ni) {
        f32x4 v = acc[mi][ni];
        float o0=v[0]+bv[0], o1=v[1]+bv[1], o2=v[2]+bv[2], o3=v[3]+bv[3];
        if (relu){o0=fmaxf(o0,0.f);o1=fmaxf(o1,0.f);o2=fmaxf(o2,0.f);o3=fmaxf(o3,0.f);}
        int p = ni*16 + lo;
        int colu = mt*16 + hi*4;
        int slot = colu >> 3, off = colu & 7;
        ushort4 uv = make_ushort4(f2b(o0), f2b(o1), f2b(o2), f2b(o3));
        *(ushort4*)&hbuf[p*256 + ((slot^(p&7))<<3) + off] = uv;
      }
    }
    asm volatile("s_waitcnt lgkmcnt(0)" ::: "memory");
    __builtin_amdgcn_sched_barrier(0);
    __builtin_amdgcn_s_barrier();   // new h visible
  }

  // ---- heads: 4 threads per point, 64 k each; fp32 head weights ----
  if (tid < NTL*64) {
    int p = tid >> 2, s = tid & 3;
    float as_=0.f, a0=0.f, a1=0.f, a2=0.f;
    for (int q=0;q<8;++q) {
      int slot = s*8+q;
      bf16x8 hv = *(const bf16x8*)&hbuf[p*256 + ((slot^(p&7))<<3)];
      #pragma unroll
      for (int j=0;j<8;++j) {
        float hf = b2f((unsigned short)hv[j]);
        int k = s*64 + q*8 + j;
        as_ = fmaf(hf, Wsig[k], as_);
        const float* wc = Wcol + 72 + k*3;
        a0 = fmaf(hf, wc[0], a0);
        a1 = fmaf(hf, wc[1], a1);
        a2 = fmaf(hf, wc[2], a2);
      }
    }
    as_ += __shfl_xor(as_,1); as_ += __shfl_xor(as_,2);
    a0 += __shfl_xor(a0,1); a0 += __shfl_xor(a0,2);
    a1 += __shfl_xor(a1,1); a1 += __shfl_xor(a1,2);
    a2 += __shfl_xor(a2,1); a2 += __shfl_xor(a2,2);
    if (s == 0) {
      sig_out[p0+p] = 1.f/(1.f+expf(-(as_ + bsig[0])));
      col_out[0*npts + p0+p] = 1.f/(1.f+expf(-(a0 + cst[6])));
      col_out[1*npts + p0+p] = 1.f/(1.f+expf(-(a1 + cst[7])));
      col_out[2*npts + p0+p] = 1.f/(1.f+expf(-(a2 + cst[8])));
    }
  }
}

// ---------------- coarse post: cdf scan (shfl), C_coarse, inverse-CDF t_fine ----------------
__global__ __launch_bounds__(1024) void k_postco(
    const float* __restrict__ sigco, const float* __restrict__ colco,
    const float* __restrict__ cst, float* __restrict__ tfine, float* __restrict__ outv)
{
  __shared__ float cdf[NC];
  __shared__ float wsum[16];
  __shared__ float r0[16], r1[16], r2[16];
  const int tid = threadIdx.x;
  const int lane = tid & 63, wid = tid >> 6;
  float v[8], inc[8];
  float run = 0.f;
  #pragma unroll
  for (int j = 0; j < 8; ++j) { v[j] = sigco[tid*8+j]; run += v[j]; inc[j] = run; }
  float sc = run;
  #pragma unroll
  for (int off = 1; off < 64; off <<= 1) {
    float t = __shfl_up(sc, off);
    if (lane >= off) sc += t;
  }
  if (lane == 63) wsum[wid] = sc;
  __syncthreads();
  if (tid < 16) {
    float wv = wsum[tid];
    float s2 = wv;
    #pragma unroll
    for (int off = 1; off < 16; off <<= 1) {
      float t = __shfl_up(s2, off);
      if (tid >= off) s2 += t;
    }
    wsum[tid] = s2 - wv;
  }
  __syncthreads();
  float excl = wsum[wid] + (sc - run);
  #pragma unroll
  for (int j = 0; j < 8; ++j) cdf[tid*8+j] = excl + inc[j];
  __syncthreads();

  float dco = cst[11];
  float a0=0.f, a1=0.f, a2=0.f;
  #pragma unroll
  for (int j = 0; j < 8; ++j) {
    int i = tid*8+j;
    float T = expf(-dco*(excl+inc[j]));
    float w = T*(1.f-expf(-dco*v[j]));
    a0 += colco[i]*w; a1 += colco[NC+i]*w; a2 += colco[2*NC+i]*w;
  }
  for (int off = 32; off; off >>= 1) {
    a0 += __shfl_down(a0, off); a1 += __shfl_down(a1, off); a2 += __shfl_down(a2, off);
  }
  if (lane==0) { r0[wid]=a0; r1[wid]=a1; r2[wid]=a2; }
  __syncthreads();
  if (tid==0) {
    float s0=0,s1=0,s2=0;
    for (int i=0;i<16;++i){s0+=r0[i];s1+=r1[i];s2+=r2[i];}
    outv[0]=s0; outv[1]=s1; outv[2]=s2;
  }

  // t_fine via inverse CDF: one binary search + monotone walk
  float cdf0 = cdf[0], cdfN = cdf[NC-1];
  float stepi = (cdfN - cdf0) / (float)(NF+1);
  float nearv = cst[9], dt = cst[10];
  int j0 = tid*16;
  float tv = cdf0 + (float)(j0+1)*stepi;
  int lo = 0, hi = NC;
  while (lo < hi) { int mid = (lo+hi)>>1; if (cdf[mid] < tv) lo = mid+1; else hi = mid; }
  for (int q = 0; q < 16; ++q) {
    int j = j0 + q;
    tv = cdf0 + (float)(j+1)*stepi;
    while (lo < NC && cdf[lo] < tv) ++lo;
    int idx = lo-1; idx = idx < 0 ? 0 : (idx > NC-2 ? NC-2 : idx);
    float sig1 = sigco[idx+1];
    tfine[j] = fmaf(dt, (float)idx, nearv) + (tv - cdf[idx]) * (dt / sig1);
  }
}

// ---------------- radix sort: 8 blocks (4 arrays x 2 halves), keys in regs, in-place scatter ----------------
__global__ __launch_bounds__(1024) void k_radix(
    const float* __restrict__ sigco, const float* __restrict__ colco,
    const float* __restrict__ sigfi, const float* __restrict__ colfi,
    float* __restrict__ rad)
{
  __shared__ unsigned int buf[RN];       // 48KB
  __shared__ unsigned int wh[16][256];   // 16KB
  __shared__ unsigned int tot[256];
  __shared__ unsigned int dbase[256];
  const int tid = threadIdx.x;
  const int w = tid >> 6, lane = tid & 63;
  const int a = blockIdx.x >> 1, hf = blockIdx.x & 1;
  const unsigned long long below = (1ull << lane) - 1ull;

  unsigned int key[12];
  #pragma unroll
  for (int j = 0; j < 12; ++j) {
    int i = w*768 + j*64 + lane;   // enumeration order = storage order
    int g = hf*RN + i;
    float v;
    if (a < 3) v = (g < NC) ? colco[a*NC+g] : colfi[a*NF + (g-NC)];
    else       v = (g < NC) ? sigco[g] : sigfi[g-NC];
    key[j] = __float_as_uint(v);
  }

  for (int p = 0; p < 4; ++p) {
    const int sh = p*8;
    for (int i = tid; i < 16*256; i += 1024) ((unsigned int*)wh)[i] = 0;
    __syncthreads();
    unsigned int lrk[12];
    #pragma unroll
    for (int j = 0; j < 12; ++j) {
      unsigned int d = (key[j] >> sh) & 255u;
      unsigned long long m = ~0ull;
      #pragma unroll
      for (int b = 0; b < 8; ++b) {
        unsigned long long bb = __ballot((d >> b) & 1u);
        m &= ((d >> b) & 1u) ? bb : ~bb;
      }
      unsigned int rkl = (unsigned int)__popcll(m & below);
      unsigned int base = wh[w][d];
      if (rkl == 0) wh[w][d] = base + (unsigned int)__popcll(m);
      lrk[j] = base + rkl;
    }
    __syncthreads();
    if (tid < 256) {
      unsigned int run2 = 0;
      #pragma unroll
      for (int ww = 0; ww < 16; ++ww) { unsigned int c = wh[ww][tid]; wh[ww][tid] = run2; run2 += c; }
      tot[tid] = run2;
    }
    __syncthreads();
    if (tid < 64) {
      unsigned int t0=tot[tid*4], t1=tot[tid*4+1], t2=tot[tid*4+2], t3=tot[tid*4+3];
      unsigned int ssum = t0+t1+t2+t3;
      unsigned int sc = ssum;
      for (int off=1; off<64; off<<=1) { unsigned int vv = __shfl_up((int)sc, off); if (lane>=off) sc += vv; }
      unsigned int ex = sc - ssum;
      dbase[tid*4] = ex; dbase[tid*4+1] = ex+t0; dbase[tid*4+2] = ex+t0+t1; dbase[tid*4+3] = ex+t0+t1+t2;
    }
    __syncthreads();
    #pragma unroll
    for (int j = 0; j < 12; ++j) {
      unsigned int d = (key[j] >> sh) & 255u;
      buf[dbase[d] + wh[w][d] + lrk[j]] = key[j];
    }
    __syncthreads();
    if (p < 3) {
      #pragma unroll
      for (int j = 0; j < 12; ++j) key[j] = buf[w*768 + j*64 + lane];
      __syncthreads();
    }
  }
  for (int i = tid; i < RN; i += 1024)
    rad[a*NT + hf*RN + i] = __uint_as_float(buf[i]);
}

// ---------------- merge: 5 rows; row0 = t_coarse(analytic) ∪ t_fine; rows1-4 = sorted halves ----------------
__global__ __launch_bounds__(1024) void k_merge(
    const float* __restrict__ rad, const float* __restrict__ tfine,
    const float* __restrict__ cst, float* __restrict__ srt)
{
  const int row = blockIdx.x >> 2, q = blockIdx.x & 3;
  const float dt = cst[10], nv = cst[9];
  const bool isT = (row == 0);
  const float* A = isT ? (const float*)nullptr : rad + (row-1)*NT;
  const float* B = isT ? tfine : (A + RN);
  const int nA = isT ? NC : RN, nB = isT ? NF : RN;
  int k0 = q*6144 + (int)threadIdx.x*6;
  int lo = k0-nB; if (lo < 0) lo = 0;
  int hi = k0 < nA ? k0 : nA;
  while (lo < hi) {
    int mid = (lo+hi)>>1;
    float av = isT ? fmaf(dt,(float)mid,nv) : A[mid];
    if (av <= B[k0-mid-1]) lo = mid+1; else hi = mid;
  }
  int i = lo, j = k0 - lo;
  float* o = srt + row*NT;
  #pragma unroll
  for (int c = 0; c < 6; ++c) {
    float av = (i < nA) ? (isT ? fmaf(dt,(float)i,nv) : A[i]) : 0.f;
    bool ta = (j >= nB) || (i < nA && av <= B[j]);
    float v = ta ? av : B[j];
    if (ta) ++i; else ++j;
    o[k0+c] = v;
  }
}

// ---------------- final: weighted cumsum over sorted bundle (shfl scan) ----------------
__global__ __launch_bounds__(1024) void k_final(
    const float* __restrict__ srt, float* __restrict__ outv)
{
  const float* trow = srt;
  const float* c0r = srt + NT;
  const float* c1r = srt + 2*NT;
  const float* c2r = srt + 3*NT;
  const float* sgr = srt + 4*NT;
  __shared__ float wsum[16];
  __shared__ float r0[16], r1[16], r2[16];
  const int tid = threadIdx.x;
  const int lane = tid & 63, wid = tid >> 6;
  float sd[24], inc[24];
  float run = 0.f;
  int base = tid*24;
  float tprev = trow[base];
  #pragma unroll
  for (int j = 0; j < 24; ++j) {
    int i = base + j;
    float tnext = (i < NT-1) ? trow[i+1] : 0.f;
    float delta = (i == NT-1) ? LASTD : (tnext - tprev);
    sd[j] = delta * sgr[i];
    run += sd[j];
    inc[j] = run;
    tprev = tnext;
  }
  float sc = run;
  #pragma unroll
  for (int off = 1; off < 64; off <<= 1) {
    float t = __shfl_up(sc, off);
    if (lane >= off) sc += t;
  }
  if (lane == 63) wsum[wid] = sc;
  __syncthreads();
  if (tid < 16) {
    float wv = wsum[tid];
    float s2 = wv;
    #pragma unroll
    for (int off = 1; off < 16; off <<= 1) {
      float t = __shfl_up(s2, off);
      if (tid >= off) s2 += t;
    }
    wsum[tid] = s2 - wv;
  }
  __syncthreads();
  float excl = wsum[wid] + (sc - run);
  float a0=0.f, a1=0.f, a2=0.f;
  #pragma unroll
  for (int j = 0; j < 24; ++j) {
    int i = base + j;
    float T = expf(-(excl+inc[j]));
    float w = T*(1.f-expf(-sd[j]));
    a0 += c0r[i]*w; a1 += c1r[i]*w; a2 += c2r[i]*w;
  }
  for (int off = 32; off; off >>= 1) {
    a0 += __shfl_down(a0, off); a1 += __shfl_down(a1, off); a2 += __shfl_down(a2, off);
  }
  if (lane==0) { r0[wid]=a0; r1[wid]=a1; r2[wid]=a2; }
  __syncthreads();
  if (tid==0) {
    float s0=0,s1=0,s2=0;
    for (int i=0;i<16;++i){s0+=r0[i];s1+=r1[i];s2+=r2[i];}
    outv[3]=s0; outv[4]=s1; outv[5]=s2;
  }
}

extern "C" void kernel_launch(void* const* d_in, const int* in_sizes, int n_in,
                              void* d_out, int out_size, void* d_ws, size_t ws_size,
                              hipStream_t stream) {
  (void)in_sizes; (void)n_in; (void)out_size; (void)ws_size;
  const float* hor  = (const float*)d_in[0];
  const float* ver  = (const float*)d_in[1];
  const float* tm   = (const float*)d_in[2];
  const float* nearp= (const float*)d_in[3];
  const float* farp = (const float*)d_in[4];
  const float* W0   = (const float*)d_in[5];
  const float* b0   = (const float*)d_in[6];
  const float* Wh   = (const float*)d_in[7];
  const float* bh   = (const float*)d_in[8];
  const float* Wsig = (const float*)d_in[9];
  const float* bsig = (const float*)d_in[10];
  const float* Wcol = (const float*)d_in[11];
  const float* bcol = (const float*)d_in[12];
  float* out = (float*)d_out;
  float* ws  = (float*)d_ws;

  float* cst   = ws + WS_CONST;
  float* tfine = ws + WS_TFINE;
  float* sigco = ws + WS_SIGCO;
  float* colco = ws + WS_COLCO;
  float* sigfi = ws + WS_SIGFI;
  float* colfi = ws + WS_COLFI;
  float* srt   = ws + WS_SRT;
  float* rad   = ws + WS_RAD;
  unsigned short* Wt = (unsigned short*)(ws + WS_WT);

  k_prep<<<dim3(1), dim3(64), 0, stream>>>(hor, ver, tm, nearp, farp, Wcol, bcol, cst);
  k_prep_w<<<dim3(528), dim3(256), 0, stream>>>(W0, Wh, Wt);
  k_mlp_mfma<2><<<dim3(NC/32), dim3(256), 0, stream>>>(cst, Wt, b0, bh, Wsig, bsig, Wcol,
                                                       (const float*)nullptr, NC, sigco, colco);
  k_postco<<<dim3(1), dim3(1024), 0, stream>>>(sigco, colco, cst, tfine, out);
  k_mlp_mfma<4><<<dim3(NF/64), dim3(256), 0, stream>>>(cst, Wt, b0, bh, Wsig, bsig, Wcol,
                                                       (const float*)tfine, NF, sigfi, colfi);
  k_radix<<<dim3(8), dim3(1024), 0, stream>>>(sigco, colco, sigfi, colfi, rad);
  k_merge<<<dim3(20), dim3(1024), 0, stream>>>(rad, tfine, cst, srt);
  k_final<<<dim3(1), dim3(1024), 0, stream>>>(srt, out);
}

// Round 7
// 187.055 us; speedup vs baseline: 1.4314x; 1.0157x over previous
//
#include <hip/hip_runtime.h>
#include <math.h>

#define NC 8192
#define NF 16384
#define NT 24576
#define RN 12288
#define LASTD 1e-4f
#define PI_F 3.14159265358979323846f

// ws layout (float offsets)
#define WS_CONST 0
#define WS_TFINE 64
#define WS_SIGCO (WS_TFINE + NF)
#define WS_COLCO (WS_SIGCO + NC)
#define WS_SIGFI (WS_COLCO + 3*NC)
#define WS_COLFI (WS_SIGFI + NF)
#define WS_SRT   (WS_COLFI + 3*NF)
#define WS_RAD   (WS_SRT + 5*NT)
#define WS_WT    (WS_RAD + 4*NT)   // bf16 weights, 66 chunks * 8192 ushort

typedef __attribute__((ext_vector_type(8))) short bf16x8;
typedef __attribute__((ext_vector_type(4))) float f32x4;

static __device__ inline unsigned short f2b(float x){
  union { float f; unsigned int u; } c; c.f = x;
  unsigned int u = c.u;
  return (unsigned short)((u + 0x7fffu + ((u>>16)&1u)) >> 16);
}
static __device__ inline float b2f(unsigned short u){
  union { unsigned int u; float f; } c; c.u = ((unsigned int)u)<<16; return c.f;
}
__device__ __forceinline__ int swz(int p, int d){
  return (((d>>3)^(p&7))<<3) + (d&7);
}

// ---------------- prep: weights -> bf16 chunks; block 528 does scalar prep ----------------
// chunk c (0..65) -> [mt(16)][lane(64)][j(8)] ushort; chunk = 8192 ushort = 16KB
__global__ __launch_bounds__(256) void k_prep_w(
    const float* __restrict__ W0, const float* __restrict__ Wh,
    unsigned short* __restrict__ Wt,
    const float* hor_, const float* ver_, const float* tm,
    const float* near_, const float* far_,
    const float* Wcol, const float* bcol, float* cst)
{
  if (blockIdx.x == 528) {
    if (threadIdx.x != 0) return;
    float hor = hor_[0], ver = ver_[0], nearv = near_[0], farv = far_[0];
    float dw[3];
    for (int j = 0; j < 3; ++j)
      dw[j] = tm[j*4+0]*hor + tm[j*4+1]*ver + tm[j*4+2] + tm[j*4+3];
    float enc[24];
    for (int i = 0; i < 3; ++i)
      for (int l = 0; l < 4; ++l) {
        float f = PI_F * exp2f(2.f*(float)l);
        float ang = dw[i]*f;
        enc[i*8 + l*2]     = sinf(ang);
        enc[i*8 + l*2 + 1] = cosf(ang);
      }
    for (int c = 0; c < 3; ++c) {
      float s = bcol[c];
      for (int d = 0; d < 24; ++d) s += enc[d]*Wcol[d*3+c];
      cst[6+c] = s;
    }
    for (int j = 0; j < 3; ++j) {
      cst[0+j] = tm[j*4+0]*hor + tm[j*4+1]*ver + tm[j*4+3];
      cst[3+j] = tm[j*4+2];
    }
    cst[9]  = nearv;
    cst[10] = (farv - nearv) / (float)(NC - 1);
    cst[11] = (farv - nearv) / (float)NC;
    return;
  }
  int base = (blockIdx.x*256 + threadIdx.x)*4;
  for (int e = base; e < base+4; ++e) {
    int c = e >> 13;
    if (c >= 66) break;
    int r = e & 8191;
    int mt = r >> 9;
    int q = r & 511;
    int ln = q >> 3, j = q & 7;
    int out = mt*16 + (ln & 15);
    int kk = (ln >> 4)*8 + j;
    float v;
    if (c < 2) {
      int k = c*32 + kk;
      v = (k < 60) ? W0[k*256 + out] : 0.f;
    } else {
      int m = (c-2) >> 3, kc = (c-2) & 7;
      v = Wh[m*65536 + (kc*32+kk)*256 + out];
    }
    Wt[e] = f2b(v);
  }
}

// ---------------- MFMA MLP: depth-3 async chunk pipeline, 2 blocks/CU ----------------
// 66 chunks streamed continuously across layers; wave w stages/reads mt range [4w,4w+4).
// Per chunk: stage c+3 (4 fire-and-forget gl_lds) -> vmcnt(12) -> 6 ds_read_b128 -> 8*NTL MFMA.
template<int NTL>   // points per block = NTL*16
__global__ __launch_bounds__(256, 2) void k_mlp_mfma(
    const float* __restrict__ cst, const unsigned short* __restrict__ Wt,
    const float* __restrict__ b0, const float* __restrict__ bh,
    const float* __restrict__ Wsig, const float* __restrict__ bsig,
    const float* __restrict__ Wcol,
    const float* __restrict__ tf, int npts,
    float* __restrict__ sig_out, float* __restrict__ col_out)
{
  __shared__ __align__(16) unsigned short hbuf[NTL*16*256];   // NTL*8 KB
  __shared__ __align__(16) unsigned short wbuf[4][8192];      // 4 x 16KB ring
  const int tid = threadIdx.x;
  const int w = tid >> 6, lane = tid & 63;
  const int lo = lane & 15, hi = lane >> 4;
  const int p0 = blockIdx.x * (NTL*16);

  // stage chunk c into ring slot c&3 (wave-local 4KB region, no barriers needed)
  auto stage = [&](int c) {
    if (c < 66) {
      const char* src = (const char*)Wt + (size_t)c*16384 + w*4096 + lane*16;
      char* dst = (char*)&wbuf[c & 3][0] + w*4096 + lane*16;
      #pragma unroll
      for (int i = 0; i < 4; ++i)
        __builtin_amdgcn_global_load_lds(
          (const __attribute__((address_space(1))) unsigned int*)(src + i*1024),
          (__attribute__((address_space(3))) unsigned int*)(dst + i*1024), 16, 0, 0);
    }
  };

  // prologue: get 3 chunks in flight before doing anything else
  stage(0); stage(1); stage(2);

  // ---- positional encoding (overlaps prologue loads): 1 sincos + double-angle ladder ----
  if (tid < NTL*16*3) {
    int p = tid / 3, i = tid - p*3;
    int gp = p0 + p;
    float step = cst[10], nearv = cst[9];
    float t = tf ? tf[gp] : fmaf(step, (float)gp, nearv);
    float x = fmaf(cst[3+i], t, cst[0+i]);
    float s, c;
    sincosf(PI_F * x, &s, &c);
    unsigned short* row = &hbuf[p*256];
    #pragma unroll
    for (int l = 0; l < 10; ++l) {
      int d0 = i*20 + l*2;
      row[swz(p, d0)]   = f2b(s);
      row[swz(p, d0+1)] = f2b(c);
      float s2 = 2.f*s*c, c2 = (c-s)*(c+s);
      s = 2.f*s2*c2; c = (c2-s2)*(c2+s2);
    }
    if (i == 0) {
      #pragma unroll
      for (int d = 60; d < 64; ++d) row[swz(p, d)] = 0;
    }
  }
  asm volatile("s_waitcnt lgkmcnt(0)" ::: "memory");
  __builtin_amdgcn_sched_barrier(0);
  __builtin_amdgcn_s_barrier();   // hbuf encoding visible (vmcnt prefetch stays in flight)

  f32x4 acc[4][NTL];
  const f32x4 z4 = {0.f,0.f,0.f,0.f};
  int c = 0;
  #pragma unroll 1
  for (int l = 0; l < 9; ++l) {
    const int nch = (l == 0) ? 2 : 8;
    #pragma unroll
    for (int mi=0;mi<4;++mi)
      #pragma unroll
      for (int ni=0;ni<NTL;++ni) acc[mi][ni] = z4;

    #pragma unroll 1
    for (int k = 0; k < nch; ++k, ++c) {
      stage(c+3);
      {
        int rem = 65 - c;   // chunks (newer than c) still in flight after this stage
        if (rem >= 3)      asm volatile("s_waitcnt vmcnt(12)" ::: "memory");
        else if (rem == 2) asm volatile("s_waitcnt vmcnt(8)"  ::: "memory");
        else if (rem == 1) asm volatile("s_waitcnt vmcnt(4)"  ::: "memory");
        else               asm volatile("s_waitcnt vmcnt(0)"  ::: "memory");
      }
      __builtin_amdgcn_sched_barrier(0);
      const unsigned short* wb = &wbuf[c & 3][0];
      bf16x8 afr[4], bfr[NTL];
      #pragma unroll
      for (int mi=0;mi<4;++mi)
        afr[mi] = *(const bf16x8*)&wb[(w*4+mi)*512 + lane*8];
      int slot = k*4 + hi;
      #pragma unroll
      for (int ni=0;ni<NTL;++ni) {
        int p = ni*16 + lo;
        bfr[ni] = *(const bf16x8*)&hbuf[p*256 + ((slot^(p&7))<<3)];
      }
      #pragma unroll
      for (int mi=0;mi<4;++mi)
        #pragma unroll
        for (int ni=0;ni<NTL;++ni)
          acc[mi][ni] = __builtin_amdgcn_mfma_f32_16x16x32_bf16(afr[mi], bfr[ni], acc[mi][ni], 0, 0, 0);
      __builtin_amdgcn_sched_barrier(0);
    }

    __builtin_amdgcn_s_barrier();   // all waves done reading hbuf (layer input consumed)
    const float* bias = (l==0)? b0 : bh + (l-1)*256;
    const bool relu = (l < 8);
    #pragma unroll
    for (int mi=0;mi<4;++mi) {
      int mt = w*4+mi;
      f32x4 bv = *(const f32x4*)&bias[mt*16 + hi*4];
      #pragma unroll
      for (int ni=0;ni<NTL;++ni) {
        f32x4 v = acc[mi][ni];
        float o0=v[0]+bv[0], o1=v[1]+bv[1], o2=v[2]+bv[2], o3=v[3]+bv[3];
        if (relu){o0=fmaxf(o0,0.f);o1=fmaxf(o1,0.f);o2=fmaxf(o2,0.f);o3=fmaxf(o3,0.f);}
        int p = ni*16 + lo;
        int colu = mt*16 + hi*4;
        int slot2 = colu >> 3, off = colu & 7;
        ushort4 uv = make_ushort4(f2b(o0), f2b(o1), f2b(o2), f2b(o3));
        *(ushort4*)&hbuf[p*256 + ((slot2^(p&7))<<3) + off] = uv;
      }
    }
    asm volatile("s_waitcnt lgkmcnt(0)" ::: "memory");
    __builtin_amdgcn_sched_barrier(0);
    __builtin_amdgcn_s_barrier();   // new h visible
  }

  // ---- heads: 4 threads per point, 64 k each; fp32 head weights ----
  if (tid < NTL*64) {
    int p = tid >> 2, s = tid & 3;
    float as_=0.f, a0=0.f, a1=0.f, a2=0.f;
    for (int q=0;q<8;++q) {
      int slot = s*8+q;
      bf16x8 hv = *(const bf16x8*)&hbuf[p*256 + ((slot^(p&7))<<3)];
      #pragma unroll
      for (int j=0;j<8;++j) {
        float hf = b2f((unsigned short)hv[j]);
        int k = s*64 + q*8 + j;
        as_ = fmaf(hf, Wsig[k], as_);
        const float* wc = Wcol + 72 + k*3;
        a0 = fmaf(hf, wc[0], a0);
        a1 = fmaf(hf, wc[1], a1);
        a2 = fmaf(hf, wc[2], a2);
      }
    }
    as_ += __shfl_xor(as_,1); as_ += __shfl_xor(as_,2);
    a0 += __shfl_xor(a0,1); a0 += __shfl_xor(a0,2);
    a1 += __shfl_xor(a1,1); a1 += __shfl_xor(a1,2);
    a2 += __shfl_xor(a2,1); a2 += __shfl_xor(a2,2);
    if (s == 0) {
      sig_out[p0+p] = 1.f/(1.f+expf(-(as_ + bsig[0])));
      col_out[0*npts + p0+p] = 1.f/(1.f+expf(-(a0 + cst[6])));
      col_out[1*npts + p0+p] = 1.f/(1.f+expf(-(a1 + cst[7])));
      col_out[2*npts + p0+p] = 1.f/(1.f+expf(-(a2 + cst[8])));
    }
  }
}

// ---------------- coarse post: cdf scan (shfl), C_coarse, inverse-CDF t_fine ----------------
__global__ __launch_bounds__(1024) void k_postco(
    const float* __restrict__ sigco, const float* __restrict__ colco,
    const float* __restrict__ cst, float* __restrict__ tfine, float* __restrict__ outv)
{
  __shared__ float cdf[NC];
  __shared__ float wsum[16];
  __shared__ float r0[16], r1[16], r2[16];
  const int tid = threadIdx.x;
  const int lane = tid & 63, wid = tid >> 6;
  float v[8], inc[8];
  float run = 0.f;
  #pragma unroll
  for (int j = 0; j < 8; ++j) { v[j] = sigco[tid*8+j]; run += v[j]; inc[j] = run; }
  float sc = run;
  #pragma unroll
  for (int off = 1; off < 64; off <<= 1) {
    float t = __shfl_up(sc, off);
    if (lane >= off) sc += t;
  }
  if (lane == 63) wsum[wid] = sc;
  __syncthreads();
  if (tid < 16) {
    float wv = wsum[tid];
    float s2 = wv;
    #pragma unroll
    for (int off = 1; off < 16; off <<= 1) {
      float t = __shfl_up(s2, off);
      if (tid >= off) s2 += t;
    }
    wsum[tid] = s2 - wv;
  }
  __syncthreads();
  float excl = wsum[wid] + (sc - run);
  #pragma unroll
  for (int j = 0; j < 8; ++j) cdf[tid*8+j] = excl + inc[j];
  __syncthreads();

  float dco = cst[11];
  float a0=0.f, a1=0.f, a2=0.f;
  #pragma unroll
  for (int j = 0; j < 8; ++j) {
    int i = tid*8+j;
    float T = expf(-dco*(excl+inc[j]));
    float w = T*(1.f-expf(-dco*v[j]));
    a0 += colco[i]*w; a1 += colco[NC+i]*w; a2 += colco[2*NC+i]*w;
  }
  for (int off = 32; off; off >>= 1) {
    a0 += __shfl_down(a0, off); a1 += __shfl_down(a1, off); a2 += __shfl_down(a2, off);
  }
  if (lane==0) { r0[wid]=a0; r1[wid]=a1; r2[wid]=a2; }
  __syncthreads();
  if (tid==0) {
    float s0=0,s1=0,s2=0;
    for (int i=0;i<16;++i){s0+=r0[i];s1+=r1[i];s2+=r2[i];}
    outv[0]=s0; outv[1]=s1; outv[2]=s2;
  }

  // t_fine via inverse CDF: one binary search + monotone walk
  float cdf0 = cdf[0], cdfN = cdf[NC-1];
  float stepi = (cdfN - cdf0) / (float)(NF+1);
  float nearv = cst[9], dt = cst[10];
  int j0 = tid*16;
  float tv = cdf0 + (float)(j0+1)*stepi;
  int lo = 0, hi = NC;
  while (lo < hi) { int mid = (lo+hi)>>1; if (cdf[mid] < tv) lo = mid+1; else hi = mid; }
  for (int q = 0; q < 16; ++q) {
    int j = j0 + q;
    tv = cdf0 + (float)(j+1)*stepi;
    while (lo < NC && cdf[lo] < tv) ++lo;
    int idx = lo-1; idx = idx < 0 ? 0 : (idx > NC-2 ? NC-2 : idx);
    float sig1 = sigco[idx+1];
    tfine[j] = fmaf(dt, (float)idx, nearv) + (tv - cdf[idx]) * (dt / sig1);
  }
}

// ---------------- radix sort: 8 blocks (4 arrays x 2 halves), keys in regs, in-place scatter ----------------
__global__ __launch_bounds__(1024) void k_radix(
    const float* __restrict__ sigco, const float* __restrict__ colco,
    const float* __restrict__ sigfi, const float* __restrict__ colfi,
    float* __restrict__ rad)
{
  __shared__ unsigned int buf[RN];       // 48KB
  __shared__ unsigned int wh[16][256];   // 16KB
  __shared__ unsigned int tot[256];
  __shared__ unsigned int dbase[256];
  const int tid = threadIdx.x;
  const int w = tid >> 6, lane = tid & 63;
  const int a = blockIdx.x >> 1, hf = blockIdx.x & 1;
  const unsigned long long below = (1ull << lane) - 1ull;

  unsigned int key[12];
  #pragma unroll
  for (int j = 0; j < 12; ++j) {
    int i = w*768 + j*64 + lane;   // enumeration order = storage order
    int g = hf*RN + i;
    float v;
    if (a < 3) v = (g < NC) ? colco[a*NC+g] : colfi[a*NF + (g-NC)];
    else       v = (g < NC) ? sigco[g] : sigfi[g-NC];
    key[j] = __float_as_uint(v);
  }

  for (int p = 0; p < 4; ++p) {
    const int sh = p*8;
    for (int i = tid; i < 16*256; i += 1024) ((unsigned int*)wh)[i] = 0;
    __syncthreads();
    unsigned int lrk[12];
    #pragma unroll
    for (int j = 0; j < 12; ++j) {
      unsigned int d = (key[j] >> sh) & 255u;
      unsigned long long m = ~0ull;
      #pragma unroll
      for (int b = 0; b < 8; ++b) {
        unsigned long long bb = __ballot((d >> b) & 1u);
        m &= ((d >> b) & 1u) ? bb : ~bb;
      }
      unsigned int rkl = (unsigned int)__popcll(m & below);
      unsigned int base = wh[w][d];
      if (rkl == 0) wh[w][d] = base + (unsigned int)__popcll(m);
      lrk[j] = base + rkl;
    }
    __syncthreads();
    if (tid < 256) {
      unsigned int run2 = 0;
      #pragma unroll
      for (int ww = 0; ww < 16; ++ww) { unsigned int c = wh[ww][tid]; wh[ww][tid] = run2; run2 += c; }
      tot[tid] = run2;
    }
    __syncthreads();
    if (tid < 64) {
      unsigned int t0=tot[tid*4], t1=tot[tid*4+1], t2=tot[tid*4+2], t3=tot[tid*4+3];
      unsigned int ssum = t0+t1+t2+t3;
      unsigned int sc = ssum;
      for (int off=1; off<64; off<<=1) { unsigned int vv = __shfl_up((int)sc, off); if (lane>=off) sc += vv; }
      unsigned int ex = sc - ssum;
      dbase[tid*4] = ex; dbase[tid*4+1] = ex+t0; dbase[tid*4+2] = ex+t0+t1; dbase[tid*4+3] = ex+t0+t1+t2;
    }
    __syncthreads();
    #pragma unroll
    for (int j = 0; j < 12; ++j) {
      unsigned int d = (key[j] >> sh) & 255u;
      buf[dbase[d] + wh[w][d] + lrk[j]] = key[j];
    }
    __syncthreads();
    if (p < 3) {
      #pragma unroll
      for (int j = 0; j < 12; ++j) key[j] = buf[w*768 + j*64 + lane];
      __syncthreads();
    }
  }
  for (int i = tid; i < RN; i += 1024)
    rad[a*NT + hf*RN + i] = __uint_as_float(buf[i]);
}

// ---------------- merge: 5 rows; row0 = t_coarse(analytic) ∪ t_fine; rows1-4 = sorted halves ----------------
__global__ __launch_bounds__(1024) void k_merge(
    const float* __restrict__ rad, const float* __restrict__ tfine,
    const float* __restrict__ cst, float* __restrict__ srt)
{
  const int row = blockIdx.x >> 2, q = blockIdx.x & 3;
  const float dt = cst[10], nv = cst[9];
  const bool isT = (row == 0);
  const float* A = isT ? (const float*)nullptr : rad + (row-1)*NT;
  const float* B = isT ? tfine : (A + RN);
  const int nA = isT ? NC : RN, nB = isT ? NF : RN;
  int k0 = q*6144 + (int)threadIdx.x*6;
  int lo = k0-nB; if (lo < 0) lo = 0;
  int hi = k0 < nA ? k0 : nA;
  while (lo < hi) {
    int mid = (lo+hi)>>1;
    float av = isT ? fmaf(dt,(float)mid,nv) : A[mid];
    if (av <= B[k0-mid-1]) lo = mid+1; else hi = mid;
  }
  int i = lo, j = k0 - lo;
  float* o = srt + row*NT;
  #pragma unroll
  for (int c = 0; c < 6; ++c) {
    float av = (i < nA) ? (isT ? fmaf(dt,(float)i,nv) : A[i]) : 0.f;
    bool ta = (j >= nB) || (i < nA && av <= B[j]);
    float v = ta ? av : B[j];
    if (ta) ++i; else ++j;
    o[k0+c] = v;
  }
}

// ---------------- final: weighted cumsum over sorted bundle (shfl scan) ----------------
__global__ __launch_bounds__(1024) void k_final(
    const float* __restrict__ srt, float* __restrict__ outv)
{
  const float* trow = srt;
  const float* c0r = srt + NT;
  const float* c1r = srt + 2*NT;
  const float* c2r = srt + 3*NT;
  const float* sgr = srt + 4*NT;
  __shared__ float wsum[16];
  __shared__ float r0[16], r1[16], r2[16];
  const int tid = threadIdx.x;
  const int lane = tid & 63, wid = tid >> 6;
  float sd[24], inc[24];
  float run = 0.f;
  int base = tid*24;
  float tprev = trow[base];
  #pragma unroll
  for (int j = 0; j < 24; ++j) {
    int i = base + j;
    float tnext = (i < NT-1) ? trow[i+1] : 0.f;
    float delta = (i == NT-1) ? LASTD : (tnext - tprev);
    sd[j] = delta * sgr[i];
    run += sd[j];
    inc[j] = run;
    tprev = tnext;
  }
  float sc = run;
  #pragma unroll
  for (int off = 1; off < 64; off <<= 1) {
    float t = __shfl_up(sc, off);
    if (lane >= off) sc += t;
  }
  if (lane == 63) wsum[wid] = sc;
  __syncthreads();
  if (tid < 16) {
    float wv = wsum[tid];
    float s2 = wv;
    #pragma unroll
    for (int off = 1; off < 16; off <<= 1) {
      float t = __shfl_up(s2, off);
      if (tid >= off) s2 += t;
    }
    wsum[tid] = s2 - wv;
  }
  __syncthreads();
  float excl = wsum[wid] + (sc - run);
  float a0=0.f, a1=0.f, a2=0.f;
  #pragma unroll
  for (int j = 0; j < 24; ++j) {
    int i = base + j;
    float T = expf(-(excl+inc[j]));
    float w = T*(1.f-expf(-sd[j]));
    a0 += c0r[i]*w; a1 += c1r[i]*w; a2 += c2r[i]*w;
  }
  for (int off = 32; off; off >>= 1) {
    a0 += __shfl_down(a0, off); a1 += __shfl_down(a1, off); a2 += __shfl_down(a2, off);
  }
  if (lane==0) { r0[wid]=a0; r1[wid]=a1; r2[wid]=a2; }
  __syncthreads();
  if (tid==0) {
    float s0=0,s1=0,s2=0;
    for (int i=0;i<16;++i){s0+=r0[i];s1+=r1[i];s2+=r2[i];}
    outv[3]=s0; outv[4]=s1; outv[5]=s2;
  }
}

extern "C" void kernel_launch(void* const* d_in, const int* in_sizes, int n_in,
                              void* d_out, int out_size, void* d_ws, size_t ws_size,
                              hipStream_t stream) {
  (void)in_sizes; (void)n_in; (void)out_size; (void)ws_size;
  const float* hor  = (const float*)d_in[0];
  const float* ver  = (const float*)d_in[1];
  const float* tm   = (const float*)d_in[2];
  const float* nearp= (const float*)d_in[3];
  const float* farp = (const float*)d_in[4];
  const float* W0   = (const float*)d_in[5];
  const float* b0   = (const float*)d_in[6];
  const float* Wh   = (const float*)d_in[7];
  const float* bh   = (const float*)d_in[8];
  const float* Wsig = (const float*)d_in[9];
  const float* bsig = (const float*)d_in[10];
  const float* Wcol = (const float*)d_in[11];
  const float* bcol = (const float*)d_in[12];
  float* out = (float*)d_out;
  float* ws  = (float*)d_ws;

  float* cst   = ws + WS_CONST;
  float* tfine = ws + WS_TFINE;
  float* sigco = ws + WS_SIGCO;
  float* colco = ws + WS_COLCO;
  float* sigfi = ws + WS_SIGFI;
  float* colfi = ws + WS_COLFI;
  float* srt   = ws + WS_SRT;
  float* rad   = ws + WS_RAD;
  unsigned short* Wt = (unsigned short*)(ws + WS_WT);

  k_prep_w<<<dim3(529), dim3(256), 0, stream>>>(W0, Wh, Wt, hor, ver, tm, nearp, farp,
                                                Wcol, bcol, cst);
  k_mlp_mfma<1><<<dim3(NC/16), dim3(256), 0, stream>>>(cst, Wt, b0, bh, Wsig, bsig, Wcol,
                                                       (const float*)nullptr, NC, sigco, colco);
  k_postco<<<dim3(1), dim3(1024), 0, stream>>>(sigco, colco, cst, tfine, out);
  k_mlp_mfma<2><<<dim3(NF/32), dim3(256), 0, stream>>>(cst, Wt, b0, bh, Wsig, bsig, Wcol,
                                                       (const float*)tfine, NF, sigfi, colfi);
  k_radix<<<dim3(8), dim3(1024), 0, stream>>>(sigco, colco, sigfi, colfi, rad);
  k_merge<<<dim3(20), dim3(1024), 0, stream>>>(rad, tfine, cst, srt);
  k_final<<<dim3(1), dim3(1024), 0, stream>>>(srt, out);
}

// Round 8
// 157.923 us; speedup vs baseline: 1.6955x; 1.1845x over previous
//
#include <hip/hip_runtime.h>
#include <math.h>

#define NC 8192
#define NF 16384
#define NT 24576
#define RN 12288
#define LASTD 1e-4f
#define PI_F 3.14159265358979323846f

// ws layout (float offsets)
#define WS_CONST 0
#define WS_TFINE 64
#define WS_SIGCO (WS_TFINE + NF)
#define WS_COLCO (WS_SIGCO + NC)
#define WS_SIGFI (WS_COLCO + 3*NC)
#define WS_COLFI (WS_SIGFI + NF)
#define WS_SRT   (WS_COLFI + 3*NF)
#define WS_RAD   (WS_SRT + 5*NT)
#define WS_WT    (WS_RAD + 4*NT)   // bf16 weights, 66 chunks * 8192 ushort

typedef __attribute__((ext_vector_type(8))) short bf16x8;
typedef __attribute__((ext_vector_type(4))) float f32x4;

static __device__ inline unsigned short f2b(float x){
  union { float f; unsigned int u; } c; c.f = x;
  unsigned int u = c.u;
  return (unsigned short)((u + 0x7fffu + ((u>>16)&1u)) >> 16);
}
static __device__ inline float b2f(unsigned short u){
  union { unsigned int u; float f; } c; c.u = ((unsigned int)u)<<16; return c.f;
}
__device__ __forceinline__ int swz(int p, int d){
  return (((d>>3)^(p&7))<<3) + (d&7);
}

// ---------------- prep: weights -> bf16 chunks; block 528 does scalar prep ----------------
// chunk c (0..65) -> [mt(16)][lane(64)][j(8)] ushort; chunk = 8192 ushort = 16KB
__global__ __launch_bounds__(256) void k_prep_w(
    const float* __restrict__ W0, const float* __restrict__ Wh,
    unsigned short* __restrict__ Wt,
    const float* hor_, const float* ver_, const float* tm,
    const float* near_, const float* far_,
    const float* Wcol, const float* bcol, float* cst)
{
  if (blockIdx.x == 528) {
    if (threadIdx.x != 0) return;
    float hor = hor_[0], ver = ver_[0], nearv = near_[0], farv = far_[0];
    float dw[3];
    for (int j = 0; j < 3; ++j)
      dw[j] = tm[j*4+0]*hor + tm[j*4+1]*ver + tm[j*4+2] + tm[j*4+3];
    float enc[24];
    for (int i = 0; i < 3; ++i)
      for (int l = 0; l < 4; ++l) {
        float f = PI_F * exp2f(2.f*(float)l);
        float ang = dw[i]*f;
        enc[i*8 + l*2]     = sinf(ang);
        enc[i*8 + l*2 + 1] = cosf(ang);
      }
    for (int c = 0; c < 3; ++c) {
      float s = bcol[c];
      for (int d = 0; d < 24; ++d) s += enc[d]*Wcol[d*3+c];
      cst[6+c] = s;
    }
    for (int j = 0; j < 3; ++j) {
      cst[0+j] = tm[j*4+0]*hor + tm[j*4+1]*ver + tm[j*4+3];
      cst[3+j] = tm[j*4+2];
    }
    cst[9]  = nearv;
    cst[10] = (farv - nearv) / (float)(NC - 1);
    cst[11] = (farv - nearv) / (float)NC;
    return;
  }
  int base = (blockIdx.x*256 + threadIdx.x)*4;
  for (int e = base; e < base+4; ++e) {
    int c = e >> 13;
    if (c >= 66) break;
    int r = e & 8191;
    int mt = r >> 9;
    int q = r & 511;
    int ln = q >> 3, j = q & 7;
    int out = mt*16 + (ln & 15);
    int kk = (ln >> 4)*8 + j;
    float v;
    if (c < 2) {
      int k = c*32 + kk;
      v = (k < 60) ? W0[k*256 + out] : 0.f;
    } else {
      int m = (c-2) >> 3, kc = (c-2) & 7;
      v = Wh[m*65536 + (kc*32+kk)*256 + out];
    }
    Wt[e] = f2b(v);
  }
}

// ---------------- MFMA MLP: register-staged depth-4 weight prefetch (asm), h in LDS ----------------
// Weight stream never touches LDS: 4-slot VGPR ring of A-fragments, counted vmcnt, per-wave
// independent. Slot index (2+kc)&3 is compile-time after unroll (8 chunks/layer). LDS = hbuf only.
template<int NTL>   // points per block = NTL*16
__global__ __launch_bounds__(256, 3) void k_mlp_mfma(
    const float* __restrict__ cst, const unsigned short* __restrict__ Wt,
    const float* __restrict__ b0, const float* __restrict__ bh,
    const float* __restrict__ Wsig, const float* __restrict__ bsig,
    const float* __restrict__ Wcol,
    const float* __restrict__ tf, int npts,
    float* __restrict__ sig_out, float* __restrict__ col_out)
{
  __shared__ __align__(16) unsigned short hbuf[NTL*16*256];   // NTL*8 KB
  const int tid = threadIdx.x;
  const int w = tid >> 6, lane = tid & 63;
  const int lo = lane & 15, hi = lane >> 4;
  const int p0 = blockIdx.x * (NTL*16);

  // ---- positional encoding: 1 sincos + double-angle ladder per (point,dim) ----
  if (tid < NTL*16*3) {
    int p = tid / 3, i = tid - p*3;
    int gp = p0 + p;
    float step = cst[10], nearv = cst[9];
    float t = tf ? tf[gp] : fmaf(step, (float)gp, nearv);
    float x = fmaf(cst[3+i], t, cst[0+i]);
    float s, c;
    sincosf(PI_F * x, &s, &c);
    unsigned short* row = &hbuf[p*256];
    #pragma unroll
    for (int l = 0; l < 10; ++l) {
      int d0 = i*20 + l*2;
      row[swz(p, d0)]   = f2b(s);
      row[swz(p, d0+1)] = f2b(c);
      float s2 = 2.f*s*c, c2 = (c-s)*(c+s);
      s = 2.f*s2*c2; c = (c2-s2)*(c2+s2);
    }
    if (i == 0) {
      #pragma unroll
      for (int d = 60; d < 64; ++d) row[swz(p, d)] = 0;
    }
  }
  __syncthreads();   // drains all counters: vmcnt clean before prefetch choreography

  const char* wbase = (const char*)Wt + (size_t)w*4096 + (size_t)lane*16;
  bf16x8 A00,A01,A02,A03, A10,A11,A12,A13, A20,A21,A22,A23, A30,A31,A32,A33;
  f32x4 acc[4][NTL];

#define GLD4(r0,r1,r2,r3,cc) do{ const char* p_ = wbase + ((size_t)(cc))*16384; \
  asm volatile("global_load_dwordx4 %0, %4, off\n\t" \
               "global_load_dwordx4 %1, %4, off offset:1024\n\t" \
               "global_load_dwordx4 %2, %4, off offset:2048\n\t" \
               "global_load_dwordx4 %3, %4, off offset:3072" \
    : "=&v"(r0), "=&v"(r1), "=&v"(r2), "=&v"(r3) : "v"(p_)); }while(0)

#define VMW(NF_) do{ int nf__=(NF_); \
  if(nf__>=3)      asm volatile("s_waitcnt vmcnt(12)":::"memory"); \
  else if(nf__==2) asm volatile("s_waitcnt vmcnt(8)":::"memory"); \
  else if(nf__==1) asm volatile("s_waitcnt vmcnt(4)":::"memory"); \
  else             asm volatile("s_waitcnt vmcnt(0)":::"memory"); \
  __builtin_amdgcn_sched_barrier(0); }while(0)

#define CONSUME(a0,a1,a2,a3,KK) do{ \
  bf16x8 bfr_[NTL]; \
  _Pragma("unroll") \
  for(int ni=0;ni<NTL;++ni){ int pp=ni*16+lo; int sl_=(KK)*4+hi; \
    bfr_[ni]=*(const bf16x8*)&hbuf[pp*256+((sl_^(pp&7))<<3)]; } \
  _Pragma("unroll") \
  for(int ni=0;ni<NTL;++ni){ \
    acc[0][ni]=__builtin_amdgcn_mfma_f32_16x16x32_bf16(a0,bfr_[ni],acc[0][ni],0,0,0); \
    acc[1][ni]=__builtin_amdgcn_mfma_f32_16x16x32_bf16(a1,bfr_[ni],acc[1][ni],0,0,0); \
    acc[2][ni]=__builtin_amdgcn_mfma_f32_16x16x32_bf16(a2,bfr_[ni],acc[2][ni],0,0,0); \
    acc[3][ni]=__builtin_amdgcn_mfma_f32_16x16x32_bf16(a3,bfr_[ni],acc[3][ni],0,0,0); } \
}while(0)

  auto zacc = [&]() {
    const f32x4 z4 = {0.f,0.f,0.f,0.f};
    #pragma unroll
    for (int mi=0;mi<4;++mi)
      #pragma unroll
      for (int ni=0;ni<NTL;++ni) acc[mi][ni] = z4;
  };
  auto epilogue = [&](const float* bias, bool relu) {
    #pragma unroll
    for (int mi=0;mi<4;++mi) {
      int mt = w*4+mi;
      f32x4 bv = *(const f32x4*)&bias[mt*16 + hi*4];
      #pragma unroll
      for (int ni=0;ni<NTL;++ni) {
        f32x4 v = acc[mi][ni];
        float o0=v[0]+bv[0], o1=v[1]+bv[1], o2=v[2]+bv[2], o3=v[3]+bv[3];
        if (relu){o0=fmaxf(o0,0.f);o1=fmaxf(o1,0.f);o2=fmaxf(o2,0.f);o3=fmaxf(o3,0.f);}
        int pp = ni*16 + lo;
        int colu = mt*16 + hi*4;
        int sl = colu >> 3, off = colu & 7;
        ushort4 uv = make_ushort4(f2b(o0), f2b(o1), f2b(o2), f2b(o3));
        *(ushort4*)&hbuf[pp*256 + ((sl^(pp&7))<<3) + off] = uv;
      }
    }
  };

  // prologue: 4 chunks in flight in registers
  GLD4(A00,A01,A02,A03,0); GLD4(A10,A11,A12,A13,1);
  GLD4(A20,A21,A22,A23,2); GLD4(A30,A31,A32,A33,3);

  // ---- layer 0: chunks 0,1 ----
  zacc();
  VMW(3); CONSUME(A00,A01,A02,A03,0); __builtin_amdgcn_sched_barrier(0); GLD4(A00,A01,A02,A03,4);
  VMW(3); CONSUME(A10,A11,A12,A13,1); __builtin_amdgcn_sched_barrier(0); GLD4(A10,A11,A12,A13,5);
  __builtin_amdgcn_s_barrier();
  epilogue(b0, true);
  asm volatile("s_waitcnt lgkmcnt(0)":::"memory");
  __builtin_amdgcn_sched_barrier(0);
  __builtin_amdgcn_s_barrier();

  // ---- layers 1..8: chunks 2+(l-1)*8 .. +7; ring slot (2+kc)&3 compile-time ----
  #pragma unroll 1
  for (int l = 1; l < 9; ++l) {
    zacc();
    const int cb = 2 + (l-1)*8;
    #pragma unroll
    for (int kc = 0; kc < 8; ++kc) {
      int c = cb + kc;
      int nf = 65 - c; nf = nf > 3 ? 3 : nf;
      VMW(nf);
      switch ((2+kc)&3) {
        case 0:  CONSUME(A00,A01,A02,A03,kc); break;
        case 1:  CONSUME(A10,A11,A12,A13,kc); break;
        case 2:  CONSUME(A20,A21,A22,A23,kc); break;
        default: CONSUME(A30,A31,A32,A33,kc); break;
      }
      __builtin_amdgcn_sched_barrier(0);
      if (c + 4 <= 65) {
        switch ((2+kc)&3) {
          case 0:  GLD4(A00,A01,A02,A03,c+4); break;
          case 1:  GLD4(A10,A11,A12,A13,c+4); break;
          case 2:  GLD4(A20,A21,A22,A23,c+4); break;
          default: GLD4(A30,A31,A32,A33,c+4); break;
        }
      }
    }
    __builtin_amdgcn_s_barrier();   // all waves done reading hbuf
    epilogue(bh + (l-1)*256, l < 8);
    asm volatile("s_waitcnt lgkmcnt(0)":::"memory");
    __builtin_amdgcn_sched_barrier(0);
    __builtin_amdgcn_s_barrier();   // new h visible
  }
#undef GLD4
#undef VMW
#undef CONSUME

  // ---- heads: 4 threads per point, 64 k each; fp32 head weights ----
  if (tid < NTL*64) {
    int p = tid >> 2, s = tid & 3;
    float as_=0.f, a0=0.f, a1=0.f, a2=0.f;
    for (int q=0;q<8;++q) {
      int slot = s*8+q;
      bf16x8 hv = *(const bf16x8*)&hbuf[p*256 + ((slot^(p&7))<<3)];
      #pragma unroll
      for (int j=0;j<8;++j) {
        float hf = b2f((unsigned short)hv[j]);
        int k = s*64 + q*8 + j;
        as_ = fmaf(hf, Wsig[k], as_);
        const float* wc = Wcol + 72 + k*3;
        a0 = fmaf(hf, wc[0], a0);
        a1 = fmaf(hf, wc[1], a1);
        a2 = fmaf(hf, wc[2], a2);
      }
    }
    as_ += __shfl_xor(as_,1); as_ += __shfl_xor(as_,2);
    a0 += __shfl_xor(a0,1); a0 += __shfl_xor(a0,2);
    a1 += __shfl_xor(a1,1); a1 += __shfl_xor(a1,2);
    a2 += __shfl_xor(a2,1); a2 += __shfl_xor(a2,2);
    if (s == 0) {
      sig_out[p0+p] = 1.f/(1.f+expf(-(as_ + bsig[0])));
      col_out[0*npts + p0+p] = 1.f/(1.f+expf(-(a0 + cst[6])));
      col_out[1*npts + p0+p] = 1.f/(1.f+expf(-(a1 + cst[7])));
      col_out[2*npts + p0+p] = 1.f/(1.f+expf(-(a2 + cst[8])));
    }
  }
}

// ---------------- coarse post: cdf scan (shfl), C_coarse, inverse-CDF t_fine ----------------
__global__ __launch_bounds__(1024) void k_postco(
    const float* __restrict__ sigco, const float* __restrict__ colco,
    const float* __restrict__ cst, float* __restrict__ tfine, float* __restrict__ outv)
{
  __shared__ float cdf[NC];
  __shared__ float wsum[16];
  __shared__ float r0[16], r1[16], r2[16];
  const int tid = threadIdx.x;
  const int lane = tid & 63, wid = tid >> 6;
  float v[8], inc[8];
  float run = 0.f;
  #pragma unroll
  for (int j = 0; j < 8; ++j) { v[j] = sigco[tid*8+j]; run += v[j]; inc[j] = run; }
  float sc = run;
  #pragma unroll
  for (int off = 1; off < 64; off <<= 1) {
    float t = __shfl_up(sc, off);
    if (lane >= off) sc += t;
  }
  if (lane == 63) wsum[wid] = sc;
  __syncthreads();
  if (tid < 16) {
    float wv = wsum[tid];
    float s2 = wv;
    #pragma unroll
    for (int off = 1; off < 16; off <<= 1) {
      float t = __shfl_up(s2, off);
      if (tid >= off) s2 += t;
    }
    wsum[tid] = s2 - wv;
  }
  __syncthreads();
  float excl = wsum[wid] + (sc - run);
  #pragma unroll
  for (int j = 0; j < 8; ++j) cdf[tid*8+j] = excl + inc[j];
  __syncthreads();

  float dco = cst[11];
  float a0=0.f, a1=0.f, a2=0.f;
  #pragma unroll
  for (int j = 0; j < 8; ++j) {
    int i = tid*8+j;
    float T = expf(-dco*(excl+inc[j]));
    float w = T*(1.f-expf(-dco*v[j]));
    a0 += colco[i]*w; a1 += colco[NC+i]*w; a2 += colco[2*NC+i]*w;
  }
  for (int off = 32; off; off >>= 1) {
    a0 += __shfl_down(a0, off); a1 += __shfl_down(a1, off); a2 += __shfl_down(a2, off);
  }
  if (lane==0) { r0[wid]=a0; r1[wid]=a1; r2[wid]=a2; }
  __syncthreads();
  if (tid==0) {
    float s0=0,s1=0,s2=0;
    for (int i=0;i<16;++i){s0+=r0[i];s1+=r1[i];s2+=r2[i];}
    outv[0]=s0; outv[1]=s1; outv[2]=s2;
  }

  // t_fine via inverse CDF: one binary search + monotone walk
  float cdf0 = cdf[0], cdfN = cdf[NC-1];
  float stepi = (cdfN - cdf0) / (float)(NF+1);
  float nearv = cst[9], dt = cst[10];
  int j0 = tid*16;
  float tv = cdf0 + (float)(j0+1)*stepi;
  int lo = 0, hi = NC;
  while (lo < hi) { int mid = (lo+hi)>>1; if (cdf[mid] < tv) lo = mid+1; else hi = mid; }
  for (int q = 0; q < 16; ++q) {
    int j = j0 + q;
    tv = cdf0 + (float)(j+1)*stepi;
    while (lo < NC && cdf[lo] < tv) ++lo;
    int idx = lo-1; idx = idx < 0 ? 0 : (idx > NC-2 ? NC-2 : idx);
    float sig1 = sigco[idx+1];
    tfine[j] = fmaf(dt, (float)idx, nearv) + (tv - cdf[idx]) * (dt / sig1);
  }
}

// ---------------- radix sort: 8 blocks (4 arrays x 2 halves), keys in regs, in-place scatter ----------------
__global__ __launch_bounds__(1024) void k_radix(
    const float* __restrict__ sigco, const float* __restrict__ colco,
    const float* __restrict__ sigfi, const float* __restrict__ colfi,
    float* __restrict__ rad)
{
  __shared__ unsigned int buf[RN];       // 48KB
  __shared__ unsigned int wh[16][256];   // 16KB
  __shared__ unsigned int tot[256];
  __shared__ unsigned int dbase[256];
  const int tid = threadIdx.x;
  const int w = tid >> 6, lane = tid & 63;
  const int a = blockIdx.x >> 1, hf = blockIdx.x & 1;
  const unsigned long long below = (1ull << lane) - 1ull;

  unsigned int key[12];
  #pragma unroll
  for (int j = 0; j < 12; ++j) {
    int i = w*768 + j*64 + lane;   // enumeration order = storage order
    int g = hf*RN + i;
    float v;
    if (a < 3) v = (g < NC) ? colco[a*NC+g] : colfi[a*NF + (g-NC)];
    else       v = (g < NC) ? sigco[g] : sigfi[g-NC];
    key[j] = __float_as_uint(v);
  }

  for (int p = 0; p < 4; ++p) {
    const int sh = p*8;
    for (int i = tid; i < 16*256; i += 1024) ((unsigned int*)wh)[i] = 0;
    __syncthreads();
    unsigned int lrk[12];
    #pragma unroll
    for (int j = 0; j < 12; ++j) {
      unsigned int d = (key[j] >> sh) & 255u;
      unsigned long long m = ~0ull;
      #pragma unroll
      for (int b = 0; b < 8; ++b) {
        unsigned long long bb = __ballot((d >> b) & 1u);
        m &= ((d >> b) & 1u) ? bb : ~bb;
      }
      unsigned int rkl = (unsigned int)__popcll(m & below);
      unsigned int base = wh[w][d];
      if (rkl == 0) wh[w][d] = base + (unsigned int)__popcll(m);
      lrk[j] = base + rkl;
    }
    __syncthreads();
    if (tid < 256) {
      unsigned int run2 = 0;
      #pragma unroll
      for (int ww = 0; ww < 16; ++ww) { unsigned int c = wh[ww][tid]; wh[ww][tid] = run2; run2 += c; }
      tot[tid] = run2;
    }
    __syncthreads();
    if (tid < 64) {
      unsigned int t0=tot[tid*4], t1=tot[tid*4+1], t2=tot[tid*4+2], t3=tot[tid*4+3];
      unsigned int ssum = t0+t1+t2+t3;
      unsigned int sc = ssum;
      for (int off=1; off<64; off<<=1) { unsigned int vv = __shfl_up((int)sc, off); if (lane>=off) sc += vv; }
      unsigned int ex = sc - ssum;
      dbase[tid*4] = ex; dbase[tid*4+1] = ex+t0; dbase[tid*4+2] = ex+t0+t1; dbase[tid*4+3] = ex+t0+t1+t2;
    }
    __syncthreads();
    #pragma unroll
    for (int j = 0; j < 12; ++j) {
      unsigned int d = (key[j] >> sh) & 255u;
      buf[dbase[d] + wh[w][d] + lrk[j]] = key[j];
    }
    __syncthreads();
    if (p < 3) {
      #pragma unroll
      for (int j = 0; j < 12; ++j) key[j] = buf[w*768 + j*64 + lane];
      __syncthreads();
    }
  }
  for (int i = tid; i < RN; i += 1024)
    rad[a*NT + hf*RN + i] = __uint_as_float(buf[i]);
}

// ---------------- merge: 5 rows; row0 = t_coarse(analytic) ∪ t_fine; rows1-4 = sorted halves ----------------
__global__ __launch_bounds__(1024) void k_merge(
    const float* __restrict__ rad, const float* __restrict__ tfine,
    const float* __restrict__ cst, float* __restrict__ srt)
{
  const int row = blockIdx.x >> 2, q = blockIdx.x & 3;
  const float dt = cst[10], nv = cst[9];
  const bool isT = (row == 0);
  const float* A = isT ? (const float*)nullptr : rad + (row-1)*NT;
  const float* B = isT ? tfine : (A + RN);
  const int nA = isT ? NC : RN, nB = isT ? NF : RN;
  int k0 = q*6144 + (int)threadIdx.x*6;
  int lo = k0-nB; if (lo < 0) lo = 0;
  int hi = k0 < nA ? k0 : nA;
  while (lo < hi) {
    int mid = (lo+hi)>>1;
    float av = isT ? fmaf(dt,(float)mid,nv) : A[mid];
    if (av <= B[k0-mid-1]) lo = mid+1; else hi = mid;
  }
  int i = lo, j = k0 - lo;
  float* o = srt + row*NT;
  #pragma unroll
  for (int c = 0; c < 6; ++c) {
    float av = (i < nA) ? (isT ? fmaf(dt,(float)i,nv) : A[i]) : 0.f;
    bool ta = (j >= nB) || (i < nA && av <= B[j]);
    float v = ta ? av : B[j];
    if (ta) ++i; else ++j;
    o[k0+c] = v;
  }
}

// ---------------- final: weighted cumsum over sorted bundle (shfl scan) ----------------
__global__ __launch_bounds__(1024) void k_final(
    const float* __restrict__ srt, float* __restrict__ outv)
{
  const float* trow = srt;
  const float* c0r = srt + NT;
  const float* c1r = srt + 2*NT;
  const float* c2r = srt + 3*NT;
  const float* sgr = srt + 4*NT;
  __shared__ float wsum[16];
  __shared__ float r0[16], r1[16], r2[16];
  const int tid = threadIdx.x;
  const int lane = tid & 63, wid = tid >> 6;
  float sd[24], inc[24];
  float run = 0.f;
  int base = tid*24;
  float tprev = trow[base];
  #pragma unroll
  for (int j = 0; j < 24; ++j) {
    int i = base + j;
    float tnext = (i < NT-1) ? trow[i+1] : 0.f;
    float delta = (i == NT-1) ? LASTD : (tnext - tprev);
    sd[j] = delta * sgr[i];
    run += sd[j];
    inc[j] = run;
    tprev = tnext;
  }
  float sc = run;
  #pragma unroll
  for (int off = 1; off < 64; off <<= 1) {
    float t = __shfl_up(sc, off);
    if (lane >= off) sc += t;
  }
  if (lane == 63) wsum[wid] = sc;
  __syncthreads();
  if (tid < 16) {
    float wv = wsum[tid];
    float s2 = wv;
    #pragma unroll
    for (int off = 1; off < 16; off <<= 1) {
      float t = __shfl_up(s2, off);
      if (tid >= off) s2 += t;
    }
    wsum[tid] = s2 - wv;
  }
  __syncthreads();
  float excl = wsum[wid] + (sc - run);
  float a0=0.f, a1=0.f, a2=0.f;
  #pragma unroll
  for (int j = 0; j < 24; ++j) {
    int i = base + j;
    float T = expf(-(excl+inc[j]));
    float w = T*(1.f-expf(-sd[j]));
    a0 += c0r[i]*w; a1 += c1r[i]*w; a2 += c2r[i]*w;
  }
  for (int off = 32; off; off >>= 1) {
    a0 += __shfl_down(a0, off); a1 += __shfl_down(a1, off); a2 += __shfl_down(a2, off);
  }
  if (lane==0) { r0[wid]=a0; r1[wid]=a1; r2[wid]=a2; }
  __syncthreads();
  if (tid==0) {
    float s0=0,s1=0,s2=0;
    for (int i=0;i<16;++i){s0+=r0[i];s1+=r1[i];s2+=r2[i];}
    outv[3]=s0; outv[4]=s1; outv[5]=s2;
  }
}

extern "C" void kernel_launch(void* const* d_in, const int* in_sizes, int n_in,
                              void* d_out, int out_size, void* d_ws, size_t ws_size,
                              hipStream_t stream) {
  (void)in_sizes; (void)n_in; (void)out_size; (void)ws_size;
  const float* hor  = (const float*)d_in[0];
  const float* ver  = (const float*)d_in[1];
  const float* tm   = (const float*)d_in[2];
  const float* nearp= (const float*)d_in[3];
  const float* farp = (const float*)d_in[4];
  const float* W0   = (const float*)d_in[5];
  const float* b0   = (const float*)d_in[6];
  const float* Wh   = (const float*)d_in[7];
  const float* bh   = (const float*)d_in[8];
  const float* Wsig = (const float*)d_in[9];
  const float* bsig = (const float*)d_in[10];
  const float* Wcol = (const float*)d_in[11];
  const float* bcol = (const float*)d_in[12];
  float* out = (float*)d_out;
  float* ws  = (float*)d_ws;

  float* cst   = ws + WS_CONST;
  float* tfine = ws + WS_TFINE;
  float* sigco = ws + WS_SIGCO;
  float* colco = ws + WS_COLCO;
  float* sigfi = ws + WS_SIGFI;
  float* colfi = ws + WS_COLFI;
  float* srt   = ws + WS_SRT;
  float* rad   = ws + WS_RAD;
  unsigned short* Wt = (unsigned short*)(ws + WS_WT);

  k_prep_w<<<dim3(529), dim3(256), 0, stream>>>(W0, Wh, Wt, hor, ver, tm, nearp, farp,
                                                Wcol, bcol, cst);
  k_mlp_mfma<2><<<dim3(NC/32), dim3(256), 0, stream>>>(cst, Wt, b0, bh, Wsig, bsig, Wcol,
                                                       (const float*)nullptr, NC, sigco, colco);
  k_postco<<<dim3(1), dim3(1024), 0, stream>>>(sigco, colco, cst, tfine, out);
  k_mlp_mfma<2><<<dim3(NF/32), dim3(256), 0, stream>>>(cst, Wt, b0, bh, Wsig, bsig, Wcol,
                                                       (const float*)tfine, NF, sigfi, colfi);
  k_radix<<<dim3(8), dim3(1024), 0, stream>>>(sigco, colco, sigfi, colfi, rad);
  k_merge<<<dim3(20), dim3(1024), 0, stream>>>(rad, tfine, cst, srt);
  k_final<<<dim3(1), dim3(1024), 0, stream>>>(srt, out);
}

// Round 9
// 155.943 us; speedup vs baseline: 1.7170x; 1.0127x over previous
//
#include <hip/hip_runtime.h>
#include <math.h>

#define NC 8192
#define NF 16384
#define NT 24576
#define RN 12288
#define LASTD 1e-4f
#define PI_F 3.14159265358979323846f

// ws layout (float offsets)
#define WS_CONST 0
#define WS_TFINE 64
#define WS_SIGCO (WS_TFINE + NF)
#define WS_COLCO (WS_SIGCO + NC)
#define WS_SIGFI (WS_COLCO + 3*NC)
#define WS_COLFI (WS_SIGFI + NF)
#define WS_SRT   (WS_COLFI + 3*NF)
#define WS_RAD   (WS_SRT + 5*NT)
#define WS_WT    (WS_RAD + 4*NT)   // bf16 weights, 66 chunks * 8192 ushort

typedef __attribute__((ext_vector_type(8))) short bf16x8;
typedef __attribute__((ext_vector_type(4))) float f32x4;

static __device__ inline unsigned short f2b(float x){
  union { float f; unsigned int u; } c; c.f = x;
  unsigned int u = c.u;
  return (unsigned short)((u + 0x7fffu + ((u>>16)&1u)) >> 16);
}
static __device__ inline float b2f(unsigned short u){
  union { unsigned int u; float f; } c; c.u = ((unsigned int)u)<<16; return c.f;
}
__device__ __forceinline__ int swz(int p, int d){
  return (((d>>3)^(p&7))<<3) + (d&7);
}

// ---------------- prep: weights -> bf16 chunks; block 528 does scalar prep ----------------
// chunk c (0..65) -> [mt(16)][lane(64)][j(8)] ushort; chunk = 8192 ushort = 16KB
__global__ __launch_bounds__(256) void k_prep_w(
    const float* __restrict__ W0, const float* __restrict__ Wh,
    unsigned short* __restrict__ Wt,
    const float* hor_, const float* ver_, const float* tm,
    const float* near_, const float* far_,
    const float* Wcol, const float* bcol, float* cst)
{
  if (blockIdx.x == 528) {
    if (threadIdx.x != 0) return;
    float hor = hor_[0], ver = ver_[0], nearv = near_[0], farv = far_[0];
    float dw[3];
    for (int j = 0; j < 3; ++j)
      dw[j] = tm[j*4+0]*hor + tm[j*4+1]*ver + tm[j*4+2] + tm[j*4+3];
    float enc[24];
    for (int i = 0; i < 3; ++i)
      for (int l = 0; l < 4; ++l) {
        float f = PI_F * exp2f(2.f*(float)l);
        float ang = dw[i]*f;
        enc[i*8 + l*2]     = sinf(ang);
        enc[i*8 + l*2 + 1] = cosf(ang);
      }
    for (int c = 0; c < 3; ++c) {
      float s = bcol[c];
      for (int d = 0; d < 24; ++d) s += enc[d]*Wcol[d*3+c];
      cst[6+c] = s;
    }
    for (int j = 0; j < 3; ++j) {
      cst[0+j] = tm[j*4+0]*hor + tm[j*4+1]*ver + tm[j*4+3];
      cst[3+j] = tm[j*4+2];
    }
    cst[9]  = nearv;
    cst[10] = (farv - nearv) / (float)(NC - 1);
    cst[11] = (farv - nearv) / (float)NC;
    return;
  }
  int base = (blockIdx.x*256 + threadIdx.x)*4;
  for (int e = base; e < base+4; ++e) {
    int c = e >> 13;
    if (c >= 66) break;
    int r = e & 8191;
    int mt = r >> 9;
    int q = r & 511;
    int ln = q >> 3, j = q & 7;
    int out = mt*16 + (ln & 15);
    int kk = (ln >> 4)*8 + j;
    float v;
    if (c < 2) {
      int k = c*32 + kk;
      v = (k < 60) ? W0[k*256 + out] : 0.f;
    } else {
      int m = (c-2) >> 3, kc = (c-2) & 7;
      v = Wh[m*65536 + (kc*32+kk)*256 + out];
    }
    Wt[e] = f2b(v);
  }
}

// ---------------- MFMA MLP: depth-8 register weight ring, biases in LDS ----------------
// Weight stream: 8-slot VGPR ring (asm global_load_dwordx4), counted vmcnt never drained
// mid-pass (biases read from LDS -> no vmcnt pollution). B-frag ds_reads issued BEFORE the
// vmcnt wait so LDS latency hides under the queue wait.
template<int NTL>   // points per block = NTL*16
__global__ __launch_bounds__(256, 1) void k_mlp_mfma(
    const float* __restrict__ cst, const unsigned short* __restrict__ Wt,
    const float* __restrict__ b0, const float* __restrict__ bh,
    const float* __restrict__ Wsig, const float* __restrict__ bsig,
    const float* __restrict__ Wcol,
    const float* __restrict__ tf, int npts,
    float* __restrict__ sig_out, float* __restrict__ col_out)
{
  __shared__ __align__(16) unsigned short hbuf[NTL*16*256];   // NTL*8 KB
  __shared__ __align__(16) float bbuf[9*256];                 // 9 KB biases
  const int tid = threadIdx.x;
  const int w = tid >> 6, lane = tid & 63;
  const int lo = lane & 15, hi = lane >> 4;
  const int p0 = blockIdx.x * (NTL*16);

  // ---- positional encoding: 1 sincos + double-angle ladder per (point,dim) ----
  if (tid < NTL*16*3) {
    int p = tid / 3, i = tid - p*3;
    int gp = p0 + p;
    float step = cst[10], nearv = cst[9];
    float t = tf ? tf[gp] : fmaf(step, (float)gp, nearv);
    float x = fmaf(cst[3+i], t, cst[0+i]);
    float s, c;
    sincosf(PI_F * x, &s, &c);
    unsigned short* row = &hbuf[p*256];
    #pragma unroll
    for (int l = 0; l < 10; ++l) {
      int d0 = i*20 + l*2;
      row[swz(p, d0)]   = f2b(s);
      row[swz(p, d0+1)] = f2b(c);
      float s2 = 2.f*s*c, c2 = (c-s)*(c+s);
      s = 2.f*s2*c2; c = (c2-s2)*(c2+s2);
    }
    if (i == 0) {
      #pragma unroll
      for (int d = 60; d < 64; ++d) row[swz(p, d)] = 0;
    }
  }
  // ---- biases -> LDS (so epilogue never touches vmcnt) ----
  #pragma unroll
  for (int j = 0; j < 9; ++j)
    bbuf[j*256 + tid] = (j == 0) ? b0[tid] : bh[(j-1)*256 + tid];
  __syncthreads();   // drains all counters: clean slate before prefetch choreography

  const char* wbase = (const char*)Wt + (size_t)w*4096 + (size_t)lane*16;
  bf16x8 R0a,R0b,R0c,R0d, R1a,R1b,R1c,R1d, R2a,R2b,R2c,R2d, R3a,R3b,R3c,R3d,
         R4a,R4b,R4c,R4d, R5a,R5b,R5c,R5d, R6a,R6b,R6c,R6d, R7a,R7b,R7c,R7d;
  f32x4 acc[4][NTL];

#define GLD4(r0,r1,r2,r3,cc) do{ const char* p_ = wbase + ((size_t)(cc))*16384; \
  asm volatile("global_load_dwordx4 %0, %4, off\n\t" \
               "global_load_dwordx4 %1, %4, off offset:1024\n\t" \
               "global_load_dwordx4 %2, %4, off offset:2048\n\t" \
               "global_load_dwordx4 %3, %4, off offset:3072" \
    : "=&v"(r0), "=&v"(r1), "=&v"(r2), "=&v"(r3) : "v"(p_)); }while(0)

#define VMWQ(Q) do{ int nfc__ = 65-(Q); nfc__ = nfc__>7?7:nfc__; \
  switch(nfc__){ \
    case 7: asm volatile("s_waitcnt vmcnt(28)":::"memory"); break; \
    case 6: asm volatile("s_waitcnt vmcnt(24)":::"memory"); break; \
    case 5: asm volatile("s_waitcnt vmcnt(20)":::"memory"); break; \
    case 4: asm volatile("s_waitcnt vmcnt(16)":::"memory"); break; \
    case 3: asm volatile("s_waitcnt vmcnt(12)":::"memory"); break; \
    case 2: asm volatile("s_waitcnt vmcnt(8)":::"memory"); break; \
    case 1: asm volatile("s_waitcnt vmcnt(4)":::"memory"); break; \
    default: asm volatile("s_waitcnt vmcnt(0)":::"memory"); break; } \
  __builtin_amdgcn_sched_barrier(0); }while(0)

// one chunk: B-frag ds_reads (before the wait) -> vmcnt wait -> MFMAs -> reissue slot
#define STEP(r0,r1,r2,r3,KK,Q) do{ \
  bf16x8 bfr_[NTL]; \
  _Pragma("unroll") \
  for(int ni=0;ni<NTL;++ni){ int pp=ni*16+lo; int sl_=(KK)*4+hi; \
    bfr_[ni]=*(const bf16x8*)&hbuf[pp*256+((sl_^(pp&7))<<3)]; } \
  VMWQ(Q); \
  _Pragma("unroll") \
  for(int ni=0;ni<NTL;++ni){ \
    acc[0][ni]=__builtin_amdgcn_mfma_f32_16x16x32_bf16(r0,bfr_[ni],acc[0][ni],0,0,0); \
    acc[1][ni]=__builtin_amdgcn_mfma_f32_16x16x32_bf16(r1,bfr_[ni],acc[1][ni],0,0,0); \
    acc[2][ni]=__builtin_amdgcn_mfma_f32_16x16x32_bf16(r2,bfr_[ni],acc[2][ni],0,0,0); \
    acc[3][ni]=__builtin_amdgcn_mfma_f32_16x16x32_bf16(r3,bfr_[ni],acc[3][ni],0,0,0); } \
  __builtin_amdgcn_sched_barrier(0); \
  if ((Q)+8 <= 65) GLD4(r0,r1,r2,r3,(Q)+8); \
}while(0)

  auto zacc = [&]() {
    const f32x4 z4 = {0.f,0.f,0.f,0.f};
    #pragma unroll
    for (int mi=0;mi<4;++mi)
      #pragma unroll
      for (int ni=0;ni<NTL;++ni) acc[mi][ni] = z4;
  };
  auto epilogue = [&](int l, bool relu) {
    const float* bias = &bbuf[l*256];
    #pragma unroll
    for (int mi=0;mi<4;++mi) {
      int mt = w*4+mi;
      f32x4 bv = *(const f32x4*)&bias[mt*16 + hi*4];   // LDS read (lgkm)
      #pragma unroll
      for (int ni=0;ni<NTL;++ni) {
        f32x4 v = acc[mi][ni];
        float o0=v[0]+bv[0], o1=v[1]+bv[1], o2=v[2]+bv[2], o3=v[3]+bv[3];
        if (relu){o0=fmaxf(o0,0.f);o1=fmaxf(o1,0.f);o2=fmaxf(o2,0.f);o3=fmaxf(o3,0.f);}
        int pp = ni*16 + lo;
        int colu = mt*16 + hi*4;
        int sl = colu >> 3, off = colu & 7;
        ushort4 uv = make_ushort4(f2b(o0), f2b(o1), f2b(o2), f2b(o3));
        *(ushort4*)&hbuf[pp*256 + ((sl^(pp&7))<<3) + off] = uv;
      }
    }
  };

  // prologue: 8 chunks (32 loads) in flight
  GLD4(R0a,R0b,R0c,R0d,0); GLD4(R1a,R1b,R1c,R1d,1);
  GLD4(R2a,R2b,R2c,R2d,2); GLD4(R3a,R3b,R3c,R3d,3);
  GLD4(R4a,R4b,R4c,R4d,4); GLD4(R5a,R5b,R5c,R5d,5);
  GLD4(R6a,R6b,R6c,R6d,6); GLD4(R7a,R7b,R7c,R7d,7);

  // ---- layer 0: chunks 0,1 (slots 0,1) ----
  zacc();
  STEP(R0a,R0b,R0c,R0d, 0, 0);
  STEP(R1a,R1b,R1c,R1d, 1, 1);
  __builtin_amdgcn_s_barrier();
  epilogue(0, true);
  asm volatile("s_waitcnt lgkmcnt(0)":::"memory");
  __builtin_amdgcn_sched_barrier(0);
  __builtin_amdgcn_s_barrier();

  // ---- layers 1..8: chunks cb..cb+7, ring slots (2+kc)&7 = 2,3,4,5,6,7,0,1 ----
  #pragma unroll 1
  for (int l = 1; l < 9; ++l) {
    zacc();
    const int cb = 2 + (l-1)*8;
    STEP(R2a,R2b,R2c,R2d, 0, cb+0);
    STEP(R3a,R3b,R3c,R3d, 1, cb+1);
    STEP(R4a,R4b,R4c,R4d, 2, cb+2);
    STEP(R5a,R5b,R5c,R5d, 3, cb+3);
    STEP(R6a,R6b,R6c,R6d, 4, cb+4);
    STEP(R7a,R7b,R7c,R7d, 5, cb+5);
    STEP(R0a,R0b,R0c,R0d, 6, cb+6);
    STEP(R1a,R1b,R1c,R1d, 7, cb+7);
    __builtin_amdgcn_s_barrier();   // all waves done reading hbuf
    epilogue(l, l < 8);
    asm volatile("s_waitcnt lgkmcnt(0)":::"memory");
    __builtin_amdgcn_sched_barrier(0);
    __builtin_amdgcn_s_barrier();   // new h visible
  }
#undef GLD4
#undef VMWQ
#undef STEP

  // ---- heads: 4 threads per point, 64 k each; fp32 head weights ----
  if (tid < NTL*64) {
    int p = tid >> 2, s = tid & 3;
    float as_=0.f, a0=0.f, a1=0.f, a2=0.f;
    for (int q=0;q<8;++q) {
      int slot = s*8+q;
      bf16x8 hv = *(const bf16x8*)&hbuf[p*256 + ((slot^(p&7))<<3)];
      #pragma unroll
      for (int j=0;j<8;++j) {
        float hf = b2f((unsigned short)hv[j]);
        int k = s*64 + q*8 + j;
        as_ = fmaf(hf, Wsig[k], as_);
        const float* wc = Wcol + 72 + k*3;
        a0 = fmaf(hf, wc[0], a0);
        a1 = fmaf(hf, wc[1], a1);
        a2 = fmaf(hf, wc[2], a2);
      }
    }
    as_ += __shfl_xor(as_,1); as_ += __shfl_xor(as_,2);
    a0 += __shfl_xor(a0,1); a0 += __shfl_xor(a0,2);
    a1 += __shfl_xor(a1,1); a1 += __shfl_xor(a1,2);
    a2 += __shfl_xor(a2,1); a2 += __shfl_xor(a2,2);
    if (s == 0) {
      sig_out[p0+p] = 1.f/(1.f+expf(-(as_ + bsig[0])));
      col_out[0*npts + p0+p] = 1.f/(1.f+expf(-(a0 + cst[6])));
      col_out[1*npts + p0+p] = 1.f/(1.f+expf(-(a1 + cst[7])));
      col_out[2*npts + p0+p] = 1.f/(1.f+expf(-(a2 + cst[8])));
    }
  }
}

// ---------------- coarse post: cdf scan (shfl), C_coarse, inverse-CDF t_fine ----------------
__global__ __launch_bounds__(1024) void k_postco(
    const float* __restrict__ sigco, const float* __restrict__ colco,
    const float* __restrict__ cst, float* __restrict__ tfine, float* __restrict__ outv)
{
  __shared__ float cdf[NC];
  __shared__ float wsum[16];
  __shared__ float r0[16], r1[16], r2[16];
  const int tid = threadIdx.x;
  const int lane = tid & 63, wid = tid >> 6;
  float v[8], inc[8];
  float run = 0.f;
  #pragma unroll
  for (int j = 0; j < 8; ++j) { v[j] = sigco[tid*8+j]; run += v[j]; inc[j] = run; }
  float sc = run;
  #pragma unroll
  for (int off = 1; off < 64; off <<= 1) {
    float t = __shfl_up(sc, off);
    if (lane >= off) sc += t;
  }
  if (lane == 63) wsum[wid] = sc;
  __syncthreads();
  if (tid < 16) {
    float wv = wsum[tid];
    float s2 = wv;
    #pragma unroll
    for (int off = 1; off < 16; off <<= 1) {
      float t = __shfl_up(s2, off);
      if (tid >= off) s2 += t;
    }
    wsum[tid] = s2 - wv;
  }
  __syncthreads();
  float excl = wsum[wid] + (sc - run);
  #pragma unroll
  for (int j = 0; j < 8; ++j) cdf[tid*8+j] = excl + inc[j];
  __syncthreads();

  float dco = cst[11];
  float a0=0.f, a1=0.f, a2=0.f;
  #pragma unroll
  for (int j = 0; j < 8; ++j) {
    int i = tid*8+j;
    float T = expf(-dco*(excl+inc[j]));
    float w = T*(1.f-expf(-dco*v[j]));
    a0 += colco[i]*w; a1 += colco[NC+i]*w; a2 += colco[2*NC+i]*w;
  }
  for (int off = 32; off; off >>= 1) {
    a0 += __shfl_down(a0, off); a1 += __shfl_down(a1, off); a2 += __shfl_down(a2, off);
  }
  if (lane==0) { r0[wid]=a0; r1[wid]=a1; r2[wid]=a2; }
  __syncthreads();
  if (tid==0) {
    float s0=0,s1=0,s2=0;
    for (int i=0;i<16;++i){s0+=r0[i];s1+=r1[i];s2+=r2[i];}
    outv[0]=s0; outv[1]=s1; outv[2]=s2;
  }

  // t_fine via inverse CDF: one binary search + monotone walk
  float cdf0 = cdf[0], cdfN = cdf[NC-1];
  float stepi = (cdfN - cdf0) / (float)(NF+1);
  float nearv = cst[9], dt = cst[10];
  int j0 = tid*16;
  float tv = cdf0 + (float)(j0+1)*stepi;
  int lo = 0, hi = NC;
  while (lo < hi) { int mid = (lo+hi)>>1; if (cdf[mid] < tv) lo = mid+1; else hi = mid; }
  for (int q = 0; q < 16; ++q) {
    int j = j0 + q;
    tv = cdf0 + (float)(j+1)*stepi;
    while (lo < NC && cdf[lo] < tv) ++lo;
    int idx = lo-1; idx = idx < 0 ? 0 : (idx > NC-2 ? NC-2 : idx);
    float sig1 = sigco[idx+1];
    tfine[j] = fmaf(dt, (float)idx, nearv) + (tv - cdf[idx]) * (dt / sig1);
  }
}

// ---------------- radix sort: 8 blocks (4 arrays x 2 halves), keys in regs, in-place scatter ----------------
__global__ __launch_bounds__(1024) void k_radix(
    const float* __restrict__ sigco, const float* __restrict__ colco,
    const float* __restrict__ sigfi, const float* __restrict__ colfi,
    float* __restrict__ rad)
{
  __shared__ unsigned int buf[RN];       // 48KB
  __shared__ unsigned int wh[16][256];   // 16KB
  __shared__ unsigned int tot[256];
  __shared__ unsigned int dbase[256];
  const int tid = threadIdx.x;
  const int w = tid >> 6, lane = tid & 63;
  const int a = blockIdx.x >> 1, hf = blockIdx.x & 1;
  const unsigned long long below = (1ull << lane) - 1ull;

  unsigned int key[12];
  #pragma unroll
  for (int j = 0; j < 12; ++j) {
    int i = w*768 + j*64 + lane;   // enumeration order = storage order
    int g = hf*RN + i;
    float v;
    if (a < 3) v = (g < NC) ? colco[a*NC+g] : colfi[a*NF + (g-NC)];
    else       v = (g < NC) ? sigco[g] : sigfi[g-NC];
    key[j] = __float_as_uint(v);
  }

  for (int p = 0; p < 4; ++p) {
    const int sh = p*8;
    for (int i = tid; i < 16*256; i += 1024) ((unsigned int*)wh)[i] = 0;
    __syncthreads();
    unsigned int lrk[12];
    #pragma unroll
    for (int j = 0; j < 12; ++j) {
      unsigned int d = (key[j] >> sh) & 255u;
      unsigned long long m = ~0ull;
      #pragma unroll
      for (int b = 0; b < 8; ++b) {
        unsigned long long bb = __ballot((d >> b) & 1u);
        m &= ((d >> b) & 1u) ? bb : ~bb;
      }
      unsigned int rkl = (unsigned int)__popcll(m & below);
      unsigned int base = wh[w][d];
      if (rkl == 0) wh[w][d] = base + (unsigned int)__popcll(m);
      lrk[j] = base + rkl;
    }
    __syncthreads();
    if (tid < 256) {
      unsigned int run2 = 0;
      #pragma unroll
      for (int ww = 0; ww < 16; ++ww) { unsigned int c = wh[ww][tid]; wh[ww][tid] = run2; run2 += c; }
      tot[tid] = run2;
    }
    __syncthreads();
    if (tid < 64) {
      unsigned int t0=tot[tid*4], t1=tot[tid*4+1], t2=tot[tid*4+2], t3=tot[tid*4+3];
      unsigned int ssum = t0+t1+t2+t3;
      unsigned int sc = ssum;
      for (int off=1; off<64; off<<=1) { unsigned int vv = __shfl_up((int)sc, off); if (lane>=off) sc += vv; }
      unsigned int ex = sc - ssum;
      dbase[tid*4] = ex; dbase[tid*4+1] = ex+t0; dbase[tid*4+2] = ex+t0+t1; dbase[tid*4+3] = ex+t0+t1+t2;
    }
    __syncthreads();
    #pragma unroll
    for (int j = 0; j < 12; ++j) {
      unsigned int d = (key[j] >> sh) & 255u;
      buf[dbase[d] + wh[w][d] + lrk[j]] = key[j];
    }
    __syncthreads();
    if (p < 3) {
      #pragma unroll
      for (int j = 0; j < 12; ++j) key[j] = buf[w*768 + j*64 + lane];
      __syncthreads();
    }
  }
  for (int i = tid; i < RN; i += 1024)
    rad[a*NT + hf*RN + i] = __uint_as_float(buf[i]);
}

// ---------------- merge: 5 rows; row0 = t_coarse(analytic) ∪ t_fine; rows1-4 = sorted halves ----------------
__global__ __launch_bounds__(1024) void k_merge(
    const float* __restrict__ rad, const float* __restrict__ tfine,
    const float* __restrict__ cst, float* __restrict__ srt)
{
  const int row = blockIdx.x >> 2, q = blockIdx.x & 3;
  const float dt = cst[10], nv = cst[9];
  const bool isT = (row == 0);
  const float* A = isT ? (const float*)nullptr : rad + (row-1)*NT;
  const float* B = isT ? tfine : (A + RN);
  const int nA = isT ? NC : RN, nB = isT ? NF : RN;
  int k0 = q*6144 + (int)threadIdx.x*6;
  int lo = k0-nB; if (lo < 0) lo = 0;
  int hi = k0 < nA ? k0 : nA;
  while (lo < hi) {
    int mid = (lo+hi)>>1;
    float av = isT ? fmaf(dt,(float)mid,nv) : A[mid];
    if (av <= B[k0-mid-1]) lo = mid+1; else hi = mid;
  }
  int i = lo, j = k0 - lo;
  float* o = srt + row*NT;
  #pragma unroll
  for (int c = 0; c < 6; ++c) {
    float av = (i < nA) ? (isT ? fmaf(dt,(float)i,nv) : A[i]) : 0.f;
    bool ta = (j >= nB) || (i < nA && av <= B[j]);
    float v = ta ? av : B[j];
    if (ta) ++i; else ++j;
    o[k0+c] = v;
  }
}

// ---------------- final: weighted cumsum over sorted bundle (shfl scan) ----------------
__global__ __launch_bounds__(1024) void k_final(
    const float* __restrict__ srt, float* __restrict__ outv)
{
  const float* trow = srt;
  const float* c0r = srt + NT;
  const float* c1r = srt + 2*NT;
  const float* c2r = srt + 3*NT;
  const float* sgr = srt + 4*NT;
  __shared__ float wsum[16];
  __shared__ float r0[16], r1[16], r2[16];
  const int tid = threadIdx.x;
  const int lane = tid & 63, wid = tid >> 6;
  float sd[24], inc[24];
  float run = 0.f;
  int base = tid*24;
  float tprev = trow[base];
  #pragma unroll
  for (int j = 0; j < 24; ++j) {
    int i = base + j;
    float tnext = (i < NT-1) ? trow[i+1] : 0.f;
    float delta = (i == NT-1) ? LASTD : (tnext - tprev);
    sd[j] = delta * sgr[i];
    run += sd[j];
    inc[j] = run;
    tprev = tnext;
  }
  float sc = run;
  #pragma unroll
  for (int off = 1; off < 64; off <<= 1) {
    float t = __shfl_up(sc, off);
    if (lane >= off) sc += t;
  }
  if (lane == 63) wsum[wid] = sc;
  __syncthreads();
  if (tid < 16) {
    float wv = wsum[tid];
    float s2 = wv;
    #pragma unroll
    for (int off = 1; off < 16; off <<= 1) {
      float t = __shfl_up(s2, off);
      if (tid >= off) s2 += t;
    }
    wsum[tid] = s2 - wv;
  }
  __syncthreads();
  float excl = wsum[wid] + (sc - run);
  float a0=0.f, a1=0.f, a2=0.f;
  #pragma unroll
  for (int j = 0; j < 24; ++j) {
    int i = base + j;
    float T = expf(-(excl+inc[j]));
    float w = T*(1.f-expf(-sd[j]));
    a0 += c0r[i]*w; a1 += c1r[i]*w; a2 += c2r[i]*w;
  }
  for (int off = 32; off; off >>= 1) {
    a0 += __shfl_down(a0, off); a1 += __shfl_down(a1, off); a2 += __shfl_down(a2, off);
  }
  if (lane==0) { r0[wid]=a0; r1[wid]=a1; r2[wid]=a2; }
  __syncthreads();
  if (tid==0) {
    float s0=0,s1=0,s2=0;
    for (int i=0;i<16;++i){s0+=r0[i];s1+=r1[i];s2+=r2[i];}
    outv[3]=s0; outv[4]=s1; outv[5]=s2;
  }
}

extern "C" void kernel_launch(void* const* d_in, const int* in_sizes, int n_in,
                              void* d_out, int out_size, void* d_ws, size_t ws_size,
                              hipStream_t stream) {
  (void)in_sizes; (void)n_in; (void)out_size; (void)ws_size;
  const float* hor  = (const float*)d_in[0];
  const float* ver  = (const float*)d_in[1];
  const float* tm   = (const float*)d_in[2];
  const float* nearp= (const float*)d_in[3];
  const float* farp = (const float*)d_in[4];
  const float* W0   = (const float*)d_in[5];
  const float* b0   = (const float*)d_in[6];
  const float* Wh   = (const float*)d_in[7];
  const float* bh   = (const float*)d_in[8];
  const float* Wsig = (const float*)d_in[9];
  const float* bsig = (const float*)d_in[10];
  const float* Wcol = (const float*)d_in[11];
  const float* bcol = (const float*)d_in[12];
  float* out = (float*)d_out;
  float* ws  = (float*)d_ws;

  float* cst   = ws + WS_CONST;
  float* tfine = ws + WS_TFINE;
  float* sigco = ws + WS_SIGCO;
  float* colco = ws + WS_COLCO;
  float* sigfi = ws + WS_SIGFI;
  float* colfi = ws + WS_COLFI;
  float* srt   = ws + WS_SRT;
  float* rad   = ws + WS_RAD;
  unsigned short* Wt = (unsigned short*)(ws + WS_WT);

  k_prep_w<<<dim3(529), dim3(256), 0, stream>>>(W0, Wh, Wt, hor, ver, tm, nearp, farp,
                                                Wcol, bcol, cst);
  k_mlp_mfma<2><<<dim3(NC/32), dim3(256), 0, stream>>>(cst, Wt, b0, bh, Wsig, bsig, Wcol,
                                                       (const float*)nullptr, NC, sigco, colco);
  k_postco<<<dim3(1), dim3(1024), 0, stream>>>(sigco, colco, cst, tfine, out);
  k_mlp_mfma<4><<<dim3(NF/64), dim3(256), 0, stream>>>(cst, Wt, b0, bh, Wsig, bsig, Wcol,
                                                       (const float*)tfine, NF, sigfi, colfi);
  k_radix<<<dim3(8), dim3(1024), 0, stream>>>(sigco, colco, sigfi, colfi, rad);
  k_merge<<<dim3(20), dim3(1024), 0, stream>>>(rad, tfine, cst, srt);
  k_final<<<dim3(1), dim3(1024), 0, stream>>>(srt, out);
}

// Round 10
// 152.730 us; speedup vs baseline: 1.7531x; 1.0210x over previous
//
#include <hip/hip_runtime.h>
#include <math.h>

#define NC 8192
#define NF 16384
#define NT 24576
#define RN 12288
#define LASTD 1e-4f
#define PI_F 3.14159265358979323846f

// ws layout (float offsets)
#define WS_CONST 0
#define WS_TFINE 64
#define WS_SIGCO (WS_TFINE + NF)
#define WS_COLCO (WS_SIGCO + NC)
#define WS_SIGFI (WS_COLCO + 3*NC)
#define WS_COLFI (WS_SIGFI + NF)
#define WS_SRT   (WS_COLFI + 3*NF)
#define WS_RAD   (WS_SRT + 5*NT)
#define WS_WT    (WS_RAD + 4*NT)   // bf16 weights, 66 chunks * 8192 ushort

typedef __attribute__((ext_vector_type(8))) short bf16x8;
typedef __attribute__((ext_vector_type(4))) float f32x4;

static __device__ inline unsigned short f2b(float x){
  union { float f; unsigned int u; } c; c.f = x;
  unsigned int u = c.u;
  return (unsigned short)((u + 0x7fffu + ((u>>16)&1u)) >> 16);
}
static __device__ inline float b2f(unsigned short u){
  union { unsigned int u; float f; } c; c.u = ((unsigned int)u)<<16; return c.f;
}
__device__ __forceinline__ int swz(int p, int d){
  return (((d>>3)^(p&7))<<3) + (d&7);
}

// ---------------- prep: weights -> bf16 chunks; block 528 does scalar prep ----------------
// chunk c (0..65) -> [mt(16)][lane(64)][j(8)] ushort; chunk = 8192 ushort = 16KB
__global__ __launch_bounds__(256) void k_prep_w(
    const float* __restrict__ W0, const float* __restrict__ Wh,
    unsigned short* __restrict__ Wt,
    const float* hor_, const float* ver_, const float* tm,
    const float* near_, const float* far_,
    const float* Wcol, const float* bcol, float* cst)
{
  if (blockIdx.x == 528) {
    if (threadIdx.x != 0) return;
    float hor = hor_[0], ver = ver_[0], nearv = near_[0], farv = far_[0];
    float dw[3];
    for (int j = 0; j < 3; ++j)
      dw[j] = tm[j*4+0]*hor + tm[j*4+1]*ver + tm[j*4+2] + tm[j*4+3];
    float enc[24];
    for (int i = 0; i < 3; ++i)
      for (int l = 0; l < 4; ++l) {
        float f = PI_F * exp2f(2.f*(float)l);
        float ang = dw[i]*f;
        enc[i*8 + l*2]     = sinf(ang);
        enc[i*8 + l*2 + 1] = cosf(ang);
      }
    for (int c = 0; c < 3; ++c) {
      float s = bcol[c];
      for (int d = 0; d < 24; ++d) s += enc[d]*Wcol[d*3+c];
      cst[6+c] = s;
    }
    for (int j = 0; j < 3; ++j) {
      cst[0+j] = tm[j*4+0]*hor + tm[j*4+1]*ver + tm[j*4+3];
      cst[3+j] = tm[j*4+2];
    }
    cst[9]  = nearv;
    cst[10] = (farv - nearv) / (float)(NC - 1);
    cst[11] = (farv - nearv) / (float)NC;
    return;
  }
  int base = (blockIdx.x*256 + threadIdx.x)*4;
  for (int e = base; e < base+4; ++e) {
    int c = e >> 13;
    if (c >= 66) break;
    int r = e & 8191;
    int mt = r >> 9;
    int q = r & 511;
    int ln = q >> 3, j = q & 7;
    int out = mt*16 + (ln & 15);
    int kk = (ln >> 4)*8 + j;
    float v;
    if (c < 2) {
      int k = c*32 + kk;
      v = (k < 60) ? W0[k*256 + out] : 0.f;
    } else {
      int m = (c-2) >> 3, kc = (c-2) & 7;
      v = Wh[m*65536 + (kc*32+kk)*256 + out];
    }
    Wt[e] = f2b(v);
  }
}

// ---------------- MFMA MLP: 8 waves x 2 M-tiles, true depth-8 register ring ----------------
// Per wave per chunk: 2 asm global_load_dwordx4 (2KB). Ring = 16 bf16x8 (64 VGPR) -> fits,
// no spill. Counted vmcnt never drained mid-pass; biases in LDS (no vmcnt pollution).
template<int NTL>   // points per block = NTL*16 (NTL=2)
__global__ __launch_bounds__(512, 1) void k_mlp_mfma(
    const float* __restrict__ cst, const unsigned short* __restrict__ Wt,
    const float* __restrict__ b0, const float* __restrict__ bh,
    const float* __restrict__ Wsig, const float* __restrict__ bsig,
    const float* __restrict__ Wcol,
    const float* __restrict__ tf, int npts,
    float* __restrict__ sig_out, float* __restrict__ col_out)
{
  __shared__ __align__(16) unsigned short hbuf[NTL*16*256];   // 16 KB
  __shared__ __align__(16) float bbuf[9*256];                 // 9 KB biases
  const int tid = threadIdx.x;
  const int w = tid >> 6, lane = tid & 63;
  const int lo = lane & 15, hi = lane >> 4;
  const int p0 = blockIdx.x * (NTL*16);

  // ---- positional encoding: 1 sincos + double-angle ladder per (point,dim) ----
  if (tid < NTL*16*3) {
    int p = tid / 3, i = tid - p*3;
    int gp = p0 + p;
    float step = cst[10], nearv = cst[9];
    float t = tf ? tf[gp] : fmaf(step, (float)gp, nearv);
    float x = fmaf(cst[3+i], t, cst[0+i]);
    float s, c;
    sincosf(PI_F * x, &s, &c);
    unsigned short* row = &hbuf[p*256];
    #pragma unroll
    for (int l = 0; l < 10; ++l) {
      int d0 = i*20 + l*2;
      row[swz(p, d0)]   = f2b(s);
      row[swz(p, d0+1)] = f2b(c);
      float s2 = 2.f*s*c, c2 = (c-s)*(c+s);
      s = 2.f*s2*c2; c = (c2-s2)*(c2+s2);
    }
    if (i == 0) {
      #pragma unroll
      for (int d = 60; d < 64; ++d) row[swz(p, d)] = 0;
    }
  }
  // ---- biases -> LDS (epilogue never touches vmcnt) ----
  for (int i = tid; i < 9*256; i += 512) {
    int j = i >> 8, t = i & 255;
    bbuf[i] = (j == 0) ? b0[t] : bh[(j-1)*256 + t];
  }
  __syncthreads();   // clean counters before prefetch choreography

  const char* wbase = (const char*)Wt + (size_t)w*2048 + (size_t)lane*16;
  bf16x8 S0a,S0b, S1a,S1b, S2a,S2b, S3a,S3b, S4a,S4b, S5a,S5b, S6a,S6b, S7a,S7b;
  f32x4 acc[2][NTL];

#define GLD2(ra,rb,cc) do{ const char* p_ = wbase + ((size_t)(cc))*16384; \
  asm volatile("global_load_dwordx4 %0, %2, off\n\t" \
               "global_load_dwordx4 %1, %2, off offset:1024" \
    : "=&v"(ra), "=&v"(rb) : "v"(p_)); }while(0)

#define VMWQ(Q) do{ int nfc__ = 65-(Q); nfc__ = nfc__>7?7:nfc__; \
  switch(nfc__){ \
    case 7: asm volatile("s_waitcnt vmcnt(14)":::"memory"); break; \
    case 6: asm volatile("s_waitcnt vmcnt(12)":::"memory"); break; \
    case 5: asm volatile("s_waitcnt vmcnt(10)":::"memory"); break; \
    case 4: asm volatile("s_waitcnt vmcnt(8)":::"memory"); break; \
    case 3: asm volatile("s_waitcnt vmcnt(6)":::"memory"); break; \
    case 2: asm volatile("s_waitcnt vmcnt(4)":::"memory"); break; \
    case 1: asm volatile("s_waitcnt vmcnt(2)":::"memory"); break; \
    default: asm volatile("s_waitcnt vmcnt(0)":::"memory"); break; } \
  __builtin_amdgcn_sched_barrier(0); }while(0)

// one chunk: B-frag ds_reads (before the wait) -> vmcnt wait -> MFMAs -> reissue slot
#define STEP(ra,rb,KK,Q) do{ \
  bf16x8 bfr_[NTL]; \
  _Pragma("unroll") \
  for(int ni=0;ni<NTL;++ni){ int pp=ni*16+lo; int sl_=(KK)*4+hi; \
    bfr_[ni]=*(const bf16x8*)&hbuf[pp*256+((sl_^(pp&7))<<3)]; } \
  VMWQ(Q); \
  _Pragma("unroll") \
  for(int ni=0;ni<NTL;++ni){ \
    acc[0][ni]=__builtin_amdgcn_mfma_f32_16x16x32_bf16(ra,bfr_[ni],acc[0][ni],0,0,0); \
    acc[1][ni]=__builtin_amdgcn_mfma_f32_16x16x32_bf16(rb,bfr_[ni],acc[1][ni],0,0,0); } \
  __builtin_amdgcn_sched_barrier(0); \
  if ((Q)+8 <= 65) GLD2(ra,rb,(Q)+8); \
}while(0)

  auto zacc = [&]() {
    const f32x4 z4 = {0.f,0.f,0.f,0.f};
    #pragma unroll
    for (int mi=0;mi<2;++mi)
      #pragma unroll
      for (int ni=0;ni<NTL;++ni) acc[mi][ni] = z4;
  };
  auto epilogue = [&](int l, bool relu) {
    const float* bias = &bbuf[l*256];
    #pragma unroll
    for (int mi=0;mi<2;++mi) {
      int mt = w*2+mi;
      f32x4 bv = *(const f32x4*)&bias[mt*16 + hi*4];   // LDS read (lgkm)
      #pragma unroll
      for (int ni=0;ni<NTL;++ni) {
        f32x4 v = acc[mi][ni];
        float o0=v[0]+bv[0], o1=v[1]+bv[1], o2=v[2]+bv[2], o3=v[3]+bv[3];
        if (relu){o0=fmaxf(o0,0.f);o1=fmaxf(o1,0.f);o2=fmaxf(o2,0.f);o3=fmaxf(o3,0.f);}
        int pp = ni*16 + lo;
        int colu = mt*16 + hi*4;
        int sl = colu >> 3, off = colu & 7;
        ushort4 uv = make_ushort4(f2b(o0), f2b(o1), f2b(o2), f2b(o3));
        *(ushort4*)&hbuf[pp*256 + ((sl^(pp&7))<<3) + off] = uv;
      }
    }
  };

  // prologue: 8 chunks (16 loads) in flight
  GLD2(S0a,S0b,0); GLD2(S1a,S1b,1); GLD2(S2a,S2b,2); GLD2(S3a,S3b,3);
  GLD2(S4a,S4b,4); GLD2(S5a,S5b,5); GLD2(S6a,S6b,6); GLD2(S7a,S7b,7);

  // ---- layer 0: chunks 0,1 (slots 0,1) ----
  zacc();
  STEP(S0a,S0b, 0, 0);
  STEP(S1a,S1b, 1, 1);
  __builtin_amdgcn_s_barrier();
  epilogue(0, true);
  asm volatile("s_waitcnt lgkmcnt(0)":::"memory");
  __builtin_amdgcn_sched_barrier(0);
  __builtin_amdgcn_s_barrier();

  // ---- layers 1..8: chunks cb..cb+7, ring slots (2+kc)&7 = 2,3,4,5,6,7,0,1 ----
  #pragma unroll 1
  for (int l = 1; l < 9; ++l) {
    zacc();
    const int cb = 2 + (l-1)*8;
    STEP(S2a,S2b, 0, cb+0);
    STEP(S3a,S3b, 1, cb+1);
    STEP(S4a,S4b, 2, cb+2);
    STEP(S5a,S5b, 3, cb+3);
    STEP(S6a,S6b, 4, cb+4);
    STEP(S7a,S7b, 5, cb+5);
    STEP(S0a,S0b, 6, cb+6);
    STEP(S1a,S1b, 7, cb+7);
    __builtin_amdgcn_s_barrier();   // all waves done reading hbuf
    epilogue(l, l < 8);
    asm volatile("s_waitcnt lgkmcnt(0)":::"memory");
    __builtin_amdgcn_sched_barrier(0);
    __builtin_amdgcn_s_barrier();   // new h visible
  }
#undef GLD2
#undef VMWQ
#undef STEP

  // ---- heads: 4 threads per point, 64 k each; fp32 head weights ----
  if (tid < NTL*64) {
    int p = tid >> 2, s = tid & 3;
    float as_=0.f, a0=0.f, a1=0.f, a2=0.f;
    for (int q=0;q<8;++q) {
      int slot = s*8+q;
      bf16x8 hv = *(const bf16x8*)&hbuf[p*256 + ((slot^(p&7))<<3)];
      #pragma unroll
      for (int j=0;j<8;++j) {
        float hf = b2f((unsigned short)hv[j]);
        int k = s*64 + q*8 + j;
        as_ = fmaf(hf, Wsig[k], as_);
        const float* wc = Wcol + 72 + k*3;
        a0 = fmaf(hf, wc[0], a0);
        a1 = fmaf(hf, wc[1], a1);
        a2 = fmaf(hf, wc[2], a2);
      }
    }
    as_ += __shfl_xor(as_,1); as_ += __shfl_xor(as_,2);
    a0 += __shfl_xor(a0,1); a0 += __shfl_xor(a0,2);
    a1 += __shfl_xor(a1,1); a1 += __shfl_xor(a1,2);
    a2 += __shfl_xor(a2,1); a2 += __shfl_xor(a2,2);
    if (s == 0) {
      sig_out[p0+p] = 1.f/(1.f+expf(-(as_ + bsig[0])));
      col_out[0*npts + p0+p] = 1.f/(1.f+expf(-(a0 + cst[6])));
      col_out[1*npts + p0+p] = 1.f/(1.f+expf(-(a1 + cst[7])));
      col_out[2*npts + p0+p] = 1.f/(1.f+expf(-(a2 + cst[8])));
    }
  }
}

// ---------------- coarse post: cdf scan (shfl), C_coarse, inverse-CDF t_fine ----------------
__global__ __launch_bounds__(1024) void k_postco(
    const float* __restrict__ sigco, const float* __restrict__ colco,
    const float* __restrict__ cst, float* __restrict__ tfine, float* __restrict__ outv)
{
  __shared__ float cdf[NC];
  __shared__ float wsum[16];
  __shared__ float r0[16], r1[16], r2[16];
  const int tid = threadIdx.x;
  const int lane = tid & 63, wid = tid >> 6;
  float v[8], inc[8];
  float run = 0.f;
  #pragma unroll
  for (int j = 0; j < 8; ++j) { v[j] = sigco[tid*8+j]; run += v[j]; inc[j] = run; }
  float sc = run;
  #pragma unroll
  for (int off = 1; off < 64; off <<= 1) {
    float t = __shfl_up(sc, off);
    if (lane >= off) sc += t;
  }
  if (lane == 63) wsum[wid] = sc;
  __syncthreads();
  if (tid < 16) {
    float wv = wsum[tid];
    float s2 = wv;
    #pragma unroll
    for (int off = 1; off < 16; off <<= 1) {
      float t = __shfl_up(s2, off);
      if (tid >= off) s2 += t;
    }
    wsum[tid] = s2 - wv;
  }
  __syncthreads();
  float excl = wsum[wid] + (sc - run);
  #pragma unroll
  for (int j = 0; j < 8; ++j) cdf[tid*8+j] = excl + inc[j];
  __syncthreads();

  float dco = cst[11];
  float a0=0.f, a1=0.f, a2=0.f;
  #pragma unroll
  for (int j = 0; j < 8; ++j) {
    int i = tid*8+j;
    float T = expf(-dco*(excl+inc[j]));
    float w = T*(1.f-expf(-dco*v[j]));
    a0 += colco[i]*w; a1 += colco[NC+i]*w; a2 += colco[2*NC+i]*w;
  }
  for (int off = 32; off; off >>= 1) {
    a0 += __shfl_down(a0, off); a1 += __shfl_down(a1, off); a2 += __shfl_down(a2, off);
  }
  if (lane==0) { r0[wid]=a0; r1[wid]=a1; r2[wid]=a2; }
  __syncthreads();
  if (tid==0) {
    float s0=0,s1=0,s2=0;
    for (int i=0;i<16;++i){s0+=r0[i];s1+=r1[i];s2+=r2[i];}
    outv[0]=s0; outv[1]=s1; outv[2]=s2;
  }

  // t_fine via inverse CDF: one binary search + monotone walk
  float cdf0 = cdf[0], cdfN = cdf[NC-1];
  float stepi = (cdfN - cdf0) / (float)(NF+1);
  float nearv = cst[9], dt = cst[10];
  int j0 = tid*16;
  float tv = cdf0 + (float)(j0+1)*stepi;
  int lo = 0, hi = NC;
  while (lo < hi) { int mid = (lo+hi)>>1; if (cdf[mid] < tv) lo = mid+1; else hi = mid; }
  for (int q = 0; q < 16; ++q) {
    int j = j0 + q;
    tv = cdf0 + (float)(j+1)*stepi;
    while (lo < NC && cdf[lo] < tv) ++lo;
    int idx = lo-1; idx = idx < 0 ? 0 : (idx > NC-2 ? NC-2 : idx);
    float sig1 = sigco[idx+1];
    tfine[j] = fmaf(dt, (float)idx, nearv) + (tv - cdf[idx]) * (dt / sig1);
  }
}

// ---------------- radix sort: 8 blocks (4 arrays x 2 halves), keys in regs, in-place scatter ----------------
__global__ __launch_bounds__(1024) void k_radix(
    const float* __restrict__ sigco, const float* __restrict__ colco,
    const float* __restrict__ sigfi, const float* __restrict__ colfi,
    float* __restrict__ rad)
{
  __shared__ unsigned int buf[RN];       // 48KB
  __shared__ unsigned int wh[16][256];   // 16KB
  __shared__ unsigned int tot[256];
  __shared__ unsigned int dbase[256];
  const int tid = threadIdx.x;
  const int w = tid >> 6, lane = tid & 63;
  const int a = blockIdx.x >> 1, hf = blockIdx.x & 1;
  const unsigned long long below = (1ull << lane) - 1ull;

  unsigned int key[12];
  #pragma unroll
  for (int j = 0; j < 12; ++j) {
    int i = w*768 + j*64 + lane;   // enumeration order = storage order
    int g = hf*RN + i;
    float v;
    if (a < 3) v = (g < NC) ? colco[a*NC+g] : colfi[a*NF + (g-NC)];
    else       v = (g < NC) ? sigco[g] : sigfi[g-NC];
    key[j] = __float_as_uint(v);
  }

  for (int p = 0; p < 4; ++p) {
    const int sh = p*8;
    for (int i = tid; i < 16*256; i += 1024) ((unsigned int*)wh)[i] = 0;
    __syncthreads();
    unsigned int lrk[12];
    #pragma unroll
    for (int j = 0; j < 12; ++j) {
      unsigned int d = (key[j] >> sh) & 255u;
      unsigned long long m = ~0ull;
      #pragma unroll
      for (int b = 0; b < 8; ++b) {
        unsigned long long bb = __ballot((d >> b) & 1u);
        m &= ((d >> b) & 1u) ? bb : ~bb;
      }
      unsigned int rkl = (unsigned int)__popcll(m & below);
      unsigned int base = wh[w][d];
      if (rkl == 0) wh[w][d] = base + (unsigned int)__popcll(m);
      lrk[j] = base + rkl;
    }
    __syncthreads();
    if (tid < 256) {
      unsigned int run2 = 0;
      #pragma unroll
      for (int ww = 0; ww < 16; ++ww) { unsigned int c = wh[ww][tid]; wh[ww][tid] = run2; run2 += c; }
      tot[tid] = run2;
    }
    __syncthreads();
    if (tid < 64) {
      unsigned int t0=tot[tid*4], t1=tot[tid*4+1], t2=tot[tid*4+2], t3=tot[tid*4+3];
      unsigned int ssum = t0+t1+t2+t3;
      unsigned int sc = ssum;
      for (int off=1; off<64; off<<=1) { unsigned int vv = __shfl_up((int)sc, off); if (lane>=off) sc += vv; }
      unsigned int ex = sc - ssum;
      dbase[tid*4] = ex; dbase[tid*4+1] = ex+t0; dbase[tid*4+2] = ex+t0+t1; dbase[tid*4+3] = ex+t0+t1+t2;
    }
    __syncthreads();
    #pragma unroll
    for (int j = 0; j < 12; ++j) {
      unsigned int d = (key[j] >> sh) & 255u;
      buf[dbase[d] + wh[w][d] + lrk[j]] = key[j];
    }
    __syncthreads();
    if (p < 3) {
      #pragma unroll
      for (int j = 0; j < 12; ++j) key[j] = buf[w*768 + j*64 + lane];
      __syncthreads();
    }
  }
  for (int i = tid; i < RN; i += 1024)
    rad[a*NT + hf*RN + i] = __uint_as_float(buf[i]);
}

// ---------------- merge: 5 rows; row0 = t_coarse(analytic) ∪ t_fine; rows1-4 = sorted halves ----------------
__global__ __launch_bounds__(1024) void k_merge(
    const float* __restrict__ rad, const float* __restrict__ tfine,
    const float* __restrict__ cst, float* __restrict__ srt)
{
  const int row = blockIdx.x >> 2, q = blockIdx.x & 3;
  const float dt = cst[10], nv = cst[9];
  const bool isT = (row == 0);
  const float* A = isT ? (const float*)nullptr : rad + (row-1)*NT;
  const float* B = isT ? tfine : (A + RN);
  const int nA = isT ? NC : RN, nB = isT ? NF : RN;
  int k0 = q*6144 + (int)threadIdx.x*6;
  int lo = k0-nB; if (lo < 0) lo = 0;
  int hi = k0 < nA ? k0 : nA;
  while (lo < hi) {
    int mid = (lo+hi)>>1;
    float av = isT ? fmaf(dt,(float)mid,nv) : A[mid];
    if (av <= B[k0-mid-1]) lo = mid+1; else hi = mid;
  }
  int i = lo, j = k0 - lo;
  float* o = srt + row*NT;
  #pragma unroll
  for (int c = 0; c < 6; ++c) {
    float av = (i < nA) ? (isT ? fmaf(dt,(float)i,nv) : A[i]) : 0.f;
    bool ta = (j >= nB) || (i < nA && av <= B[j]);
    float v = ta ? av : B[j];
    if (ta) ++i; else ++j;
    o[k0+c] = v;
  }
}

// ---------------- final: weighted cumsum over sorted bundle (shfl scan) ----------------
__global__ __launch_bounds__(1024) void k_final(
    const float* __restrict__ srt, float* __restrict__ outv)
{
  const float* trow = srt;
  const float* c0r = srt + NT;
  const float* c1r = srt + 2*NT;
  const float* c2r = srt + 3*NT;
  const float* sgr = srt + 4*NT;
  __shared__ float wsum[16];
  __shared__ float r0[16], r1[16], r2[16];
  const int tid = threadIdx.x;
  const int lane = tid & 63, wid = tid >> 6;
  float sd[24], inc[24];
  float run = 0.f;
  int base = tid*24;
  float tprev = trow[base];
  #pragma unroll
  for (int j = 0; j < 24; ++j) {
    int i = base + j;
    float tnext = (i < NT-1) ? trow[i+1] : 0.f;
    float delta = (i == NT-1) ? LASTD : (tnext - tprev);
    sd[j] = delta * sgr[i];
    run += sd[j];
    inc[j] = run;
    tprev = tnext;
  }
  float sc = run;
  #pragma unroll
  for (int off = 1; off < 64; off <<= 1) {
    float t = __shfl_up(sc, off);
    if (lane >= off) sc += t;
  }
  if (lane == 63) wsum[wid] = sc;
  __syncthreads();
  if (tid < 16) {
    float wv = wsum[tid];
    float s2 = wv;
    #pragma unroll
    for (int off = 1; off < 16; off <<= 1) {
      float t = __shfl_up(s2, off);
      if (tid >= off) s2 += t;
    }
    wsum[tid] = s2 - wv;
  }
  __syncthreads();
  float excl = wsum[wid] + (sc - run);
  float a0=0.f, a1=0.f, a2=0.f;
  #pragma unroll
  for (int j = 0; j < 24; ++j) {
    int i = base + j;
    float T = expf(-(excl+inc[j]));
    float w = T*(1.f-expf(-sd[j]));
    a0 += c0r[i]*w; a1 += c1r[i]*w; a2 += c2r[i]*w;
  }
  for (int off = 32; off; off >>= 1) {
    a0 += __shfl_down(a0, off); a1 += __shfl_down(a1, off); a2 += __shfl_down(a2, off);
  }
  if (lane==0) { r0[wid]=a0; r1[wid]=a1; r2[wid]=a2; }
  __syncthreads();
  if (tid==0) {
    float s0=0,s1=0,s2=0;
    for (int i=0;i<16;++i){s0+=r0[i];s1+=r1[i];s2+=r2[i];}
    outv[3]=s0; outv[4]=s1; outv[5]=s2;
  }
}

extern "C" void kernel_launch(void* const* d_in, const int* in_sizes, int n_in,
                              void* d_out, int out_size, void* d_ws, size_t ws_size,
                              hipStream_t stream) {
  (void)in_sizes; (void)n_in; (void)out_size; (void)ws_size;
  const float* hor  = (const float*)d_in[0];
  const float* ver  = (const float*)d_in[1];
  const float* tm   = (const float*)d_in[2];
  const float* nearp= (const float*)d_in[3];
  const float* farp = (const float*)d_in[4];
  const float* W0   = (const float*)d_in[5];
  const float* b0   = (const float*)d_in[6];
  const float* Wh   = (const float*)d_in[7];
  const float* bh   = (const float*)d_in[8];
  const float* Wsig = (const float*)d_in[9];
  const float* bsig = (const float*)d_in[10];
  const float* Wcol = (const float*)d_in[11];
  const float* bcol = (const float*)d_in[12];
  float* out = (float*)d_out;
  float* ws  = (float*)d_ws;

  float* cst   = ws + WS_CONST;
  float* tfine = ws + WS_TFINE;
  float* sigco = ws + WS_SIGCO;
  float* colco = ws + WS_COLCO;
  float* sigfi = ws + WS_SIGFI;
  float* colfi = ws + WS_COLFI;
  float* srt   = ws + WS_SRT;
  float* rad   = ws + WS_RAD;
  unsigned short* Wt = (unsigned short*)(ws + WS_WT);

  k_prep_w<<<dim3(529), dim3(256), 0, stream>>>(W0, Wh, Wt, hor, ver, tm, nearp, farp,
                                                Wcol, bcol, cst);
  k_mlp_mfma<2><<<dim3(NC/32), dim3(512), 0, stream>>>(cst, Wt, b0, bh, Wsig, bsig, Wcol,
                                                       (const float*)nullptr, NC, sigco, colco);
  k_postco<<<dim3(1), dim3(1024), 0, stream>>>(sigco, colco, cst, tfine, out);
  k_mlp_mfma<2><<<dim3(NF/32), dim3(512), 0, stream>>>(cst, Wt, b0, bh, Wsig, bsig, Wcol,
                                                       (const float*)tfine, NF, sigfi, colfi);
  k_radix<<<dim3(8), dim3(1024), 0, stream>>>(sigco, colco, sigfi, colfi, rad);
  k_merge<<<dim3(20), dim3(1024), 0, stream>>>(rad, tfine, cst, srt);
  k_final<<<dim3(1), dim3(1024), 0, stream>>>(srt, out);
}